// Round 3
// baseline (27316.010 us; speedup 1.0000x reference)
//
#include <hip/hip_runtime.h>
#include <hip/hip_bf16.h>

// All reference dtypes are float32: inputs, weights, and output are f32.

// ---------------------------------------------------------------------------
// Direct conv k=4 s=2 p=1. One thread per output element, layout (N,C,OH,OW).
// Block 256 threads, all same co (blockIdx.y); weight slice (Cin*16 f32) in LDS.
// Grid: (N*OH*OW/256, Cout). N*OH*OW divisible by 256 for every layer.
// ---------------------------------------------------------------------------
__global__ __launch_bounds__(256) void conv_k4s2(
    const float* __restrict__ in, const float* __restrict__ w, float* __restrict__ out,
    int N, int Cin, int Cout, int IH, int IW, int OH, int OW)
{
    extern __shared__ float wl[];           // Cin*16 weights for this co
    const int co = blockIdx.y;
    const int nw = Cin * 16;
    for (int j = threadIdx.x; j < nw; j += 256)
        wl[j] = w[(size_t)co * nw + j];     // w[co][ci][kh][kw]
    __syncthreads();

    const int spb = OH * OW;
    const int f   = blockIdx.x * 256 + threadIdx.x;
    const int n   = f / spb;
    const int rem = f - n * spb;
    const int oh  = rem / OW;
    const int ow  = rem - oh * OW;
    const int ih0 = 2 * oh - 1, iw0 = 2 * ow - 1;

    const float* inb = in + (size_t)n * Cin * IH * IW;
    float v = 0.f;
    for (int ci = 0; ci < Cin; ++ci) {
        const float* p  = inb + (size_t)ci * IH * IW;
        const float* wr = wl + ci * 16;
        #pragma unroll
        for (int kh = 0; kh < 4; ++kh) {
            const int ih = ih0 + kh;
            if ((unsigned)ih < (unsigned)IH) {
                const float* row = p + (size_t)ih * IW;
                #pragma unroll
                for (int kw = 0; kw < 4; ++kw) {
                    const int iw = iw0 + kw;
                    if ((unsigned)iw < (unsigned)IW)
                        v = fmaf(row[iw], wr[kh * 4 + kw], v);
                }
            }
        }
    }
    out[((size_t)n * Cout + co) * spb + rem] = v;
}

// ---------------------------------------------------------------------------
// ConvTranspose2d k=4 s=2 p=1 (torch weight layout (Cin, Cout, 4, 4)).
// out[oh,ow] has exactly <=2x2 taps: kh in {p, p+2}, p=(oh+1)&1, ih=(oh+1-kh)/2.
// ---------------------------------------------------------------------------
__global__ __launch_bounds__(256) void deconv_k4s2(
    const float* __restrict__ in, const float* __restrict__ w, float* __restrict__ out,
    int N, int Cin, int Cout, int IH, int IW, int OH, int OW)
{
    extern __shared__ float wl[];           // Cin*16
    const int co = blockIdx.y;
    const int nw = Cin * 16;
    for (int j = threadIdx.x; j < nw; j += 256) {
        int ci = j >> 4, t = j & 15;
        wl[j] = w[((size_t)ci * Cout + co) * 16 + t];
    }
    __syncthreads();

    const int spb = OH * OW;
    const int f   = blockIdx.x * 256 + threadIdx.x;
    const int n   = f / spb;
    const int rem = f - n * spb;
    const int oh  = rem / OW;
    const int ow  = rem - oh * OW;

    const int khp = (oh + 1) & 1;
    const int kwp = (ow + 1) & 1;
    const int ihA = (oh + 1 - khp) >> 1;    // tap A row (kh = khp)
    const int iwA = (ow + 1 - kwp) >> 1;
    const bool vA = ihA < IH, vB = ihA >= 1;   // tap B row is ihA-1 (kh = khp+2)
    const bool hA = iwA < IW, hB = iwA >= 1;
    const int wA = khp * 4, wB = (khp + 2) * 4;

    const float* inb = in + (size_t)n * Cin * IH * IW;
    float v = 0.f;
    for (int ci = 0; ci < Cin; ++ci) {
        const float* p  = inb + (size_t)ci * IH * IW;
        const float* wr = wl + ci * 16;
        if (vA) {
            const float* row = p + (size_t)ihA * IW;
            if (hA) v = fmaf(row[iwA],     wr[wA + kwp],     v);
            if (hB) v = fmaf(row[iwA - 1], wr[wA + kwp + 2], v);
        }
        if (vB) {
            const float* row = p + (size_t)(ihA - 1) * IW;
            if (hA) v = fmaf(row[iwA],     wr[wB + kwp],     v);
            if (hB) v = fmaf(row[iwA - 1], wr[wB + kwp + 2], v);
        }
    }
    out[((size_t)n * Cout + co) * spb + rem] = v;
}

// Final deconv (64 -> 3) + tanh, f32 output.
__global__ __launch_bounds__(256) void deconv_tanh(
    const float* __restrict__ in, const float* __restrict__ w, float* __restrict__ out,
    int N, int Cin, int Cout, int IH, int IW, int OH, int OW)
{
    extern __shared__ float wl[];
    const int co = blockIdx.y;
    const int nw = Cin * 16;
    for (int j = threadIdx.x; j < nw; j += 256) {
        int ci = j >> 4, t = j & 15;
        wl[j] = w[((size_t)ci * Cout + co) * 16 + t];
    }
    __syncthreads();

    const int spb = OH * OW;
    const int f   = blockIdx.x * 256 + threadIdx.x;
    const int n   = f / spb;
    const int rem = f - n * spb;
    const int oh  = rem / OW;
    const int ow  = rem - oh * OW;

    const int khp = (oh + 1) & 1;
    const int kwp = (ow + 1) & 1;
    const int ihA = (oh + 1 - khp) >> 1;
    const int iwA = (ow + 1 - kwp) >> 1;
    const bool vA = ihA < IH, vB = ihA >= 1;
    const bool hA = iwA < IW, hB = iwA >= 1;
    const int wA = khp * 4, wB = (khp + 2) * 4;

    const float* inb = in + (size_t)n * Cin * IH * IW;
    float v = 0.f;
    for (int ci = 0; ci < Cin; ++ci) {
        const float* p  = inb + (size_t)ci * IH * IW;
        const float* wr = wl + ci * 16;
        if (vA) {
            const float* row = p + (size_t)ihA * IW;
            if (hA) v = fmaf(row[iwA],     wr[wA + kwp],     v);
            if (hB) v = fmaf(row[iwA - 1], wr[wA + kwp + 2], v);
        }
        if (vB) {
            const float* row = p + (size_t)(ihA - 1) * IW;
            if (hA) v = fmaf(row[iwA],     wr[wB + kwp],     v);
            if (hB) v = fmaf(row[iwA - 1], wr[wB + kwp + 2], v);
        }
    }
    out[((size_t)n * Cout + co) * spb + rem] = tanhf(v);
}

// ---------------------------------------------------------------------------
// BN batch stats, step 1: partial sum/sumsq per (channel, chunk).
// Grid (S, C), block 256. x layout (N, C, sp) with sp = 1<<spLog.
// ---------------------------------------------------------------------------
__global__ __launch_bounds__(256) void bn_partial(
    const float* __restrict__ x, float* __restrict__ psum, float* __restrict__ psq,
    int C, int spLog, int cnt, int S)
{
    const int c = blockIdx.y;
    const int s = blockIdx.x;
    const int chunk = cnt / S;
    const int lo = s * chunk, hi = lo + chunk;
    const int mask = (1 << spLog) - 1;
    float acc = 0.f, acc2 = 0.f;
    for (int idx = lo + threadIdx.x; idx < hi; idx += 256) {
        int n = idx >> spLog, pos = idx & mask;
        float v = x[(((size_t)n * C + c) << spLog) | (size_t)pos];
        acc += v; acc2 += v * v;
    }
    __shared__ float ls[256], lq[256];
    ls[threadIdx.x] = acc; lq[threadIdx.x] = acc2;
    __syncthreads();
    for (int st = 128; st > 0; st >>= 1) {
        if (threadIdx.x < st) {
            ls[threadIdx.x] += ls[threadIdx.x + st];
            lq[threadIdx.x] += lq[threadIdx.x + st];
        }
        __syncthreads();
    }
    if (threadIdx.x == 0) { psum[c * S + s] = ls[0]; psq[c * S + s] = lq[0]; }
}

// BN step 2: fold partials into per-channel scale/shift.
__global__ __launch_bounds__(256) void bn_finalize(
    const float* __restrict__ psum, const float* __restrict__ psq,
    const float* __restrict__ gamma, const float* __restrict__ beta,
    float* __restrict__ scale, float* __restrict__ shift,
    int C, int S, float inv_count)
{
    int c = blockIdx.x * 256 + threadIdx.x;
    if (c >= C) return;
    float s = 0.f, q = 0.f;
    for (int i = 0; i < S; ++i) { s += psum[c * S + i]; q += psq[c * S + i]; }
    float m   = s * inv_count;
    float var = q * inv_count - m * m;
    var = var < 0.f ? 0.f : var;
    float sc = gamma[c] * rsqrtf(var + 1e-5f);
    scale[c] = sc;
    shift[c] = beta[c] - m * sc;
}

// BN step 3: affine + LeakyReLU(slope) in place. C is a power of two (Cmask).
__global__ __launch_bounds__(256) void bn_act(
    float* __restrict__ x, const float* __restrict__ scale, const float* __restrict__ shift,
    int Cmask, int spLog, float slope, size_t total)
{
    size_t i = (size_t)blockIdx.x * 256 + threadIdx.x;
    if (i >= total) return;
    int c = (int)((i >> spLog) & (size_t)Cmask);
    float v = x[i] * scale[c] + shift[c];
    x[i] = v >= 0.f ? v : slope * v;
}

// Per-channel Linear(16,16): y[b,c,t] = sum_s in[b,c,s]*w[c,t,s] + bias[c,t]
__global__ __launch_bounds__(256) void chanlin(
    const float* __restrict__ in, const float* __restrict__ w, const float* __restrict__ bias,
    float* __restrict__ out)
{
    const int i = blockIdx.x * 256 + threadIdx.x;   // 256*512*16 = 2097152 total
    const int t = i & 15;
    const int c = (i >> 4) & 511;
    const float* src = in + ((size_t)(i >> 4) << 4);        // (b,c) row of 16
    const float* wr  = w + ((size_t)(c * 16 + t) << 4);     // w[c][t][:]
    float acc = bias[c * 16 + t];
    #pragma unroll
    for (int s = 0; s < 16; ++s)
        acc = fmaf(src[s], wr[s], acc);
    out[i] = acc;
}

extern "C" void kernel_launch(void* const* d_in, const int* in_sizes, int n_in,
                              void* d_out, int out_size, void* d_ws, size_t ws_size,
                              hipStream_t stream)
{
    const float* x   = (const float*)d_in[0];
    const float* w1  = (const float*)d_in[1];
    const float* w2  = (const float*)d_in[2];
    const float* w3  = (const float*)d_in[3];
    const float* w4  = (const float*)d_in[4];
    const float* g1  = (const float*)d_in[5];
    const float* b1  = (const float*)d_in[6];
    const float* g2  = (const float*)d_in[7];
    const float* b2  = (const float*)d_in[8];
    const float* g3  = (const float*)d_in[9];
    const float* b3  = (const float*)d_in[10];
    const float* g4  = (const float*)d_in[11];
    const float* b4  = (const float*)d_in[12];
    const float* cww = (const float*)d_in[13];
    const float* cwb = (const float*)d_in[14];
    const float* dw1 = (const float*)d_in[15];
    const float* dw2 = (const float*)d_in[16];
    const float* dw3 = (const float*)d_in[17];
    const float* dw4 = (const float*)d_in[18];
    const float* dg1 = (const float*)d_in[19];
    const float* db1 = (const float*)d_in[20];
    const float* dg2 = (const float*)d_in[21];
    const float* db2 = (const float*)d_in[22];
    const float* dg3 = (const float*)d_in[23];
    const float* db3 = (const float*)d_in[24];

    // workspace (floats): [psum 16K][psq 16K][scale 512][shift 512][pad]
    // arena at +65536 floats, 24M floats (96 MB). total ~100.9 MB.
    float* W     = (float*)d_ws;
    float* psum  = W;
    float* psq   = W + 16384;
    float* scale = W + 32768;
    float* shift = W + 33280;
    float* base  = W + 65536;
    const size_t OFF16 = 16777216;   // 16M floats
    const size_t OFF8  = 8388608;    // 8M floats
    const int N = 256, S = 32;

    // ---- encoder ----
    conv_k4s2<<<dim3(1024, 64), 256, 3 * 64, stream>>>(
        x, w1, base, N, 3, 64, 64, 64, 32, 32);
    bn_partial<<<dim3(S, 64), 256, 0, stream>>>(base, psum, psq, 64, 10, 262144, S);
    bn_finalize<<<2, 256, 0, stream>>>(psum, psq, g1, b1, scale, shift, 64, S, 1.f / 262144.f);
    bn_act<<<65536, 256, 0, stream>>>(base, scale, shift, 63, 10, 0.2f, (size_t)16777216);

    conv_k4s2<<<dim3(256, 128), 256, 64 * 64, stream>>>(
        base, w2, base + OFF16, N, 64, 128, 32, 32, 16, 16);
    bn_partial<<<dim3(S, 128), 256, 0, stream>>>(base + OFF16, psum, psq, 128, 8, 65536, S);
    bn_finalize<<<2, 256, 0, stream>>>(psum, psq, g2, b2, scale, shift, 128, S, 1.f / 65536.f);
    bn_act<<<32768, 256, 0, stream>>>(base + OFF16, scale, shift, 127, 8, 0.2f, (size_t)8388608);

    conv_k4s2<<<dim3(64, 256), 256, 128 * 64, stream>>>(
        base + OFF16, w3, base, N, 128, 256, 16, 16, 8, 8);
    bn_partial<<<dim3(S, 256), 256, 0, stream>>>(base, psum, psq, 256, 6, 16384, S);
    bn_finalize<<<2, 256, 0, stream>>>(psum, psq, g3, b3, scale, shift, 256, S, 1.f / 16384.f);
    bn_act<<<16384, 256, 0, stream>>>(base, scale, shift, 255, 6, 0.2f, (size_t)4194304);

    conv_k4s2<<<dim3(16, 512), 256, 256 * 64, stream>>>(
        base, w4, base + OFF16, N, 256, 512, 8, 8, 4, 4);
    bn_partial<<<dim3(S, 512), 256, 0, stream>>>(base + OFF16, psum, psq, 512, 4, 4096, S);
    bn_finalize<<<2, 256, 0, stream>>>(psum, psq, g4, b4, scale, shift, 512, S, 1.f / 4096.f);
    bn_act<<<8192, 256, 0, stream>>>(base + OFF16, scale, shift, 511, 4, 0.2f, (size_t)2097152);

    // ---- channel-wise linear ----
    chanlin<<<8192, 256, 0, stream>>>(base + OFF16, cww, cwb, base);

    // ---- decoder ----
    deconv_k4s2<<<dim3(64, 256), 256, 512 * 64, stream>>>(
        base, dw1, base + OFF16, N, 512, 256, 4, 4, 8, 8);
    bn_partial<<<dim3(S, 256), 256, 0, stream>>>(base + OFF16, psum, psq, 256, 6, 16384, S);
    bn_finalize<<<2, 256, 0, stream>>>(psum, psq, dg1, db1, scale, shift, 256, S, 1.f / 16384.f);
    bn_act<<<16384, 256, 0, stream>>>(base + OFF16, scale, shift, 255, 6, 0.f, (size_t)4194304);

    deconv_k4s2<<<dim3(256, 128), 256, 256 * 64, stream>>>(
        base + OFF16, dw2, base, N, 256, 128, 8, 8, 16, 16);
    bn_partial<<<dim3(S, 128), 256, 0, stream>>>(base, psum, psq, 128, 8, 65536, S);
    bn_finalize<<<2, 256, 0, stream>>>(psum, psq, dg2, db2, scale, shift, 128, S, 1.f / 65536.f);
    bn_act<<<32768, 256, 0, stream>>>(base, scale, shift, 127, 8, 0.f, (size_t)8388608);

    deconv_k4s2<<<dim3(1024, 64), 256, 128 * 64, stream>>>(
        base, dw3, base + OFF8, N, 128, 64, 16, 16, 32, 32);
    bn_partial<<<dim3(S, 64), 256, 0, stream>>>(base + OFF8, psum, psq, 64, 10, 262144, S);
    bn_finalize<<<2, 256, 0, stream>>>(psum, psq, dg3, db3, scale, shift, 64, S, 1.f / 262144.f);
    bn_act<<<65536, 256, 0, stream>>>(base + OFF8, scale, shift, 63, 10, 0.f, (size_t)16777216);

    deconv_tanh<<<dim3(4096, 3), 256, 64 * 64, stream>>>(
        base + OFF8, dw4, (float*)d_out, N, 64, 3, 32, 32, 64, 64);
}

// Round 4
// 2851.088 us; speedup vs baseline: 9.5809x; 9.5809x over previous
//
#include <hip/hip_runtime.h>
#include <math.h>

// ===========================================================================
// Implicit-GEMM tiled conv/deconv, f32.
// Block tile: SPT spatial positions x COB output channels, 256 threads,
// 16 acc/thread (4 sp x 4 co). K staged in LDS chunks of KC:
//   Xs[k][sp]  (im2col slice)   Ws[k][co]  (weight slice, transposed)
// Inner loop per k: 2x ds_read_b128 + 16 FMA  -> VALU-bound.
// Deconv handled per output parity (grid.z = 4): at fixed parity it is a
// 2x2-tap stride-1 conv, so the same GEMM structure applies.
// ===========================================================================

// ---------------- conv k4 s2 p1 ----------------
template<int CIN,int IH,int IW,int OH,int OW,int COUT,int KC,int SPT,int COB>
__global__ __launch_bounds__(256) void conv_mm(
    const float* __restrict__ in, const float* __restrict__ w,
    float* __restrict__ out, int N)
{
    constexpr int KTOT   = CIN * 16;
    constexpr int CHUNKS = KTOT / KC;
    constexpr int KPT    = KC * SPT / 256;   // gather elems per thread
    constexpr int WPT    = KC * COB / 256;   // weight elems per thread
    constexpr int TPC    = 256 / COB;        // threads per co (W load)
    constexpr int SPG    = SPT / 4;

    __shared__ float Xs[KC * SPT];
    __shared__ float Ws[KC * COB];

    const int t = threadIdx.x;
    // GEMM mapping
    const int sp_sub = (t % SPG) * 4;
    const int co_sub = (t / SPG) * 4;
    // gather mapping
    const int sp_g = t % SPT;
    const int kk   = t / SPT;
    const int gsp  = blockIdx.x * SPT + sp_g;
    const int n_g  = gsp / (OH * OW);
    const int rg   = gsp % (OH * OW);
    const int oh_g = rg / OW;
    const int ow_g = rg % OW;
    const int ih0  = 2 * oh_g - 1, iw0 = 2 * ow_g - 1;
    const float* inb = in + (size_t)n_g * CIN * IH * IW;
    // W-load mapping
    const int co_w = t / TPC;
    const int k0w  = (t % TPC) * WPT;
    const int cob  = blockIdx.y;
    const float* wrow = w + (size_t)(cob * COB + co_w) * KTOT;

    float acc[16];
    #pragma unroll
    for (int i = 0; i < 16; ++i) acc[i] = 0.f;

    for (int c = 0; c < CHUNKS; ++c) {
        if (c) __syncthreads();
        #pragma unroll
        for (int j = 0; j < WPT; ++j) {
            int k = k0w + j;
            float wv = 0.f;
            if (COUT % COB == 0 || cob * COB + co_w < COUT)
                wv = wrow[c * KC + k];
            Ws[k * COB + co_w] = wv;
        }
        #pragma unroll
        for (int j = 0; j < KPT; ++j) {
            int k  = kk * KPT + j;
            int kg = c * KC + k;
            int ci = kg >> 4, khw = kg & 15;
            int kh = khw >> 2, kw = khw & 3;
            int ih = ih0 + kh, iw = iw0 + kw;
            float v = 0.f;
            if ((unsigned)ih < (unsigned)IH && (unsigned)iw < (unsigned)IW)
                v = inb[((size_t)ci * IH + ih) * IW + iw];
            Xs[k * SPT + sp_g] = v;
        }
        __syncthreads();
        #pragma unroll 8
        for (int k = 0; k < KC; ++k) {
            const float4 xv = *(const float4*)&Xs[k * SPT + sp_sub];
            const float4 wv = *(const float4*)&Ws[k * COB + co_sub];
            const float x4[4] = {xv.x, xv.y, xv.z, xv.w};
            const float w4[4] = {wv.x, wv.y, wv.z, wv.w};
            #pragma unroll
            for (int a = 0; a < 4; ++a)
                #pragma unroll
                for (int b = 0; b < 4; ++b)
                    acc[a * 4 + b] = fmaf(w4[a], x4[b], acc[a * 4 + b]);
        }
    }
    // epilogue (4 consecutive sp are within one row: OW % 4 == 0)
    const int gsp0 = blockIdx.x * SPT + sp_sub;
    const int n0   = gsp0 / (OH * OW);
    const int r0   = gsp0 % (OH * OW);
    const int oh0  = r0 / OW, ow0 = r0 % OW;
    #pragma unroll
    for (int a = 0; a < 4; ++a) {
        int co = cob * COB + co_sub + a;
        if (COUT % COB == 0 || co < COUT) {
            float4 v = make_float4(acc[a*4+0], acc[a*4+1], acc[a*4+2], acc[a*4+3]);
            *(float4*)&out[(((size_t)n0 * COUT + co) * OH + oh0) * OW + ow0] = v;
        }
    }
}

// ---------------- deconv k4 s2 p1, per output parity ----------------
// oh = 2*ohh+poh, ow = 2*oww+pow. Taps: kh = (1-poh)+2*t2h, ih = ohh+poh-t2h
// (same for w). K = CIN*4, k = ci*4 + t2h*2 + t2w. Torch weight (CIN,COUT,4,4).
template<int CIN,int IH,int IW,int OH,int OW,int COUT,int KC,int SPT,int COB,bool TANH>
__global__ __launch_bounds__(256) void deconv_mm(
    const float* __restrict__ in, const float* __restrict__ w,
    float* __restrict__ out, int N)
{
    constexpr int KTOT   = CIN * 4;
    constexpr int CHUNKS = KTOT / KC;
    constexpr int KPT    = KC * SPT / 256;
    constexpr int WPT    = KC * COB / 256;
    constexpr int TPC    = 256 / COB;
    constexpr int SPG    = SPT / 4;
    constexpr int OHh = OH / 2, OWh = OW / 2;

    __shared__ float Xs[KC * SPT];
    __shared__ float Ws[KC * COB];

    const int t = threadIdx.x;
    const int poh = blockIdx.z >> 1, pw = blockIdx.z & 1;
    const int khp = 1 - poh, kwp = 1 - pw;

    const int sp_sub = (t % SPG) * 4;
    const int co_sub = (t / SPG) * 4;

    const int sp_g = t % SPT;
    const int kk   = t / SPT;
    const int gsp  = blockIdx.x * SPT + sp_g;
    const int n_g  = gsp / (OHh * OWh);
    const int rg   = gsp % (OHh * OWh);
    const int ohh  = rg / OWh;
    const int oww  = rg % OWh;
    const float* inb = in + (size_t)n_g * CIN * IH * IW;

    const int co_w = t / TPC;
    const int k0w  = (t % TPC) * WPT;
    const int cob  = blockIdx.y;
    const int cog  = cob * COB + co_w;

    float acc[16];
    #pragma unroll
    for (int i = 0; i < 16; ++i) acc[i] = 0.f;

    for (int c = 0; c < CHUNKS; ++c) {
        if (c) __syncthreads();
        #pragma unroll
        for (int j = 0; j < WPT; ++j) {
            int k   = k0w + j;
            int kg  = c * KC + k;
            int ci  = kg >> 2, tap = kg & 3;
            int t2h = tap >> 1, t2w = tap & 1;
            float wv = 0.f;
            if (COUT % COB == 0 || cog < COUT)
                wv = w[((size_t)ci * COUT + cog) * 16
                       + (khp + 2 * t2h) * 4 + (kwp + 2 * t2w)];
            Ws[k * COB + co_w] = wv;
        }
        #pragma unroll
        for (int j = 0; j < KPT; ++j) {
            int k   = kk * KPT + j;
            int kg  = c * KC + k;
            int ci  = kg >> 2, tap = kg & 3;
            int t2h = tap >> 1, t2w = tap & 1;
            int ih  = ohh + poh - t2h;
            int iw  = oww + pw  - t2w;
            float v = 0.f;
            if ((unsigned)ih < (unsigned)IH && (unsigned)iw < (unsigned)IW)
                v = inb[((size_t)ci * IH + ih) * IW + iw];
            Xs[k * SPT + sp_g] = v;
        }
        __syncthreads();
        #pragma unroll 8
        for (int k = 0; k < KC; ++k) {
            const float4 xv = *(const float4*)&Xs[k * SPT + sp_sub];
            const float4 wv = *(const float4*)&Ws[k * COB + co_sub];
            const float x4[4] = {xv.x, xv.y, xv.z, xv.w};
            const float w4[4] = {wv.x, wv.y, wv.z, wv.w};
            #pragma unroll
            for (int a = 0; a < 4; ++a)
                #pragma unroll
                for (int b = 0; b < 4; ++b)
                    acc[a * 4 + b] = fmaf(w4[a], x4[b], acc[a * 4 + b]);
        }
    }
    const int gsp0 = blockIdx.x * SPT + sp_sub;
    const int n0   = gsp0 / (OHh * OWh);
    const int r0   = gsp0 % (OHh * OWh);
    const int ohh0 = r0 / OWh, oww0 = r0 % OWh;
    const int oh0  = 2 * ohh0 + poh;
    #pragma unroll
    for (int a = 0; a < 4; ++a) {
        int co = cob * COB + co_sub + a;
        if (COUT % COB == 0 || co < COUT) {
            float* ob = out + (((size_t)n0 * COUT + co) * OH + oh0) * OW;
            #pragma unroll
            for (int b = 0; b < 4; ++b) {
                float v = acc[a * 4 + b];
                ob[2 * (oww0 + b) + pw] = TANH ? tanhf(v) : v;
            }
        }
    }
}

// ---------------- BN (3-step) + activation ----------------
__global__ __launch_bounds__(256) void bn_partial(
    const float* __restrict__ x, float* __restrict__ psum, float* __restrict__ psq,
    int C, int spLog, int cnt, int S)
{
    const int c = blockIdx.y;
    const int s = blockIdx.x;
    const int chunk = cnt / S;
    const int lo = s * chunk, hi = lo + chunk;
    const int mask = (1 << spLog) - 1;
    float acc = 0.f, acc2 = 0.f;
    for (int idx = lo + threadIdx.x; idx < hi; idx += 256) {
        int n = idx >> spLog, pos = idx & mask;
        float v = x[(((size_t)n * C + c) << spLog) | (size_t)pos];
        acc += v; acc2 += v * v;
    }
    __shared__ float ls[256], lq[256];
    ls[threadIdx.x] = acc; lq[threadIdx.x] = acc2;
    __syncthreads();
    for (int st = 128; st > 0; st >>= 1) {
        if (threadIdx.x < st) {
            ls[threadIdx.x] += ls[threadIdx.x + st];
            lq[threadIdx.x] += lq[threadIdx.x + st];
        }
        __syncthreads();
    }
    if (threadIdx.x == 0) { psum[c * S + s] = ls[0]; psq[c * S + s] = lq[0]; }
}

__global__ __launch_bounds__(256) void bn_finalize(
    const float* __restrict__ psum, const float* __restrict__ psq,
    const float* __restrict__ gamma, const float* __restrict__ beta,
    float* __restrict__ scale, float* __restrict__ shift,
    int C, int S, float inv_count)
{
    int c = blockIdx.x * 256 + threadIdx.x;
    if (c >= C) return;
    float s = 0.f, q = 0.f;
    for (int i = 0; i < S; ++i) { s += psum[c * S + i]; q += psq[c * S + i]; }
    float m   = s * inv_count;
    float var = q * inv_count - m * m;
    var = var < 0.f ? 0.f : var;
    float sc = gamma[c] * rsqrtf(var + 1e-5f);
    scale[c] = sc;
    shift[c] = beta[c] - m * sc;
}

__global__ __launch_bounds__(256) void bn_act(
    float* __restrict__ x, const float* __restrict__ scale, const float* __restrict__ shift,
    int Cmask, int spLog, float slope, size_t total)
{
    size_t i = (size_t)blockIdx.x * 256 + threadIdx.x;
    if (i >= total) return;
    int c = (int)((i >> spLog) & (size_t)Cmask);
    float v = x[i] * scale[c] + shift[c];
    x[i] = v >= 0.f ? v : slope * v;
}

// Per-channel Linear(16,16)
__global__ __launch_bounds__(256) void chanlin(
    const float* __restrict__ in, const float* __restrict__ w, const float* __restrict__ bias,
    float* __restrict__ out)
{
    const int i = blockIdx.x * 256 + threadIdx.x;
    const int t = i & 15;
    const int c = (i >> 4) & 511;
    const float* src = in + ((size_t)(i >> 4) << 4);
    const float* wr  = w + ((size_t)(c * 16 + t) << 4);
    float acc = bias[c * 16 + t];
    #pragma unroll
    for (int s = 0; s < 16; ++s)
        acc = fmaf(src[s], wr[s], acc);
    out[i] = acc;
}

extern "C" void kernel_launch(void* const* d_in, const int* in_sizes, int n_in,
                              void* d_out, int out_size, void* d_ws, size_t ws_size,
                              hipStream_t stream)
{
    const float* x   = (const float*)d_in[0];
    const float* w1  = (const float*)d_in[1];
    const float* w2  = (const float*)d_in[2];
    const float* w3  = (const float*)d_in[3];
    const float* w4  = (const float*)d_in[4];
    const float* g1  = (const float*)d_in[5];
    const float* b1  = (const float*)d_in[6];
    const float* g2  = (const float*)d_in[7];
    const float* b2  = (const float*)d_in[8];
    const float* g3  = (const float*)d_in[9];
    const float* b3  = (const float*)d_in[10];
    const float* g4  = (const float*)d_in[11];
    const float* b4  = (const float*)d_in[12];
    const float* cww = (const float*)d_in[13];
    const float* cwb = (const float*)d_in[14];
    const float* dw1 = (const float*)d_in[15];
    const float* dw2 = (const float*)d_in[16];
    const float* dw3 = (const float*)d_in[17];
    const float* dw4 = (const float*)d_in[18];
    const float* dg1 = (const float*)d_in[19];
    const float* db1 = (const float*)d_in[20];
    const float* dg2 = (const float*)d_in[21];
    const float* db2 = (const float*)d_in[22];
    const float* dg3 = (const float*)d_in[23];
    const float* db3 = (const float*)d_in[24];

    float* W     = (float*)d_ws;
    float* psum  = W;
    float* psq   = W + 16384;
    float* scale = W + 32768;
    float* shift = W + 33280;
    float* base  = W + 65536;
    const size_t OFF16 = 16777216;
    const size_t OFF8  = 8388608;
    const int N = 256, S = 32;

    // ---- encoder ----
    conv_mm<3,64,64,32,32,64, 48,128,32><<<dim3(2048,2), 256, 0, stream>>>(x, w1, base, N);
    bn_partial<<<dim3(S,64), 256, 0, stream>>>(base, psum, psq, 64, 10, 262144, S);
    bn_finalize<<<2, 256, 0, stream>>>(psum, psq, g1, b1, scale, shift, 64, S, 1.f/262144.f);
    bn_act<<<65536, 256, 0, stream>>>(base, scale, shift, 63, 10, 0.2f, (size_t)16777216);

    conv_mm<64,32,32,16,16,128, 64,128,32><<<dim3(512,4), 256, 0, stream>>>(base, w2, base + OFF16, N);
    bn_partial<<<dim3(S,128), 256, 0, stream>>>(base + OFF16, psum, psq, 128, 8, 65536, S);
    bn_finalize<<<2, 256, 0, stream>>>(psum, psq, g2, b2, scale, shift, 128, S, 1.f/65536.f);
    bn_act<<<32768, 256, 0, stream>>>(base + OFF16, scale, shift, 127, 8, 0.2f, (size_t)8388608);

    conv_mm<128,16,16,8,8,256, 64,128,32><<<dim3(128,8), 256, 0, stream>>>(base + OFF16, w3, base, N);
    bn_partial<<<dim3(S,256), 256, 0, stream>>>(base, psum, psq, 256, 6, 16384, S);
    bn_finalize<<<2, 256, 0, stream>>>(psum, psq, g3, b3, scale, shift, 256, S, 1.f/16384.f);
    bn_act<<<16384, 256, 0, stream>>>(base, scale, shift, 255, 6, 0.2f, (size_t)4194304);

    conv_mm<256,8,8,4,4,512, 64,128,32><<<dim3(32,16), 256, 0, stream>>>(base, w4, base + OFF16, N);
    bn_partial<<<dim3(S,512), 256, 0, stream>>>(base + OFF16, psum, psq, 512, 4, 4096, S);
    bn_finalize<<<2, 256, 0, stream>>>(psum, psq, g4, b4, scale, shift, 512, S, 1.f/4096.f);
    bn_act<<<8192, 256, 0, stream>>>(base + OFF16, scale, shift, 511, 4, 0.2f, (size_t)2097152);

    // ---- channel-wise linear ----
    chanlin<<<8192, 256, 0, stream>>>(base + OFF16, cww, cwb, base);

    // ---- decoder ----
    deconv_mm<512,4,4,8,8,256, 64,128,32,false><<<dim3(32,8,4), 256, 0, stream>>>(base, dw1, base + OFF16, N);
    bn_partial<<<dim3(S,256), 256, 0, stream>>>(base + OFF16, psum, psq, 256, 6, 16384, S);
    bn_finalize<<<2, 256, 0, stream>>>(psum, psq, dg1, db1, scale, shift, 256, S, 1.f/16384.f);
    bn_act<<<16384, 256, 0, stream>>>(base + OFF16, scale, shift, 255, 6, 0.f, (size_t)4194304);

    deconv_mm<256,8,8,16,16,128, 64,128,32,false><<<dim3(128,4,4), 256, 0, stream>>>(base + OFF16, dw2, base, N);
    bn_partial<<<dim3(S,128), 256, 0, stream>>>(base, psum, psq, 128, 8, 65536, S);
    bn_finalize<<<2, 256, 0, stream>>>(psum, psq, dg2, db2, scale, shift, 128, S, 1.f/65536.f);
    bn_act<<<32768, 256, 0, stream>>>(base, scale, shift, 127, 8, 0.f, (size_t)8388608);

    deconv_mm<128,16,16,32,32,64, 64,128,32,false><<<dim3(512,2,4), 256, 0, stream>>>(base, dw3, base + OFF8, N);
    bn_partial<<<dim3(S,64), 256, 0, stream>>>(base + OFF8, psum, psq, 64, 10, 262144, S);
    bn_finalize<<<2, 256, 0, stream>>>(psum, psq, dg3, db3, scale, shift, 64, S, 1.f/262144.f);
    bn_act<<<65536, 256, 0, stream>>>(base + OFF8, scale, shift, 63, 10, 0.f, (size_t)16777216);

    deconv_mm<64,32,32,64,64,3, 32,256,16,true><<<dim3(1024,1,4), 256, 0, stream>>>(base + OFF8, dw4, (float*)d_out, N);
}

// Round 5
// 2597.687 us; speedup vs baseline: 10.5155x; 1.0975x over previous
//
#include <hip/hip_runtime.h>
#include <math.h>

typedef _Float16 f16;
typedef __attribute__((ext_vector_type(8))) _Float16 f16x8;
typedef __attribute__((ext_vector_type(16))) float f32x16;

union U64x2 { unsigned long long u[2]; f16x8 v; };
union Q16   { uint4 q; unsigned long long u[2]; };
union P4    { _Float16 h[4]; unsigned long long u; };

// ===========================================================================
// fp16 MFMA implicit-GEMM conv/deconv (k4 s2 p1), NHWC activations.
// A = W [co][k], B = X(im2col) [k][sp], D[m=co][n=sp] via mfma_f32_32x32x16_f16.
// C/D layout: col=lane&31, row=(reg&3)+8*(reg>>2)+4*(lane>>5)  [guide §3].
// A/B layout: free=lane&31, k=8*(lane>>5)+j (8 contiguous f16 per lane).
// K chunked at 64 = one (kh,kw) tap x 64-ci run (CIN%64==0) -> contiguous
// global loads. LDS rows stride 68 f16 (=17 u64): 8B-aligned b64 frag reads,
// lane n / n+16 2-way bank alias (free). Deconv: per-output-parity (grid z),
// fixed parity = 2x2-tap stride-1 conv. KS>1: K-split blocks atomicAdd f32.
// ===========================================================================
template<int CIN,int IH,int IW,int OH,int OW,int COUT,int COB,int SPT,int KS,
         int CO_FR,bool DEC>
__global__ __launch_bounds__(256,2) void mfma_conv(
    const f16* __restrict__ xin, const f16* __restrict__ wp,
    f16* __restrict__ out16, float* __restrict__ out32)
{
    constexpr int OHo  = DEC ? OH/2 : OH;
    constexpr int OWo  = DEC ? OW/2 : OW;
    constexpr int KTOT = CIN * (DEC ? 4 : 16);
    constexpr int CH   = (KTOT/64) / KS;
    constexpr int RPT  = CIN / 64;                    // chunks per tap
    constexpr int RSH  = (RPT==1?0:RPT==2?1:RPT==4?2:3);
    constexpr int WSTR = CIN * 16;                    // prepped weight row
    constexpr int TPR  = 256 / COB;                   // threads per W row
    constexpr int NU4  = 8 / TPR;                     // uint4 per W part

    __shared__ unsigned long long Xs[SPT*17];
    __shared__ unsigned long long Wls[COB*17];

    const int t   = threadIdx.x;
    const int bx  = blockIdx.x;
    const int cob = blockIdx.y;
    const int bz  = blockIdx.z;
    const int par = DEC ? (bz & 3) : 0;
    const int ks  = DEC ? (bz >> 2) : bz;
    const int poh = par >> 1, pw = par & 1;

    // X-stage: thread t owns LDS row t (SPT==256)
    const int gsp_s = bx*SPT + t;
    const int img_s = gsp_s / (OHo*OWo);
    const int r_s   = gsp_s % (OHo*OWo);
    const int oy_s  = r_s / OWo;
    const int ox_s  = r_s % OWo;

    // W-stage mapping
    const int wco   = t / TPR;
    const int wpart = t % TPR;
    const f16* wbase = wp + (size_t)(cob*COB + wco)*WSTR + wpart*(64/TPR);

    // compute mapping
    const int wave = t >> 6, lane = t & 63, half = lane >> 5, l31 = lane & 31;
    const int co_w = (wave >> 1) * (CO_FR*32);
    const int sp_w = (wave & 1) * 128;

    f32x16 acc[CO_FR][4];
    #pragma unroll
    for (int i = 0; i < CO_FR; ++i)
        #pragma unroll
        for (int b = 0; b < 4; ++b)
            #pragma unroll
            for (int r = 0; r < 16; ++r) acc[i][b][r] = 0.f;

    for (int cc = 0; cc < CH; ++cc) {
        const int gc  = ks*CH + cc;
        const int tap = gc >> RSH;
        const int ci0 = (gc & (RPT-1)) << 6;
        int kh, kw, ih, iw;
        if (DEC) {
            const int t2h = tap >> 1, t2w = tap & 1;
            kh = (1-poh) + 2*t2h; kw = (1-pw) + 2*t2w;
            ih = oy_s + poh - t2h; iw = ox_s + pw - t2w;
        } else {
            kh = tap >> 2; kw = tap & 3;
            ih = 2*oy_s - 1 + kh; iw = 2*ox_s - 1 + kw;
        }
        const int woff = (kh*4 + kw)*CIN + ci0;

        if (cc) __syncthreads();
        // ---- stage W: COB rows x 64 f16 ----
        {
            const uint4* src = (const uint4*)(wbase + woff);
            #pragma unroll
            for (int j = 0; j < NU4; ++j) {
                Q16 v; v.q = src[j];
                const int u0 = wco*17 + wpart*(NU4*2) + j*2;
                Wls[u0]   = v.u[0];
                Wls[u0+1] = v.u[1];
            }
        }
        // ---- stage X: SPT rows x 64 f16 ----
        {
            const bool ok = (unsigned)ih < (unsigned)IH && (unsigned)iw < (unsigned)IW;
            const int u0 = t*17;
            if (ok) {
                const uint4* src = (const uint4*)
                    (xin + ((size_t)(img_s*IH + ih)*IW + iw)*CIN + ci0);
                #pragma unroll
                for (int j = 0; j < 8; ++j) {
                    Q16 v; v.q = src[j];
                    Xs[u0 + j*2]   = v.u[0];
                    Xs[u0 + j*2+1] = v.u[1];
                }
            } else {
                #pragma unroll
                for (int j = 0; j < 16; ++j) Xs[u0 + j] = 0ull;
            }
        }
        __syncthreads();

        // ---- 4 k-steps of 16 ----
        #pragma unroll
        for (int kk = 0; kk < 4; ++kk) {
            const int uo = kk*4 + 2*half;
            f16x8 af[CO_FR], bf[4];
            #pragma unroll
            for (int i = 0; i < CO_FR; ++i) {
                U64x2 u; const int rw = (co_w + i*32 + l31)*17 + uo;
                u.u[0] = Wls[rw]; u.u[1] = Wls[rw+1]; af[i] = u.v;
            }
            #pragma unroll
            for (int b = 0; b < 4; ++b) {
                U64x2 u; const int rx = (sp_w + b*32 + l31)*17 + uo;
                u.u[0] = Xs[rx]; u.u[1] = Xs[rx+1]; bf[b] = u.v;
            }
            #pragma unroll
            for (int i = 0; i < CO_FR; ++i)
                #pragma unroll
                for (int b = 0; b < 4; ++b)
                    acc[i][b] = __builtin_amdgcn_mfma_f32_32x32x16_f16(
                        af[i], bf[b], acc[i][b], 0, 0, 0);
        }
    }

    // ---- epilogue ----
    #pragma unroll
    for (int b = 0; b < 4; ++b) {
        const int n_loc = sp_w + b*32 + l31;
        const int gsp   = bx*SPT + n_loc;
        size_t base;
        if (DEC) {
            const int img = gsp / (OHo*OWo);
            const int r   = gsp % (OHo*OWo);
            const int oh  = 2*(r / OWo) + poh;
            const int ow  = 2*(r % OWo) + pw;
            base = ((size_t)(img*OH + oh)*OW + ow)*COUT + cob*COB;
        } else {
            base = (size_t)gsp*COUT + cob*COB;
        }
        #pragma unroll
        for (int i = 0; i < CO_FR; ++i) {
            #pragma unroll
            for (int q = 0; q < 4; ++q) {
                const int co_l = co_w + i*32 + q*8 + 4*half;
                if (KS == 1) {
                    P4 p;
                    #pragma unroll
                    for (int r2 = 0; r2 < 4; ++r2)
                        p.h[r2] = (_Float16)acc[i][b][q*4 + r2];
                    *(unsigned long long*)(out16 + base + co_l) = p.u;
                } else {
                    #pragma unroll
                    for (int r2 = 0; r2 < 4; ++r2)
                        atomicAdd(out32 + base + co_l + r2, acc[i][b][q*4 + r2]);
                }
            }
        }
    }
}

// ---------------------------------------------------------------------------
// Weight prep: f32 -> f16 [co][ (kh*4+kw)*CIN + ci ]  (6 fused segments)
// conv src: w[co][ci][khw]; deconv src: w[ci][co][khw].
// ---------------------------------------------------------------------------
__global__ __launch_bounds__(256) void prep_w(
    const float* __restrict__ w2, const float* __restrict__ w3,
    const float* __restrict__ w4, const float* __restrict__ dw1,
    const float* __restrict__ dw2, const float* __restrict__ dw3,
    f16* __restrict__ dst)
{
    const int e = blockIdx.x*256 + threadIdx.x;
    float v;
    if (e < 131072) {                    // w2: CIN=64
        int co = e >> 10, r = e & 1023, khw = r >> 6, ci = r & 63;
        v = w2[(co*64 + ci)*16 + khw];
    } else if (e < 655360) {             // w3: CIN=128
        int l = e - 131072;
        int co = l >> 11, r = l & 2047, khw = r >> 7, ci = r & 127;
        v = w3[(co*128 + ci)*16 + khw];
    } else if (e < 2752512) {            // w4: CIN=256
        int l = e - 655360;
        int co = l >> 12, r = l & 4095, khw = r >> 8, ci = r & 255;
        v = w4[(co*256 + ci)*16 + khw];
    } else if (e < 4849664) {            // dw1: CIN=512, COUT=256
        int l = e - 2752512;
        int co = l >> 13, r = l & 8191, khw = r >> 9, ci = r & 511;
        v = dw1[(ci*256 + co)*16 + khw];
    } else if (e < 5373952) {            // dw2: CIN=256, COUT=128
        int l = e - 4849664;
        int co = l >> 12, r = l & 4095, khw = r >> 8, ci = r & 255;
        v = dw2[(ci*128 + co)*16 + khw];
    } else {                             // dw3: CIN=128, COUT=64
        int l = e - 5373952;
        int co = l >> 11, r = l & 2047, khw = r >> 7, ci = r & 127;
        v = dw3[(ci*64 + co)*16 + khw];
    }
    dst[e] = (_Float16)v;
}

// ---------------------------------------------------------------------------
// conv1 (3->64, K=48): f32 VALU implicit GEMM (round-4 verified), f16 NHWC out
// ---------------------------------------------------------------------------
template<int CIN,int IH,int IW,int OH,int OW,int COUT,int KC,int SPT,int COB>
__global__ __launch_bounds__(256) void conv1_f32(
    const float* __restrict__ in, const float* __restrict__ w,
    f16* __restrict__ out)
{
    constexpr int KTOT = CIN * 16;
    constexpr int KPT  = KC * SPT / 256;
    constexpr int WPT  = KC * COB / 256;
    constexpr int TPC  = 256 / COB;
    constexpr int SPG  = SPT / 4;

    __shared__ float Xs[KC * SPT];
    __shared__ float Ws[KC * COB];

    const int t = threadIdx.x;
    const int sp_sub = (t % SPG) * 4;
    const int co_sub = (t / SPG) * 4;
    const int sp_g = t % SPT;
    const int kk   = t / SPT;
    const int gsp  = blockIdx.x * SPT + sp_g;
    const int n_g  = gsp / (OH * OW);
    const int rg   = gsp % (OH * OW);
    const int ih0  = 2 * (rg / OW) - 1, iw0 = 2 * (rg % OW) - 1;
    const float* inb = in + (size_t)n_g * CIN * IH * IW;
    const int co_w = t / TPC;
    const int k0w  = (t % TPC) * WPT;
    const int cob  = blockIdx.y;
    const float* wrow = w + (size_t)(cob * COB + co_w) * KTOT;

    float acc[16];
    #pragma unroll
    for (int i = 0; i < 16; ++i) acc[i] = 0.f;

    #pragma unroll
    for (int j = 0; j < WPT; ++j)
        Ws[(k0w + j) * COB + co_w] = wrow[k0w + j];
    #pragma unroll
    for (int j = 0; j < KPT; ++j) {
        int k  = kk * KPT + j;
        int ci = k >> 4, khw = k & 15;
        int ih = ih0 + (khw >> 2), iw = iw0 + (khw & 3);
        float v = 0.f;
        if ((unsigned)ih < (unsigned)IH && (unsigned)iw < (unsigned)IW)
            v = inb[((size_t)ci * IH + ih) * IW + iw];
        Xs[k * SPT + sp_g] = v;
    }
    __syncthreads();
    #pragma unroll 8
    for (int k = 0; k < KC; ++k) {
        const float4 xv = *(const float4*)&Xs[k * SPT + sp_sub];
        const float4 wv = *(const float4*)&Ws[k * COB + co_sub];
        const float x4[4] = {xv.x, xv.y, xv.z, xv.w};
        const float w4[4] = {wv.x, wv.y, wv.z, wv.w};
        #pragma unroll
        for (int a = 0; a < 4; ++a)
            #pragma unroll
            for (int b = 0; b < 4; ++b)
                acc[a*4+b] = fmaf(w4[a], x4[b], acc[a*4+b]);
    }
    const int gsp0 = blockIdx.x * SPT + sp_sub;
    #pragma unroll
    for (int a = 0; a < 4; ++a) {
        const int co = cob * COB + co_sub + a;
        #pragma unroll
        for (int b = 0; b < 4; ++b)
            out[(size_t)(gsp0 + b) * COUT + co] = (_Float16)acc[a*4+b];
    }
}

// ---------------------------------------------------------------------------
// deconv4 (64->3) + tanh: f32 VALU GEMM, f16 NHWC in, f32 NCHW out
// ---------------------------------------------------------------------------
template<int CIN,int IH,int IW,int OH,int OW,int COUT,int KC,int SPT,int COB>
__global__ __launch_bounds__(256) void deconv4_tanh(
    const f16* __restrict__ in, const float* __restrict__ w,
    float* __restrict__ out)
{
    constexpr int KTOT = CIN * 4;
    constexpr int CHUNKS = KTOT / KC;
    constexpr int KPT  = KC * SPT / 256;
    constexpr int WPT  = KC * COB / 256;
    constexpr int TPC  = 256 / COB;
    constexpr int SPG  = SPT / 4;
    constexpr int OHh = OH/2, OWh = OW/2;

    __shared__ float Xs[KC * SPT];
    __shared__ float Ws[KC * COB];

    const int t = threadIdx.x;
    const int poh = blockIdx.z >> 1, pw = blockIdx.z & 1;
    const int khp = 1 - poh, kwp = 1 - pw;
    const int sp_sub = (t % SPG) * 4;
    const int co_sub = (t / SPG) * 4;
    const int sp_g = t % SPT;
    const int kk   = t / SPT;
    const int gsp  = blockIdx.x * SPT + sp_g;
    const int n_g  = gsp / (OHh * OWh);
    const int rg   = gsp % (OHh * OWh);
    const int ohh  = rg / OWh, oww = rg % OWh;
    const int co_w = t / TPC;
    const int k0w  = (t % TPC) * WPT;
    const int cob  = blockIdx.y;
    const int cog  = cob * COB + co_w;

    float acc[16];
    #pragma unroll
    for (int i = 0; i < 16; ++i) acc[i] = 0.f;

    for (int c = 0; c < CHUNKS; ++c) {
        if (c) __syncthreads();
        #pragma unroll
        for (int j = 0; j < WPT; ++j) {
            int k = k0w + j, kg = c * KC + k;
            int ci = kg >> 2, tap = kg & 3;
            float wv = 0.f;
            if (cog < COUT)
                wv = w[((size_t)ci * COUT + cog) * 16
                       + (khp + 2*(tap>>1))*4 + (kwp + 2*(tap&1))];
            Ws[k * COB + co_w] = wv;
        }
        #pragma unroll
        for (int j = 0; j < KPT; ++j) {
            int k = kk * KPT + j, kg = c * KC + k;
            int ci = kg >> 2, tap = kg & 3;
            int ih = ohh + poh - (tap >> 1);
            int iw = oww + pw  - (tap & 1);
            float v = 0.f;
            if ((unsigned)ih < (unsigned)IH && (unsigned)iw < (unsigned)IW)
                v = (float)in[((size_t)(n_g*IH + ih)*IW + iw)*CIN + ci];
            Xs[k * SPT + sp_g] = v;
        }
        __syncthreads();
        #pragma unroll 8
        for (int k = 0; k < KC; ++k) {
            const float4 xv = *(const float4*)&Xs[k * SPT + sp_sub];
            const float4 wv = *(const float4*)&Ws[k * COB + co_sub];
            const float x4[4] = {xv.x, xv.y, xv.z, xv.w};
            const float w4[4] = {wv.x, wv.y, wv.z, wv.w};
            #pragma unroll
            for (int a = 0; a < 4; ++a)
                #pragma unroll
                for (int b = 0; b < 4; ++b)
                    acc[a*4+b] = fmaf(w4[a], x4[b], acc[a*4+b]);
        }
    }
    const int gsp0 = blockIdx.x * SPT + sp_sub;
    const int n0   = gsp0 / (OHh * OWh);
    const int r0   = gsp0 % (OHh * OWh);
    const int ohh0 = r0 / OWh, oww0 = r0 % OWh;
    const int oh0  = 2 * ohh0 + poh;
    #pragma unroll
    for (int a = 0; a < 4; ++a) {
        const int co = cob * COB + co_sub + a;
        if (co < COUT) {
            float* ob = out + (((size_t)n0 * COUT + co) * OH + oh0) * OW;
            #pragma unroll
            for (int b = 0; b < 4; ++b)
                ob[2*(oww0 + b) + pw] = tanhf(acc[a*4+b]);
        }
    }
}

// ---------------------------------------------------------------------------
// BN: partial stats (NHWC, 64-channel coalesced), finalize, fused affine+act
// ---------------------------------------------------------------------------
template<typename T>
__global__ __launch_bounds__(256) void bn_partial(
    const T* __restrict__ x, float* __restrict__ psum, float* __restrict__ psq,
    int C, int rowsPerS, int S)
{
    const int s = blockIdx.x;
    const int c = (blockIdx.y << 6) + (threadIdx.x & 63);
    float a = 0.f, q = 0.f;
    const int rEnd = (s + 1) * rowsPerS;
    for (int r = s*rowsPerS + (threadIdx.x >> 6); r < rEnd; r += 4) {
        float v = (float)x[(size_t)r * C + c];
        a += v; q += v * v;
    }
    __shared__ float ls[256], lq[256];
    ls[threadIdx.x] = a; lq[threadIdx.x] = q;
    __syncthreads();
    if (threadIdx.x < 64) {
        a = ls[threadIdx.x] + ls[threadIdx.x+64] + ls[threadIdx.x+128] + ls[threadIdx.x+192];
        q = lq[threadIdx.x] + lq[threadIdx.x+64] + lq[threadIdx.x+128] + lq[threadIdx.x+192];
        psum[c * S + s] = a; psq[c * S + s] = q;
    }
}

__global__ __launch_bounds__(256) void bn_finalize(
    const float* __restrict__ psum, const float* __restrict__ psq,
    const float* __restrict__ gamma, const float* __restrict__ beta,
    float* __restrict__ scale, float* __restrict__ shift,
    int C, int S, float inv_count)
{
    int c = blockIdx.x * 256 + threadIdx.x;
    if (c >= C) return;
    float s = 0.f, q = 0.f;
    for (int i = 0; i < S; ++i) { s += psum[c*S + i]; q += psq[c*S + i]; }
    float m   = s * inv_count;
    float var = q * inv_count - m * m;
    var = var < 0.f ? 0.f : var;
    float sc = gamma[c] * rsqrtf(var + 1e-5f);
    scale[c] = sc;
    shift[c] = beta[c] - m * sc;
}

__global__ __launch_bounds__(256) void bn_act16(
    f16* __restrict__ x, const float* __restrict__ sc, const float* __restrict__ sh,
    int Cmask, float slope)
{
    const size_t i8 = ((size_t)blockIdx.x*256 + threadIdx.x) * 8;
    union { uint4 u; _Float16 h[8]; } a;
    a.u = *(const uint4*)(x + i8);
    const int c0 = (int)(i8 & (size_t)Cmask);
    #pragma unroll
    for (int j = 0; j < 8; ++j) {
        float v = (float)a.h[j] * sc[c0+j] + sh[c0+j];
        a.h[j] = (_Float16)(v >= 0.f ? v : slope * v);
    }
    *(uint4*)(x + i8) = a.u;
}

__global__ __launch_bounds__(256) void bn_act32(
    const float* __restrict__ x, f16* __restrict__ y,
    const float* __restrict__ sc, const float* __restrict__ sh,
    int Cmask, float slope)
{
    const size_t i8 = ((size_t)blockIdx.x*256 + threadIdx.x) * 8;
    float4 v0 = *(const float4*)(x + i8);
    float4 v1 = *(const float4*)(x + i8 + 4);
    const float xv[8] = {v0.x,v0.y,v0.z,v0.w,v1.x,v1.y,v1.z,v1.w};
    union { uint4 u; _Float16 h[8]; } a;
    const int c0 = (int)(i8 & (size_t)Cmask);
    #pragma unroll
    for (int j = 0; j < 8; ++j) {
        float v = xv[j] * sc[c0+j] + sh[c0+j];
        a.h[j] = (_Float16)(v >= 0.f ? v : slope * v);
    }
    *(uint4*)(y + i8) = a.u;
}

// Per-channel Linear(16,16), NHWC f16 in/out
__global__ __launch_bounds__(256) void chanlin16(
    const f16* __restrict__ in, const float* __restrict__ w,
    const float* __restrict__ bias, f16* __restrict__ out)
{
    const int i = blockIdx.x*256 + threadIdx.x;     // 2,097,152 total
    const int c  = i & 511;
    const int bt = i >> 9;
    const int b  = bt >> 4, tt = bt & 15;
    const f16* src = in + ((size_t)b*16)*512 + c;
    const float* wr = w + ((size_t)c*16 + tt)*16;
    float acc = bias[c*16 + tt];
    #pragma unroll
    for (int s = 0; s < 16; ++s)
        acc = fmaf((float)src[s*512], wr[s], acc);
    out[i] = (_Float16)acc;
}

extern "C" void kernel_launch(void* const* d_in, const int* in_sizes, int n_in,
                              void* d_out, int out_size, void* d_ws, size_t ws_size,
                              hipStream_t stream)
{
    const float* x   = (const float*)d_in[0];
    const float* w1  = (const float*)d_in[1];
    const float* w2  = (const float*)d_in[2];
    const float* w3  = (const float*)d_in[3];
    const float* w4  = (const float*)d_in[4];
    const float* g1  = (const float*)d_in[5];
    const float* b1  = (const float*)d_in[6];
    const float* g2  = (const float*)d_in[7];
    const float* b2  = (const float*)d_in[8];
    const float* g3  = (const float*)d_in[9];
    const float* b3  = (const float*)d_in[10];
    const float* g4  = (const float*)d_in[11];
    const float* b4  = (const float*)d_in[12];
    const float* cww = (const float*)d_in[13];
    const float* cwb = (const float*)d_in[14];
    const float* dw1 = (const float*)d_in[15];
    const float* dw2 = (const float*)d_in[16];
    const float* dw3 = (const float*)d_in[17];
    const float* dw4 = (const float*)d_in[18];
    const float* dg1 = (const float*)d_in[19];
    const float* db1 = (const float*)d_in[20];
    const float* dg2 = (const float*)d_in[21];
    const float* db2 = (const float*)d_in[22];
    const float* dg3 = (const float*)d_in[23];
    const float* db3 = (const float*)d_in[24];

    // ws layout (bytes): psum 64K | psq 64K | scale 2K | shift 2K | pad->256K
    // slotA f16 33.55MB | slotB f16 33.55MB | scratch f32 16.78MB | wprep 11MB
    char* WS = (char*)d_ws;
    float* psum  = (float*)WS;
    float* psq   = (float*)(WS + 65536);
    float* scale = (float*)(WS + 131072);
    float* shift = (float*)(WS + 133120);
    f16* slotA   = (f16*)(WS + 262144);
    f16* slotB   = (f16*)(WS + 262144 + 33554432);
    float* scr   = (float*)(WS + 67371008);
    f16* wprep   = (f16*)(WS + 84148224);

    // weight prep (5,505,024 f16)
    prep_w<<<21504, 256, 0, stream>>>(w2, w3, w4, dw1, dw2, dw3, wprep);

    // ---- conv1 (f32 VALU), out f16 NHWC in slotB ----
    conv1_f32<3,64,64,32,32,64, 48,128,32><<<dim3(2048,2), 256, 0, stream>>>(x, w1, slotB);
    bn_partial<f16><<<dim3(256,1), 256, 0, stream>>>(slotB, psum, psq, 64, 1024, 256);
    bn_finalize<<<1, 256, 0, stream>>>(psum, psq, g1, b1, scale, shift, 64, 256, 1.f/262144.f);
    bn_act16<<<8192, 256, 0, stream>>>(slotB, scale, shift, 63, 0.2f);

    // ---- conv2 ----
    mfma_conv<64,32,32,16,16,128, 128,256,1,2,false><<<dim3(256,1,1), 256, 0, stream>>>(
        slotB, wprep, slotA, nullptr);
    bn_partial<f16><<<dim3(128,2), 256, 0, stream>>>(slotA, psum, psq, 128, 512, 128);
    bn_finalize<<<1, 256, 0, stream>>>(psum, psq, g2, b2, scale, shift, 128, 128, 1.f/65536.f);
    bn_act16<<<4096, 256, 0, stream>>>(slotA, scale, shift, 127, 0.2f);

    // ---- conv3 (K-split 2, f32 atomics) ----
    hipMemsetAsync(scr, 0, 16777216, stream);
    mfma_conv<128,16,16,8,8,256, 128,256,2,2,false><<<dim3(64,2,2), 256, 0, stream>>>(
        slotA, wprep + 131072, nullptr, scr);
    bn_partial<float><<<dim3(64,4), 256, 0, stream>>>(scr, psum, psq, 256, 256, 64);
    bn_finalize<<<1, 256, 0, stream>>>(psum, psq, g3, b3, scale, shift, 256, 64, 1.f/16384.f);
    bn_act32<<<2048, 256, 0, stream>>>(scr, slotB, scale, shift, 255, 0.2f);

    // ---- conv4 (K-split 4) ----
    hipMemsetAsync(scr, 0, 8388608, stream);
    mfma_conv<256,8,8,4,4,512, 128,256,4,2,false><<<dim3(16,4,4), 256, 0, stream>>>(
        slotB, wprep + 655360, nullptr, scr);
    bn_partial<float><<<dim3(32,8), 256, 0, stream>>>(scr, psum, psq, 512, 128, 32);
    bn_finalize<<<2, 256, 0, stream>>>(psum, psq, g4, b4, scale, shift, 512, 32, 1.f/4096.f);
    bn_act32<<<1024, 256, 0, stream>>>(scr, slotA, scale, shift, 511, 0.2f);

    // ---- channel-wise linear ----
    chanlin16<<<8192, 256, 0, stream>>>(slotA, cww, cwb, slotB);

    // ---- deconv1 (K-split 2) ----
    hipMemsetAsync(scr, 0, 16777216, stream);
    mfma_conv<512,4,4,8,8,256, 128,256,2,2,true><<<dim3(16,2,8), 256, 0, stream>>>(
        slotB, wprep + 2752512, nullptr, scr);
    bn_partial<float><<<dim3(64,4), 256, 0, stream>>>(scr, psum, psq, 256, 256, 64);
    bn_finalize<<<1, 256, 0, stream>>>(psum, psq, dg1, db1, scale, shift, 256, 64, 1.f/16384.f);
    bn_act32<<<2048, 256, 0, stream>>>(scr, slotA, scale, shift, 255, 0.f);

    // ---- deconv2 ----
    mfma_conv<256,8,8,16,16,128, 128,256,1,2,true><<<dim3(64,1,4), 256, 0, stream>>>(
        slotA, wprep + 4849664, slotB, nullptr);
    bn_partial<f16><<<dim3(128,2), 256, 0, stream>>>(slotB, psum, psq, 128, 512, 128);
    bn_finalize<<<1, 256, 0, stream>>>(psum, psq, dg2, db2, scale, shift, 128, 128, 1.f/65536.f);
    bn_act16<<<4096, 256, 0, stream>>>(slotB, scale, shift, 127, 0.f);

    // ---- deconv3 (COB=64, CO_FR=1) ----
    mfma_conv<128,16,16,32,32,64, 64,256,1,1,true><<<dim3(256,1,4), 256, 0, stream>>>(
        slotB, wprep + 5373952, slotA, nullptr);
    bn_partial<f16><<<dim3(256,1), 256, 0, stream>>>(slotA, psum, psq, 64, 1024, 256);
    bn_finalize<<<1, 256, 0, stream>>>(psum, psq, dg3, db3, scale, shift, 64, 256, 1.f/262144.f);
    bn_act16<<<8192, 256, 0, stream>>>(slotA, scale, shift, 63, 0.f);

    // ---- deconv4 + tanh (f32 VALU, f16 NHWC in, f32 NCHW out) ----
    deconv4_tanh<64,32,32,64,64,3, 32,256,16><<<dim3(1024,1,4), 256, 0, stream>>>(
        slotA, dw4, (float*)d_out);
}

// Round 6
// 1654.434 us; speedup vs baseline: 16.5108x; 1.5701x over previous
//
#include <hip/hip_runtime.h>
#include <math.h>

typedef _Float16 f16;
typedef __attribute__((ext_vector_type(8))) _Float16 f16x8;
typedef __attribute__((ext_vector_type(16))) float f32x16;

union U64x2 { unsigned long long u[2]; f16x8 v; };
union Q16   { uint4 q; unsigned long long u[2]; };
union P4    { _Float16 h[4]; unsigned long long u; };

// ===========================================================================
// fp16 MFMA implicit-GEMM conv/deconv (k4 s2 p1), NHWC activations.
// (unchanged from round 5 — verified correct)
// ===========================================================================
template<int CIN,int IH,int IW,int OH,int OW,int COUT,int COB,int SPT,int KS,
         int CO_FR,bool DEC>
__global__ __launch_bounds__(256,2) void mfma_conv(
    const f16* __restrict__ xin, const f16* __restrict__ wp,
    f16* __restrict__ out16, float* __restrict__ out32)
{
    constexpr int OHo  = DEC ? OH/2 : OH;
    constexpr int OWo  = DEC ? OW/2 : OW;
    constexpr int KTOT = CIN * (DEC ? 4 : 16);
    constexpr int CH   = (KTOT/64) / KS;
    constexpr int RPT  = CIN / 64;
    constexpr int RSH  = (RPT==1?0:RPT==2?1:RPT==4?2:3);
    constexpr int WSTR = CIN * 16;
    constexpr int TPR  = 256 / COB;
    constexpr int NU4  = 8 / TPR;

    __shared__ unsigned long long Xs[SPT*17];
    __shared__ unsigned long long Wls[COB*17];

    const int t   = threadIdx.x;
    const int bx  = blockIdx.x;
    const int cob = blockIdx.y;
    const int bz  = blockIdx.z;
    const int par = DEC ? (bz & 3) : 0;
    const int ks  = DEC ? (bz >> 2) : bz;
    const int poh = par >> 1, pw = par & 1;

    const int gsp_s = bx*SPT + t;
    const int img_s = gsp_s / (OHo*OWo);
    const int r_s   = gsp_s % (OHo*OWo);
    const int oy_s  = r_s / OWo;
    const int ox_s  = r_s % OWo;

    const int wco   = t / TPR;
    const int wpart = t % TPR;
    const f16* wbase = wp + (size_t)(cob*COB + wco)*WSTR + wpart*(64/TPR);

    const int wave = t >> 6, lane = t & 63, half = lane >> 5, l31 = lane & 31;
    const int co_w = (wave >> 1) * (CO_FR*32);
    const int sp_w = (wave & 1) * 128;

    f32x16 acc[CO_FR][4];
    #pragma unroll
    for (int i = 0; i < CO_FR; ++i)
        #pragma unroll
        for (int b = 0; b < 4; ++b)
            #pragma unroll
            for (int r = 0; r < 16; ++r) acc[i][b][r] = 0.f;

    for (int cc = 0; cc < CH; ++cc) {
        const int gc  = ks*CH + cc;
        const int tap = gc >> RSH;
        const int ci0 = (gc & (RPT-1)) << 6;
        int kh, kw, ih, iw;
        if (DEC) {
            const int t2h = tap >> 1, t2w = tap & 1;
            kh = (1-poh) + 2*t2h; kw = (1-pw) + 2*t2w;
            ih = oy_s + poh - t2h; iw = ox_s + pw - t2w;
        } else {
            kh = tap >> 2; kw = tap & 3;
            ih = 2*oy_s - 1 + kh; iw = 2*ox_s - 1 + kw;
        }
        const int woff = (kh*4 + kw)*CIN + ci0;

        if (cc) __syncthreads();
        {
            const uint4* src = (const uint4*)(wbase + woff);
            #pragma unroll
            for (int j = 0; j < NU4; ++j) {
                Q16 v; v.q = src[j];
                const int u0 = wco*17 + wpart*(NU4*2) + j*2;
                Wls[u0]   = v.u[0];
                Wls[u0+1] = v.u[1];
            }
        }
        {
            const bool ok = (unsigned)ih < (unsigned)IH && (unsigned)iw < (unsigned)IW;
            const int u0 = t*17;
            if (ok) {
                const uint4* src = (const uint4*)
                    (xin + ((size_t)(img_s*IH + ih)*IW + iw)*CIN + ci0);
                #pragma unroll
                for (int j = 0; j < 8; ++j) {
                    Q16 v; v.q = src[j];
                    Xs[u0 + j*2]   = v.u[0];
                    Xs[u0 + j*2+1] = v.u[1];
                }
            } else {
                #pragma unroll
                for (int j = 0; j < 16; ++j) Xs[u0 + j] = 0ull;
            }
        }
        __syncthreads();

        #pragma unroll
        for (int kk = 0; kk < 4; ++kk) {
            const int uo = kk*4 + 2*half;
            f16x8 af[CO_FR], bf[4];
            #pragma unroll
            for (int i = 0; i < CO_FR; ++i) {
                U64x2 u; const int rw = (co_w + i*32 + l31)*17 + uo;
                u.u[0] = Wls[rw]; u.u[1] = Wls[rw+1]; af[i] = u.v;
            }
            #pragma unroll
            for (int b = 0; b < 4; ++b) {
                U64x2 u; const int rx = (sp_w + b*32 + l31)*17 + uo;
                u.u[0] = Xs[rx]; u.u[1] = Xs[rx+1]; bf[b] = u.v;
            }
            #pragma unroll
            for (int i = 0; i < CO_FR; ++i)
                #pragma unroll
                for (int b = 0; b < 4; ++b)
                    acc[i][b] = __builtin_amdgcn_mfma_f32_32x32x16_f16(
                        af[i], bf[b], acc[i][b], 0, 0, 0);
        }
    }

    #pragma unroll
    for (int b = 0; b < 4; ++b) {
        const int n_loc = sp_w + b*32 + l31;
        const int gsp   = bx*SPT + n_loc;
        size_t base;
        if (DEC) {
            const int img = gsp / (OHo*OWo);
            const int r   = gsp % (OHo*OWo);
            const int oh  = 2*(r / OWo) + poh;
            const int ow  = 2*(r % OWo) + pw;
            base = ((size_t)(img*OH + oh)*OW + ow)*COUT + cob*COB;
        } else {
            base = (size_t)gsp*COUT + cob*COB;
        }
        #pragma unroll
        for (int i = 0; i < CO_FR; ++i) {
            #pragma unroll
            for (int q = 0; q < 4; ++q) {
                const int co_l = co_w + i*32 + q*8 + 4*half;
                if (KS == 1) {
                    P4 p;
                    #pragma unroll
                    for (int r2 = 0; r2 < 4; ++r2)
                        p.h[r2] = (_Float16)acc[i][b][q*4 + r2];
                    *(unsigned long long*)(out16 + base + co_l) = p.u;
                } else {
                    #pragma unroll
                    for (int r2 = 0; r2 < 4; ++r2)
                        atomicAdd(out32 + base + co_l + r2, acc[i][b][q*4 + r2]);
                }
            }
        }
    }
}

// ---------------------------------------------------------------------------
// Weight prep: f32 -> f16 [co][ (kh*4+kw)*CIN + ci ]  (6 fused segments)
// ---------------------------------------------------------------------------
__global__ __launch_bounds__(256) void prep_w(
    const float* __restrict__ w2, const float* __restrict__ w3,
    const float* __restrict__ w4, const float* __restrict__ dw1,
    const float* __restrict__ dw2, const float* __restrict__ dw3,
    f16* __restrict__ dst)
{
    const int e = blockIdx.x*256 + threadIdx.x;
    float v;
    if (e < 131072) {
        int co = e >> 10, r = e & 1023, khw = r >> 6, ci = r & 63;
        v = w2[(co*64 + ci)*16 + khw];
    } else if (e < 655360) {
        int l = e - 131072;
        int co = l >> 11, r = l & 2047, khw = r >> 7, ci = r & 127;
        v = w3[(co*128 + ci)*16 + khw];
    } else if (e < 2752512) {
        int l = e - 655360;
        int co = l >> 12, r = l & 4095, khw = r >> 8, ci = r & 255;
        v = w4[(co*256 + ci)*16 + khw];
    } else if (e < 4849664) {
        int l = e - 2752512;
        int co = l >> 13, r = l & 8191, khw = r >> 9, ci = r & 511;
        v = dw1[(ci*256 + co)*16 + khw];
    } else if (e < 5373952) {
        int l = e - 4849664;
        int co = l >> 12, r = l & 4095, khw = r >> 8, ci = r & 255;
        v = dw2[(ci*128 + co)*16 + khw];
    } else {
        int l = e - 5373952;
        int co = l >> 11, r = l & 2047, khw = r >> 7, ci = r & 127;
        v = dw3[(ci*64 + co)*16 + khw];
    }
    dst[e] = (_Float16)v;
}

// ---------------------------------------------------------------------------
// conv1 (3->64, K=48): f32 VALU implicit GEMM, f16 NHWC out (unchanged)
// ---------------------------------------------------------------------------
template<int CIN,int IH,int IW,int OH,int OW,int COUT,int KC,int SPT,int COB>
__global__ __launch_bounds__(256) void conv1_f32(
    const float* __restrict__ in, const float* __restrict__ w,
    f16* __restrict__ out)
{
    constexpr int KTOT = CIN * 16;
    constexpr int KPT  = KC * SPT / 256;
    constexpr int WPT  = KC * COB / 256;
    constexpr int TPC  = 256 / COB;
    constexpr int SPG  = SPT / 4;

    __shared__ float Xs[KC * SPT];
    __shared__ float Ws[KC * COB];

    const int t = threadIdx.x;
    const int sp_sub = (t % SPG) * 4;
    const int co_sub = (t / SPG) * 4;
    const int sp_g = t % SPT;
    const int kk   = t / SPT;
    const int gsp  = blockIdx.x * SPT + sp_g;
    const int n_g  = gsp / (OH * OW);
    const int rg   = gsp % (OH * OW);
    const int ih0  = 2 * (rg / OW) - 1, iw0 = 2 * (rg % OW) - 1;
    const float* inb = in + (size_t)n_g * CIN * IH * IW;
    const int co_w = t / TPC;
    const int k0w  = (t % TPC) * WPT;
    const int cob  = blockIdx.y;
    const float* wrow = w + (size_t)(cob * COB + co_w) * KTOT;

    float acc[16];
    #pragma unroll
    for (int i = 0; i < 16; ++i) acc[i] = 0.f;

    #pragma unroll
    for (int j = 0; j < WPT; ++j)
        Ws[(k0w + j) * COB + co_w] = wrow[k0w + j];
    #pragma unroll
    for (int j = 0; j < KPT; ++j) {
        int k  = kk * KPT + j;
        int ci = k >> 4, khw = k & 15;
        int ih = ih0 + (khw >> 2), iw = iw0 + (khw & 3);
        float v = 0.f;
        if ((unsigned)ih < (unsigned)IH && (unsigned)iw < (unsigned)IW)
            v = inb[((size_t)ci * IH + ih) * IW + iw];
        Xs[k * SPT + sp_g] = v;
    }
    __syncthreads();
    #pragma unroll 8
    for (int k = 0; k < KC; ++k) {
        const float4 xv = *(const float4*)&Xs[k * SPT + sp_sub];
        const float4 wv = *(const float4*)&Ws[k * COB + co_sub];
        const float x4[4] = {xv.x, xv.y, xv.z, xv.w};
        const float w4[4] = {wv.x, wv.y, wv.z, wv.w};
        #pragma unroll
        for (int a = 0; a < 4; ++a)
            #pragma unroll
            for (int b = 0; b < 4; ++b)
                acc[a*4+b] = fmaf(w4[a], x4[b], acc[a*4+b]);
    }
    const int gsp0 = blockIdx.x * SPT + sp_sub;
    #pragma unroll
    for (int a = 0; a < 4; ++a) {
        const int co = cob * COB + co_sub + a;
        #pragma unroll
        for (int b = 0; b < 4; ++b)
            out[(size_t)(gsp0 + b) * COUT + co] = (_Float16)acc[a*4+b];
    }
}

// ---------------------------------------------------------------------------
// deconv4 (64->3) + tanh, REWRITTEN: one thread = one half-res position,
// computes the full 2x2 parity quad x 3 channels (12 outputs, 3072 FMA).
// x: f16 NHWC (n,32,32,64) read as 9 neighborhood pixels x uint4 ci-chunks
// (L1 serves the 3x overlap between neighboring lanes). Weights (64,3,4,4)
// f32 indexed wave-uniformly -> scalar loads, SGPR operands, no LDS.
// Tap algebra: out(2ohh+poh, 2oww+pw) += x[ohh+poh-t2h][oww+pw-t2w] *
//              w[ci][co][(1-poh)+2*t2h][(1-pw)+2*t2w]
// ---------------------------------------------------------------------------
__global__ __launch_bounds__(256) void deconv4_fused(
    const f16* __restrict__ xin, const float* __restrict__ w,
    float* __restrict__ out)
{
    const int T   = blockIdx.x * 256 + threadIdx.x;   // 262144 total
    const int n   = T >> 10;
    const int p   = T & 1023;
    const int ohh = p >> 5, oww = p & 31;

    float acc[12];                                     // [par*3 + co]
    #pragma unroll
    for (int i = 0; i < 12; ++i) acc[i] = 0.f;

    const f16* inb = xin + (size_t)n * (32*32*64);

    for (int c8 = 0; c8 < 8; ++c8) {                   // ci chunks of 8
        union { uint4 q; _Float16 h[8]; } xp[9];
        #pragma unroll
        for (int dy = -1; dy <= 1; ++dy)
            #pragma unroll
            for (int dx = -1; dx <= 1; ++dx) {
                const int ih = ohh + dy, iw = oww + dx;
                const int j  = (dy+1)*3 + (dx+1);
                if ((unsigned)ih < 32u && (unsigned)iw < 32u)
                    xp[j].q = *(const uint4*)(inb + ((ih*32 + iw)*64) + c8*8);
                else
                    xp[j].q = make_uint4(0u,0u,0u,0u);
            }
        #pragma unroll
        for (int cl = 0; cl < 8; ++cl) {
            const int ci = c8*8 + cl;
            float xv[9];
            #pragma unroll
            for (int j = 0; j < 9; ++j) xv[j] = (float)xp[j].h[cl];
            #pragma unroll
            for (int co = 0; co < 3; ++co) {
                const float* wr = w + (ci*3 + co)*16;  // uniform -> s_load
                #pragma unroll
                for (int par = 0; par < 4; ++par) {
                    const int poh = par >> 1, pw = par & 1;
                    #pragma unroll
                    for (int tap = 0; tap < 4; ++tap) {
                        const int t2h = tap >> 1, t2w = tap & 1;
                        const int kh = (1-poh) + 2*t2h, kw = (1-pw) + 2*t2w;
                        const int jx = (poh - t2h + 1)*3 + (pw - t2w + 1);
                        acc[par*3+co] = fmaf(xv[jx], wr[kh*4+kw], acc[par*3+co]);
                    }
                }
            }
        }
    }
    #pragma unroll
    for (int par = 0; par < 4; ++par) {
        const int poh = par >> 1, pw = par & 1;
        const int oh = 2*ohh + poh, ow = 2*oww + pw;
        #pragma unroll
        for (int co = 0; co < 3; ++co)
            out[(((size_t)n*3 + co)*64 + oh)*64 + ow] = tanhf(acc[par*3+co]);
    }
}

// ---------------------------------------------------------------------------
// BN: partial stats (NHWC), finalize, fused affine+act  (unchanged)
// ---------------------------------------------------------------------------
template<typename T>
__global__ __launch_bounds__(256) void bn_partial(
    const T* __restrict__ x, float* __restrict__ psum, float* __restrict__ psq,
    int C, int rowsPerS, int S)
{
    const int s = blockIdx.x;
    const int c = (blockIdx.y << 6) + (threadIdx.x & 63);
    float a = 0.f, q = 0.f;
    const int rEnd = (s + 1) * rowsPerS;
    for (int r = s*rowsPerS + (threadIdx.x >> 6); r < rEnd; r += 4) {
        float v = (float)x[(size_t)r * C + c];
        a += v; q += v * v;
    }
    __shared__ float ls[256], lq[256];
    ls[threadIdx.x] = a; lq[threadIdx.x] = q;
    __syncthreads();
    if (threadIdx.x < 64) {
        a = ls[threadIdx.x] + ls[threadIdx.x+64] + ls[threadIdx.x+128] + ls[threadIdx.x+192];
        q = lq[threadIdx.x] + lq[threadIdx.x+64] + lq[threadIdx.x+128] + lq[threadIdx.x+192];
        psum[c * S + s] = a; psq[c * S + s] = q;
    }
}

__global__ __launch_bounds__(256) void bn_finalize(
    const float* __restrict__ psum, const float* __restrict__ psq,
    const float* __restrict__ gamma, const float* __restrict__ beta,
    float* __restrict__ scale, float* __restrict__ shift,
    int C, int S, float inv_count)
{
    int c = blockIdx.x * 256 + threadIdx.x;
    if (c >= C) return;
    float s = 0.f, q = 0.f;
    for (int i = 0; i < S; ++i) { s += psum[c*S + i]; q += psq[c*S + i]; }
    float m   = s * inv_count;
    float var = q * inv_count - m * m;
    var = var < 0.f ? 0.f : var;
    float sc = gamma[c] * rsqrtf(var + 1e-5f);
    scale[c] = sc;
    shift[c] = beta[c] - m * sc;
}

__global__ __launch_bounds__(256) void bn_act16(
    f16* __restrict__ x, const float* __restrict__ sc, const float* __restrict__ sh,
    int Cmask, float slope)
{
    const size_t i8 = ((size_t)blockIdx.x*256 + threadIdx.x) * 8;
    union { uint4 u; _Float16 h[8]; } a;
    a.u = *(const uint4*)(x + i8);
    const int c0 = (int)(i8 & (size_t)Cmask);
    #pragma unroll
    for (int j = 0; j < 8; ++j) {
        float v = (float)a.h[j] * sc[c0+j] + sh[c0+j];
        a.h[j] = (_Float16)(v >= 0.f ? v : slope * v);
    }
    *(uint4*)(x + i8) = a.u;
}

__global__ __launch_bounds__(256) void bn_act32(
    const float* __restrict__ x, f16* __restrict__ y,
    const float* __restrict__ sc, const float* __restrict__ sh,
    int Cmask, float slope)
{
    const size_t i8 = ((size_t)blockIdx.x*256 + threadIdx.x) * 8;
    float4 v0 = *(const float4*)(x + i8);
    float4 v1 = *(const float4*)(x + i8 + 4);
    const float xv[8] = {v0.x,v0.y,v0.z,v0.w,v1.x,v1.y,v1.z,v1.w};
    union { uint4 u; _Float16 h[8]; } a;
    const int c0 = (int)(i8 & (size_t)Cmask);
    #pragma unroll
    for (int j = 0; j < 8; ++j) {
        float v = xv[j] * sc[c0+j] + sh[c0+j];
        a.h[j] = (_Float16)(v >= 0.f ? v : slope * v);
    }
    *(uint4*)(y + i8) = a.u;
}

// Per-channel Linear(16,16), NHWC f16 in/out (unchanged)
__global__ __launch_bounds__(256) void chanlin16(
    const f16* __restrict__ in, const float* __restrict__ w,
    const float* __restrict__ bias, f16* __restrict__ out)
{
    const int i = blockIdx.x*256 + threadIdx.x;
    const int c  = i & 511;
    const int bt = i >> 9;
    const int b  = bt >> 4, tt = bt & 15;
    const f16* src = in + ((size_t)b*16)*512 + c;
    const float* wr = w + ((size_t)c*16 + tt)*16;
    float acc = bias[c*16 + tt];
    #pragma unroll
    for (int s = 0; s < 16; ++s)
        acc = fmaf((float)src[s*512], wr[s], acc);
    out[i] = (_Float16)acc;
}

extern "C" void kernel_launch(void* const* d_in, const int* in_sizes, int n_in,
                              void* d_out, int out_size, void* d_ws, size_t ws_size,
                              hipStream_t stream)
{
    const float* x   = (const float*)d_in[0];
    const float* w1  = (const float*)d_in[1];
    const float* w2  = (const float*)d_in[2];
    const float* w3  = (const float*)d_in[3];
    const float* w4  = (const float*)d_in[4];
    const float* g1  = (const float*)d_in[5];
    const float* b1  = (const float*)d_in[6];
    const float* g2  = (const float*)d_in[7];
    const float* b2  = (const float*)d_in[8];
    const float* g3  = (const float*)d_in[9];
    const float* b3  = (const float*)d_in[10];
    const float* g4  = (const float*)d_in[11];
    const float* b4  = (const float*)d_in[12];
    const float* cww = (const float*)d_in[13];
    const float* cwb = (const float*)d_in[14];
    const float* dw1 = (const float*)d_in[15];
    const float* dw2 = (const float*)d_in[16];
    const float* dw3 = (const float*)d_in[17];
    const float* dw4 = (const float*)d_in[18];
    const float* dg1 = (const float*)d_in[19];
    const float* db1 = (const float*)d_in[20];
    const float* dg2 = (const float*)d_in[21];
    const float* db2 = (const float*)d_in[22];
    const float* dg3 = (const float*)d_in[23];
    const float* db3 = (const float*)d_in[24];

    char* WS = (char*)d_ws;
    float* psum  = (float*)WS;
    float* psq   = (float*)(WS + 65536);
    float* scale = (float*)(WS + 131072);
    float* shift = (float*)(WS + 133120);
    f16* slotA   = (f16*)(WS + 262144);
    f16* slotB   = (f16*)(WS + 262144 + 33554432);
    float* scr   = (float*)(WS + 67371008);
    f16* wprep   = (f16*)(WS + 84148224);

    prep_w<<<21504, 256, 0, stream>>>(w2, w3, w4, dw1, dw2, dw3, wprep);

    // ---- conv1 (f32 VALU), out f16 NHWC in slotB ----
    conv1_f32<3,64,64,32,32,64, 48,128,32><<<dim3(2048,2), 256, 0, stream>>>(x, w1, slotB);
    bn_partial<f16><<<dim3(256,1), 256, 0, stream>>>(slotB, psum, psq, 64, 1024, 256);
    bn_finalize<<<1, 256, 0, stream>>>(psum, psq, g1, b1, scale, shift, 64, 256, 1.f/262144.f);
    bn_act16<<<8192, 256, 0, stream>>>(slotB, scale, shift, 63, 0.2f);

    // ---- conv2 ----
    mfma_conv<64,32,32,16,16,128, 128,256,1,2,false><<<dim3(256,1,1), 256, 0, stream>>>(
        slotB, wprep, slotA, nullptr);
    bn_partial<f16><<<dim3(128,2), 256, 0, stream>>>(slotA, psum, psq, 128, 512, 128);
    bn_finalize<<<1, 256, 0, stream>>>(psum, psq, g2, b2, scale, shift, 128, 128, 1.f/65536.f);
    bn_act16<<<4096, 256, 0, stream>>>(slotA, scale, shift, 127, 0.2f);

    // ---- conv3 (K-split 2) ----
    hipMemsetAsync(scr, 0, 16777216, stream);
    mfma_conv<128,16,16,8,8,256, 128,256,2,2,false><<<dim3(64,2,2), 256, 0, stream>>>(
        slotA, wprep + 131072, nullptr, scr);
    bn_partial<float><<<dim3(64,4), 256, 0, stream>>>(scr, psum, psq, 256, 256, 64);
    bn_finalize<<<1, 256, 0, stream>>>(psum, psq, g3, b3, scale, shift, 256, 64, 1.f/16384.f);
    bn_act32<<<2048, 256, 0, stream>>>(scr, slotB, scale, shift, 255, 0.2f);

    // ---- conv4 (K-split 4) ----
    hipMemsetAsync(scr, 0, 8388608, stream);
    mfma_conv<256,8,8,4,4,512, 128,256,4,2,false><<<dim3(16,4,4), 256, 0, stream>>>(
        slotB, wprep + 655360, nullptr, scr);
    bn_partial<float><<<dim3(32,8), 256, 0, stream>>>(scr, psum, psq, 512, 128, 32);
    bn_finalize<<<2, 256, 0, stream>>>(psum, psq, g4, b4, scale, shift, 512, 32, 1.f/4096.f);
    bn_act32<<<1024, 256, 0, stream>>>(scr, slotA, scale, shift, 511, 0.2f);

    // ---- channel-wise linear ----
    chanlin16<<<8192, 256, 0, stream>>>(slotA, cww, cwb, slotB);

    // ---- deconv1 (K-split 2) ----
    hipMemsetAsync(scr, 0, 16777216, stream);
    mfma_conv<512,4,4,8,8,256, 128,256,2,2,true><<<dim3(16,2,8), 256, 0, stream>>>(
        slotB, wprep + 2752512, nullptr, scr);
    bn_partial<float><<<dim3(64,4), 256, 0, stream>>>(scr, psum, psq, 256, 256, 64);
    bn_finalize<<<1, 256, 0, stream>>>(psum, psq, dg1, db1, scale, shift, 256, 64, 1.f/16384.f);
    bn_act32<<<2048, 256, 0, stream>>>(scr, slotA, scale, shift, 255, 0.f);

    // ---- deconv2 ----
    mfma_conv<256,8,8,16,16,128, 128,256,1,2,true><<<dim3(64,1,4), 256, 0, stream>>>(
        slotA, wprep + 4849664, slotB, nullptr);
    bn_partial<f16><<<dim3(128,2), 256, 0, stream>>>(slotB, psum, psq, 128, 512, 128);
    bn_finalize<<<1, 256, 0, stream>>>(psum, psq, dg2, db2, scale, shift, 128, 128, 1.f/65536.f);
    bn_act16<<<4096, 256, 0, stream>>>(slotB, scale, shift, 127, 0.f);

    // ---- deconv3 (COB=64, CO_FR=1) ----
    mfma_conv<128,16,16,32,32,64, 64,256,1,1,true><<<dim3(256,1,4), 256, 0, stream>>>(
        slotB, wprep + 5373952, slotA, nullptr);
    bn_partial<f16><<<dim3(256,1), 256, 0, stream>>>(slotA, psum, psq, 64, 1024, 256);
    bn_finalize<<<1, 256, 0, stream>>>(psum, psq, dg3, db3, scale, shift, 64, 256, 1.f/262144.f);
    bn_act16<<<8192, 256, 0, stream>>>(slotA, scale, shift, 63, 0.f);

    // ---- deconv4 + tanh (fused gather, no LDS) ----
    deconv4_fused<<<1024, 256, 0, stream>>>(slotA, dw4, (float*)d_out);
}

// Round 7
// 1029.035 us; speedup vs baseline: 26.5453x; 1.6078x over previous
//
#include <hip/hip_runtime.h>
#include <math.h>

typedef _Float16 f16;
typedef __attribute__((ext_vector_type(8))) _Float16 f16x8;
typedef __attribute__((ext_vector_type(16))) float f32x16;

union U64x2 { unsigned long long u[2]; f16x8 v; };
union Q16   { uint4 q; unsigned long long u[2]; };

constexpr int ilog2c(int x) { return x <= 1 ? 0 : 1 + ilog2c(x >> 1); }

// ===========================================================================
// fp16 MFMA implicit-GEMM conv/deconv (k4 s2 p1), NHWC activations.
// A-operand = X (sp rows), B-operand = W (co cols)  =>  D: row=sp, col=co.
// Epilogue stores are lane-contiguous in co (coalesced). K-split (KS>1)
// blocks write disjoint f32 partial buffers (plain stores, no atomics);
// the BN pass sums partials. LDS rows stride 68 f16 (17 u64).
// ===========================================================================
template<int CIN,int IH,int IW,int OH,int OW,int COUT,int COB,int SPT,int KS,
         int CO_FR,bool DEC>
__global__ __launch_bounds__(256,2) void mfma_conv(
    const f16* __restrict__ xin, const f16* __restrict__ wp,
    f16* __restrict__ out16, float* __restrict__ out32, size_t ps)
{
    constexpr int OHo  = DEC ? OH/2 : OH;
    constexpr int OWo  = DEC ? OW/2 : OW;
    constexpr int KTOT = CIN * (DEC ? 4 : 16);
    constexpr int CH   = (KTOT/64) / KS;
    constexpr int RPT  = CIN / 64;
    constexpr int RSH  = (RPT==1?0:RPT==2?1:RPT==4?2:3);
    constexpr int WSTR = CIN * 16;
    constexpr int TPR  = 256 / COB;
    constexpr int NU4  = 8 / TPR;
    constexpr int SPB  = OHo * OWo;          // power of two for all layers
    constexpr int LSPB = ilog2c(SPB);
    constexpr int LOWo = ilog2c(OWo);

    __shared__ unsigned long long Xs[SPT*17];
    __shared__ unsigned long long Wls[COB*17];

    const int t   = threadIdx.x;
    const int bx  = blockIdx.x;
    const int cob = blockIdx.y;
    const int bz  = blockIdx.z;
    const int par = DEC ? (bz & 3) : 0;
    const int ks  = DEC ? (bz >> 2) : bz;
    const int poh = par >> 1, pw = par & 1;

    const int gsp_s = bx*SPT + t;
    const int img_s = gsp_s >> LSPB;
    const int r_s   = gsp_s & (SPB-1);
    const int oy_s  = r_s >> LOWo;
    const int ox_s  = r_s & (OWo-1);

    const int wco   = t / TPR;
    const int wpart = t % TPR;
    const f16* wbase = wp + (size_t)(cob*COB + wco)*WSTR + wpart*(64/TPR);

    const int wave = t >> 6, lane = t & 63, half = lane >> 5, l31 = lane & 31;
    const int co_w = (wave >> 1) * (CO_FR*32);
    const int sp_w = (wave & 1) * 128;

    f32x16 acc[CO_FR][4];
    #pragma unroll
    for (int i = 0; i < CO_FR; ++i)
        #pragma unroll
        for (int b = 0; b < 4; ++b)
            #pragma unroll
            for (int r = 0; r < 16; ++r) acc[i][b][r] = 0.f;

    for (int cc = 0; cc < CH; ++cc) {
        const int gc  = ks*CH + cc;
        const int tap = gc >> RSH;
        const int ci0 = (gc & (RPT-1)) << 6;
        int kh, kw, ih, iw;
        if (DEC) {
            const int t2h = tap >> 1, t2w = tap & 1;
            kh = (1-poh) + 2*t2h; kw = (1-pw) + 2*t2w;
            ih = oy_s + poh - t2h; iw = ox_s + pw - t2w;
        } else {
            kh = tap >> 2; kw = tap & 3;
            ih = 2*oy_s - 1 + kh; iw = 2*ox_s - 1 + kw;
        }
        const int woff = (kh*4 + kw)*CIN + ci0;

        if (cc) __syncthreads();
        {
            const uint4* src = (const uint4*)(wbase + woff);
            #pragma unroll
            for (int j = 0; j < NU4; ++j) {
                Q16 v; v.q = src[j];
                const int u0 = wco*17 + wpart*(NU4*2) + j*2;
                Wls[u0]   = v.u[0];
                Wls[u0+1] = v.u[1];
            }
        }
        {
            const bool ok = (unsigned)ih < (unsigned)IH && (unsigned)iw < (unsigned)IW;
            const int u0 = t*17;
            if (ok) {
                const uint4* src = (const uint4*)
                    (xin + ((size_t)(img_s*IH + ih)*IW + iw)*CIN + ci0);
                #pragma unroll
                for (int j = 0; j < 8; ++j) {
                    Q16 v; v.q = src[j];
                    Xs[u0 + j*2]   = v.u[0];
                    Xs[u0 + j*2+1] = v.u[1];
                }
            } else {
                #pragma unroll
                for (int j = 0; j < 16; ++j) Xs[u0 + j] = 0ull;
            }
        }
        __syncthreads();

        #pragma unroll
        for (int kk = 0; kk < 4; ++kk) {
            const int uo = kk*4 + 2*half;
            f16x8 wf[CO_FR], xf[4];
            #pragma unroll
            for (int i = 0; i < CO_FR; ++i) {
                U64x2 u; const int rw = (co_w + i*32 + l31)*17 + uo;
                u.u[0] = Wls[rw]; u.u[1] = Wls[rw+1]; wf[i] = u.v;
            }
            #pragma unroll
            for (int b = 0; b < 4; ++b) {
                U64x2 u; const int rx = (sp_w + b*32 + l31)*17 + uo;
                u.u[0] = Xs[rx]; u.u[1] = Xs[rx+1]; xf[b] = u.v;
            }
            // A = X (sp rows), B = W (co cols) -> D[row=sp][col=co]
            #pragma unroll
            for (int i = 0; i < CO_FR; ++i)
                #pragma unroll
                for (int b = 0; b < 4; ++b)
                    acc[i][b] = __builtin_amdgcn_mfma_f32_32x32x16_f16(
                        xf[b], wf[i], acc[i][b], 0, 0, 0);
        }
    }

    // ---- epilogue: lane = co (contiguous) ----
    #pragma unroll
    for (int b = 0; b < 4; ++b) {
        #pragma unroll
        for (int q = 0; q < 4; ++q) {
            #pragma unroll
            for (int r2 = 0; r2 < 4; ++r2) {
                const int sp_loc = sp_w + b*32 + q*8 + 4*half + r2;
                const int gsp    = bx*SPT + sp_loc;
                size_t base;
                if (DEC) {
                    const int img = gsp >> LSPB;
                    const int r   = gsp & (SPB-1);
                    const int oh  = 2*(r >> LOWo) + poh;
                    const int ow  = 2*(r & (OWo-1)) + pw;
                    base = ((size_t)(img*OH + oh)*OW + ow)*COUT + cob*COB;
                } else {
                    base = (size_t)gsp*COUT + cob*COB;
                }
                #pragma unroll
                for (int i = 0; i < CO_FR; ++i) {
                    const int co_l = co_w + i*32 + l31;
                    const float v  = acc[i][b][q*4 + r2];
                    if (KS == 1) out16[base + co_l] = (_Float16)v;
                    else         out32[(size_t)ks*ps + base + co_l] = v;
                }
            }
        }
    }
}

// ---------------------------------------------------------------------------
// Weight prep: f32 -> f16 [co][ (kh*4+kw)*CIN + ci ]  (6 fused segments)
// ---------------------------------------------------------------------------
__global__ __launch_bounds__(256) void prep_w(
    const float* __restrict__ w2, const float* __restrict__ w3,
    const float* __restrict__ w4, const float* __restrict__ dw1,
    const float* __restrict__ dw2, const float* __restrict__ dw3,
    f16* __restrict__ dst)
{
    const int e = blockIdx.x*256 + threadIdx.x;
    float v;
    if (e < 131072) {
        int co = e >> 10, r = e & 1023, khw = r >> 6, ci = r & 63;
        v = w2[(co*64 + ci)*16 + khw];
    } else if (e < 655360) {
        int l = e - 131072;
        int co = l >> 11, r = l & 2047, khw = r >> 7, ci = r & 127;
        v = w3[(co*128 + ci)*16 + khw];
    } else if (e < 2752512) {
        int l = e - 655360;
        int co = l >> 12, r = l & 4095, khw = r >> 8, ci = r & 255;
        v = w4[(co*256 + ci)*16 + khw];
    } else if (e < 4849664) {
        int l = e - 2752512;
        int co = l >> 13, r = l & 8191, khw = r >> 9, ci = r & 511;
        v = dw1[(ci*256 + co)*16 + khw];
    } else if (e < 5373952) {
        int l = e - 4849664;
        int co = l >> 12, r = l & 4095, khw = r >> 8, ci = r & 255;
        v = dw2[(ci*128 + co)*16 + khw];
    } else {
        int l = e - 5373952;
        int co = l >> 11, r = l & 2047, khw = r >> 7, ci = r & 127;
        v = dw3[(ci*64 + co)*16 + khw];
    }
    dst[e] = (_Float16)v;
}

// ---------------------------------------------------------------------------
// conv1 (3->64, K=48): f32 VALU implicit GEMM, f16 NHWC out (unchanged)
// ---------------------------------------------------------------------------
template<int CIN,int IH,int IW,int OH,int OW,int COUT,int KC,int SPT,int COB>
__global__ __launch_bounds__(256) void conv1_f32(
    const float* __restrict__ in, const float* __restrict__ w,
    f16* __restrict__ out)
{
    constexpr int KTOT = CIN * 16;
    constexpr int KPT  = KC * SPT / 256;
    constexpr int WPT  = KC * COB / 256;
    constexpr int TPC  = 256 / COB;
    constexpr int SPG  = SPT / 4;

    __shared__ float Xs[KC * SPT];
    __shared__ float Ws[KC * COB];

    const int t = threadIdx.x;
    const int sp_sub = (t % SPG) * 4;
    const int co_sub = (t / SPG) * 4;
    const int sp_g = t % SPT;
    const int kk   = t / SPT;
    const int gsp  = blockIdx.x * SPT + sp_g;
    const int n_g  = gsp / (OH * OW);
    const int rg   = gsp % (OH * OW);
    const int ih0  = 2 * (rg / OW) - 1, iw0 = 2 * (rg % OW) - 1;
    const float* inb = in + (size_t)n_g * CIN * IH * IW;
    const int co_w = t / TPC;
    const int k0w  = (t % TPC) * WPT;
    const int cob  = blockIdx.y;
    const float* wrow = w + (size_t)(cob * COB + co_w) * KTOT;

    float acc[16];
    #pragma unroll
    for (int i = 0; i < 16; ++i) acc[i] = 0.f;

    #pragma unroll
    for (int j = 0; j < WPT; ++j)
        Ws[(k0w + j) * COB + co_w] = wrow[k0w + j];
    #pragma unroll
    for (int j = 0; j < KPT; ++j) {
        int k  = kk * KPT + j;
        int ci = k >> 4, khw = k & 15;
        int ih = ih0 + (khw >> 2), iw = iw0 + (khw & 3);
        float v = 0.f;
        if ((unsigned)ih < (unsigned)IH && (unsigned)iw < (unsigned)IW)
            v = inb[((size_t)ci * IH + ih) * IW + iw];
        Xs[k * SPT + sp_g] = v;
    }
    __syncthreads();
    #pragma unroll 8
    for (int k = 0; k < KC; ++k) {
        const float4 xv = *(const float4*)&Xs[k * SPT + sp_sub];
        const float4 wv = *(const float4*)&Ws[k * COB + co_sub];
        const float x4[4] = {xv.x, xv.y, xv.z, xv.w};
        const float w4[4] = {wv.x, wv.y, wv.z, wv.w};
        #pragma unroll
        for (int a = 0; a < 4; ++a)
            #pragma unroll
            for (int b = 0; b < 4; ++b)
                acc[a*4+b] = fmaf(w4[a], x4[b], acc[a*4+b]);
    }
    const int gsp0 = blockIdx.x * SPT + sp_sub;
    #pragma unroll
    for (int a = 0; a < 4; ++a) {
        const int co = cob * COB + co_sub + a;
        #pragma unroll
        for (int b = 0; b < 4; ++b)
            out[(size_t)(gsp0 + b) * COUT + co] = (_Float16)acc[a*4+b];
    }
}

// ---------------------------------------------------------------------------
// deconv4 (64->3) + tanh fused gather (unchanged, verified)
// ---------------------------------------------------------------------------
__global__ __launch_bounds__(256) void deconv4_fused(
    const f16* __restrict__ xin, const float* __restrict__ w,
    float* __restrict__ out)
{
    const int T   = blockIdx.x * 256 + threadIdx.x;
    const int n   = T >> 10;
    const int p   = T & 1023;
    const int ohh = p >> 5, oww = p & 31;

    float acc[12];
    #pragma unroll
    for (int i = 0; i < 12; ++i) acc[i] = 0.f;

    const f16* inb = xin + (size_t)n * (32*32*64);

    for (int c8 = 0; c8 < 8; ++c8) {
        union { uint4 q; _Float16 h[8]; } xp[9];
        #pragma unroll
        for (int dy = -1; dy <= 1; ++dy)
            #pragma unroll
            for (int dx = -1; dx <= 1; ++dx) {
                const int ih = ohh + dy, iw = oww + dx;
                const int j  = (dy+1)*3 + (dx+1);
                if ((unsigned)ih < 32u && (unsigned)iw < 32u)
                    xp[j].q = *(const uint4*)(inb + ((ih*32 + iw)*64) + c8*8);
                else
                    xp[j].q = make_uint4(0u,0u,0u,0u);
            }
        #pragma unroll
        for (int cl = 0; cl < 8; ++cl) {
            const int ci = c8*8 + cl;
            float xv[9];
            #pragma unroll
            for (int j = 0; j < 9; ++j) xv[j] = (float)xp[j].h[cl];
            #pragma unroll
            for (int co = 0; co < 3; ++co) {
                const float* wr = w + (ci*3 + co)*16;
                #pragma unroll
                for (int par = 0; par < 4; ++par) {
                    const int poh = par >> 1, pw = par & 1;
                    #pragma unroll
                    for (int tap = 0; tap < 4; ++tap) {
                        const int t2h = tap >> 1, t2w = tap & 1;
                        const int kh = (1-poh) + 2*t2h, kw = (1-pw) + 2*t2w;
                        const int jx = (poh - t2h + 1)*3 + (pw - t2w + 1);
                        acc[par*3+co] = fmaf(xv[jx], wr[kh*4+kw], acc[par*3+co]);
                    }
                }
            }
        }
    }
    #pragma unroll
    for (int par = 0; par < 4; ++par) {
        const int poh = par >> 1, pw = par & 1;
        const int oh = 2*ohh + poh, ow = 2*oww + pw;
        #pragma unroll
        for (int co = 0; co < 3; ++co)
            out[(((size_t)n*3 + co)*64 + oh)*64 + ow] = tanhf(acc[par*3+co]);
    }
}

// ---------------------------------------------------------------------------
// BN: partial stats over P partial buffers (stride ps), finalize, act.
// ---------------------------------------------------------------------------
template<typename T, int P>
__global__ __launch_bounds__(256) void bn_partial(
    const T* __restrict__ x, size_t ps, float* __restrict__ psum,
    float* __restrict__ psq, int C, int rowsPerS, int S)
{
    const int s = blockIdx.x;
    const int c = (blockIdx.y << 6) + (threadIdx.x & 63);
    float a = 0.f, q = 0.f;
    const int rEnd = (s + 1) * rowsPerS;
    for (int r = s*rowsPerS + (threadIdx.x >> 6); r < rEnd; r += 4) {
        float v = 0.f;
        #pragma unroll
        for (int p = 0; p < P; ++p)
            v += (float)x[p*ps + (size_t)r * C + c];
        a += v; q += v * v;
    }
    __shared__ float ls[256], lq[256];
    ls[threadIdx.x] = a; lq[threadIdx.x] = q;
    __syncthreads();
    if (threadIdx.x < 64) {
        a = ls[threadIdx.x] + ls[threadIdx.x+64] + ls[threadIdx.x+128] + ls[threadIdx.x+192];
        q = lq[threadIdx.x] + lq[threadIdx.x+64] + lq[threadIdx.x+128] + lq[threadIdx.x+192];
        psum[c * S + s] = a; psq[c * S + s] = q;
    }
}

__global__ __launch_bounds__(256) void bn_finalize(
    const float* __restrict__ psum, const float* __restrict__ psq,
    const float* __restrict__ gamma, const float* __restrict__ beta,
    float* __restrict__ scale, float* __restrict__ shift,
    int C, int S, float inv_count)
{
    int c = blockIdx.x * 256 + threadIdx.x;
    if (c >= C) return;
    float s = 0.f, q = 0.f;
    for (int i = 0; i < S; ++i) { s += psum[c*S + i]; q += psq[c*S + i]; }
    float m   = s * inv_count;
    float var = q * inv_count - m * m;
    var = var < 0.f ? 0.f : var;
    float sc = gamma[c] * rsqrtf(var + 1e-5f);
    scale[c] = sc;
    shift[c] = beta[c] - m * sc;
}

__global__ __launch_bounds__(256) void bn_act16(
    f16* __restrict__ x, const float* __restrict__ sc, const float* __restrict__ sh,
    int Cmask, float slope)
{
    const size_t i8 = ((size_t)blockIdx.x*256 + threadIdx.x) * 8;
    union { uint4 u; _Float16 h[8]; } a;
    a.u = *(const uint4*)(x + i8);
    const int c0 = (int)(i8 & (size_t)Cmask);
    #pragma unroll
    for (int j = 0; j < 8; ++j) {
        float v = (float)a.h[j] * sc[c0+j] + sh[c0+j];
        a.h[j] = (_Float16)(v >= 0.f ? v : slope * v);
    }
    *(uint4*)(x + i8) = a.u;
}

// sum P f32 partial buffers (stride ps) -> affine+act -> f16 NHWC
template<int P>
__global__ __launch_bounds__(256) void bn_act32(
    const float* __restrict__ x, size_t ps, f16* __restrict__ y,
    const float* __restrict__ sc, const float* __restrict__ sh,
    int Cmask, float slope)
{
    const size_t i8 = ((size_t)blockIdx.x*256 + threadIdx.x) * 8;
    float xv[8] = {0,0,0,0,0,0,0,0};
    #pragma unroll
    for (int p = 0; p < P; ++p) {
        float4 v0 = *(const float4*)(x + p*ps + i8);
        float4 v1 = *(const float4*)(x + p*ps + i8 + 4);
        xv[0]+=v0.x; xv[1]+=v0.y; xv[2]+=v0.z; xv[3]+=v0.w;
        xv[4]+=v1.x; xv[5]+=v1.y; xv[6]+=v1.z; xv[7]+=v1.w;
    }
    union { uint4 u; _Float16 h[8]; } a;
    const int c0 = (int)(i8 & (size_t)Cmask);
    #pragma unroll
    for (int j = 0; j < 8; ++j) {
        float v = xv[j] * sc[c0+j] + sh[c0+j];
        a.h[j] = (_Float16)(v >= 0.f ? v : slope * v);
    }
    *(uint4*)(y + i8) = a.u;
}

// Per-channel Linear(16,16), NHWC f16 in/out (unchanged)
__global__ __launch_bounds__(256) void chanlin16(
    const f16* __restrict__ in, const float* __restrict__ w,
    const float* __restrict__ bias, f16* __restrict__ out)
{
    const int i = blockIdx.x*256 + threadIdx.x;
    const int c  = i & 511;
    const int bt = i >> 9;
    const int b  = bt >> 4, tt = bt & 15;
    const f16* src = in + ((size_t)b*16)*512 + c;
    const float* wr = w + ((size_t)c*16 + tt)*16;
    float acc = bias[c*16 + tt];
    #pragma unroll
    for (int s = 0; s < 16; ++s)
        acc = fmaf((float)src[s*512], wr[s], acc);
    out[i] = (_Float16)acc;
}

extern "C" void kernel_launch(void* const* d_in, const int* in_sizes, int n_in,
                              void* d_out, int out_size, void* d_ws, size_t ws_size,
                              hipStream_t stream)
{
    const float* x   = (const float*)d_in[0];
    const float* w1  = (const float*)d_in[1];
    const float* w2  = (const float*)d_in[2];
    const float* w3  = (const float*)d_in[3];
    const float* w4  = (const float*)d_in[4];
    const float* g1  = (const float*)d_in[5];
    const float* b1  = (const float*)d_in[6];
    const float* g2  = (const float*)d_in[7];
    const float* b2  = (const float*)d_in[8];
    const float* g3  = (const float*)d_in[9];
    const float* b3  = (const float*)d_in[10];
    const float* g4  = (const float*)d_in[11];
    const float* b4  = (const float*)d_in[12];
    const float* cww = (const float*)d_in[13];
    const float* cwb = (const float*)d_in[14];
    const float* dw1 = (const float*)d_in[15];
    const float* dw2 = (const float*)d_in[16];
    const float* dw3 = (const float*)d_in[17];
    const float* dw4 = (const float*)d_in[18];
    const float* dg1 = (const float*)d_in[19];
    const float* db1 = (const float*)d_in[20];
    const float* dg2 = (const float*)d_in[21];
    const float* db2 = (const float*)d_in[22];
    const float* dg3 = (const float*)d_in[23];
    const float* db3 = (const float*)d_in[24];

    // ws: stats 256K | slotA 33.55M | slotB 33.55M | (gap 16.78M) | wprep 11M
    char* WS = (char*)d_ws;
    float* psum  = (float*)WS;
    float* psq   = (float*)(WS + 65536);
    float* scale = (float*)(WS + 131072);
    float* shift = (float*)(WS + 133120);
    f16* slotA   = (f16*)(WS + 262144);
    f16* slotB   = (f16*)(WS + 262144 + 33554432);
    f16* wprep   = (f16*)(WS + 84148224);

    f16*   A_hi  = slotA + 8388608;          // byte offset +16.78M inside slotA
    f16*   B_hi  = slotB + 8388608;
    float* pA    = (float*)slotA;            // f32 partial arena in slotA
    float* pB    = (float*)slotB;            // f32 partial arena in slotB

    prep_w<<<21504, 256, 0, stream>>>(w2, w3, w4, dw1, dw2, dw3, wprep);

    // ---- conv1 (f32 VALU) -> slotB f16 NHWC ----
    conv1_f32<3,64,64,32,32,64, 48,128,32><<<dim3(2048,2), 256, 0, stream>>>(x, w1, slotB);
    bn_partial<f16,1><<<dim3(256,1), 256, 0, stream>>>(slotB, 0, psum, psq, 64, 1024, 256);
    bn_finalize<<<1, 256, 0, stream>>>(psum, psq, g1, b1, scale, shift, 64, 256, 1.f/262144.f);
    bn_act16<<<8192, 256, 0, stream>>>(slotB, scale, shift, 63, 0.2f);

    // ---- conv2: slotB -> slotA f16 ----
    mfma_conv<64,32,32,16,16,128, 128,256,1,2,false><<<dim3(256,1,1), 256, 0, stream>>>(
        slotB, wprep, slotA, nullptr, 0);
    bn_partial<f16,1><<<dim3(128,2), 256, 0, stream>>>(slotA, 0, psum, psq, 128, 512, 128);
    bn_finalize<<<1, 256, 0, stream>>>(psum, psq, g2, b2, scale, shift, 128, 128, 1.f/65536.f);
    bn_act16<<<4096, 256, 0, stream>>>(slotA, scale, shift, 127, 0.2f);

    // ---- conv3 (KS=2): slotA -> partials in slotB (2 x 16.78MB f32) ----
    mfma_conv<128,16,16,8,8,256, 128,256,2,2,false><<<dim3(64,2,2), 256, 0, stream>>>(
        slotA, wprep + 131072, nullptr, pB, (size_t)4194304);
    bn_partial<float,2><<<dim3(64,4), 256, 0, stream>>>(pB, (size_t)4194304, psum, psq, 256, 256, 64);
    bn_finalize<<<1, 256, 0, stream>>>(psum, psq, g3, b3, scale, shift, 256, 64, 1.f/16384.f);
    bn_act32<2><<<2048, 256, 0, stream>>>(pB, (size_t)4194304, A_hi, scale, shift, 255, 0.2f);

    // ---- conv4 (KS=4): A_hi -> partials in slotB (4 x 8.39MB f32) ----
    mfma_conv<256,8,8,4,4,512, 128,256,4,2,false><<<dim3(16,4,4), 256, 0, stream>>>(
        A_hi, wprep + 655360, nullptr, pB, (size_t)2097152);
    bn_partial<float,4><<<dim3(32,8), 256, 0, stream>>>(pB, (size_t)2097152, psum, psq, 512, 128, 32);
    bn_finalize<<<2, 256, 0, stream>>>(psum, psq, g4, b4, scale, shift, 512, 32, 1.f/4096.f);
    bn_act32<4><<<1024, 256, 0, stream>>>(pB, (size_t)2097152, slotA, scale, shift, 511, 0.2f);

    // ---- channel-wise linear: slotA(lo) -> slotB(lo) ----
    chanlin16<<<8192, 256, 0, stream>>>(slotA, cww, cwb, slotB);

    // ---- deconv1 (KS=2): slotB(lo) -> partials in slotA ----
    mfma_conv<512,4,4,8,8,256, 128,256,2,2,true><<<dim3(16,2,8), 256, 0, stream>>>(
        slotB, wprep + 2752512, nullptr, pA, (size_t)4194304);
    bn_partial<float,2><<<dim3(64,4), 256, 0, stream>>>(pA, (size_t)4194304, psum, psq, 256, 256, 64);
    bn_finalize<<<1, 256, 0, stream>>>(psum, psq, dg1, db1, scale, shift, 256, 64, 1.f/16384.f);
    bn_act32<2><<<2048, 256, 0, stream>>>(pA, (size_t)4194304, B_hi, scale, shift, 255, 0.f);

    // ---- deconv2: B_hi -> slotA(lo) f16 ----
    mfma_conv<256,8,8,16,16,128, 128,256,1,2,true><<<dim3(64,1,4), 256, 0, stream>>>(
        B_hi, wprep + 4849664, slotA, nullptr, 0);
    bn_partial<f16,1><<<dim3(128,2), 256, 0, stream>>>(slotA, 0, psum, psq, 128, 512, 128);
    bn_finalize<<<1, 256, 0, stream>>>(psum, psq, dg2, db2, scale, shift, 128, 128, 1.f/65536.f);
    bn_act16<<<4096, 256, 0, stream>>>(slotA, scale, shift, 127, 0.f);

    // ---- deconv3 (COB=64, CO_FR=1): slotA(lo) -> slotB full ----
    mfma_conv<128,16,16,32,32,64, 64,256,1,1,true><<<dim3(256,1,4), 256, 0, stream>>>(
        slotA, wprep + 5373952, slotB, nullptr, 0);
    bn_partial<f16,1><<<dim3(256,1), 256, 0, stream>>>(slotB, 0, psum, psq, 64, 1024, 256);
    bn_finalize<<<1, 256, 0, stream>>>(psum, psq, dg3, db3, scale, shift, 64, 256, 1.f/262144.f);
    bn_act16<<<8192, 256, 0, stream>>>(slotB, scale, shift, 63, 0.f);

    // ---- deconv4 + tanh: slotB -> d_out ----
    deconv4_fused<<<1024, 256, 0, stream>>>(slotB, dw4, (float*)d_out);
}

// Round 8
// 990.292 us; speedup vs baseline: 27.5838x; 1.0391x over previous
//
#include <hip/hip_runtime.h>
#include <math.h>

typedef _Float16 f16;
typedef __attribute__((ext_vector_type(8))) _Float16 f16x8;
typedef __attribute__((ext_vector_type(16))) float f32x16;

union U64x2 { unsigned long long u[2]; f16x8 v; };
union Q16   { uint4 q; unsigned long long u[2]; };

constexpr int ilog2c(int x) { return x <= 1 ? 0 : 1 + ilog2c(x >> 1); }

__device__ __forceinline__ float fast_tanh(float x) {
    float e = __expf(2.f * x);
    return (e - 1.f) / (e + 1.f);
}

// ===========================================================================
// fp16 MFMA implicit-GEMM conv/deconv (k4 s2 p1), NHWC activations.
// A-operand = X (sp rows), B-operand = W (co cols) => D: row=sp, col=co.
// K-split (KS>1) blocks write disjoint f32 partial buffers; BN pass sums.
// (verified round 7)
// ===========================================================================
template<int CIN,int IH,int IW,int OH,int OW,int COUT,int COB,int SPT,int KS,
         int CO_FR,bool DEC>
__global__ __launch_bounds__(256,2) void mfma_conv(
    const f16* __restrict__ xin, const f16* __restrict__ wp,
    f16* __restrict__ out16, float* __restrict__ out32, size_t ps)
{
    constexpr int OHo  = DEC ? OH/2 : OH;
    constexpr int OWo  = DEC ? OW/2 : OW;
    constexpr int KTOT = CIN * (DEC ? 4 : 16);
    constexpr int CH   = (KTOT/64) / KS;
    constexpr int RPT  = CIN / 64;
    constexpr int RSH  = (RPT==1?0:RPT==2?1:RPT==4?2:3);
    constexpr int WSTR = CIN * 16;
    constexpr int TPR  = 256 / COB;
    constexpr int NU4  = 8 / TPR;
    constexpr int SPB  = OHo * OWo;
    constexpr int LSPB = ilog2c(SPB);
    constexpr int LOWo = ilog2c(OWo);

    __shared__ unsigned long long Xs[SPT*17];
    __shared__ unsigned long long Wls[COB*17];

    const int t   = threadIdx.x;
    const int bx  = blockIdx.x;
    const int cob = blockIdx.y;
    const int bz  = blockIdx.z;
    const int par = DEC ? (bz & 3) : 0;
    const int ks  = DEC ? (bz >> 2) : bz;
    const int poh = par >> 1, pw = par & 1;

    const int gsp_s = bx*SPT + t;
    const int img_s = gsp_s >> LSPB;
    const int r_s   = gsp_s & (SPB-1);
    const int oy_s  = r_s >> LOWo;
    const int ox_s  = r_s & (OWo-1);

    const int wco   = t / TPR;
    const int wpart = t % TPR;
    const f16* wbase = wp + (size_t)(cob*COB + wco)*WSTR + wpart*(64/TPR);

    const int wave = t >> 6, lane = t & 63, half = lane >> 5, l31 = lane & 31;
    const int co_w = (wave >> 1) * (CO_FR*32);
    const int sp_w = (wave & 1) * 128;

    f32x16 acc[CO_FR][4];
    #pragma unroll
    for (int i = 0; i < CO_FR; ++i)
        #pragma unroll
        for (int b = 0; b < 4; ++b)
            #pragma unroll
            for (int r = 0; r < 16; ++r) acc[i][b][r] = 0.f;

    for (int cc = 0; cc < CH; ++cc) {
        const int gc  = ks*CH + cc;
        const int tap = gc >> RSH;
        const int ci0 = (gc & (RPT-1)) << 6;
        int kh, kw, ih, iw;
        if (DEC) {
            const int t2h = tap >> 1, t2w = tap & 1;
            kh = (1-poh) + 2*t2h; kw = (1-pw) + 2*t2w;
            ih = oy_s + poh - t2h; iw = ox_s + pw - t2w;
        } else {
            kh = tap >> 2; kw = tap & 3;
            ih = 2*oy_s - 1 + kh; iw = 2*ox_s - 1 + kw;
        }
        const int woff = (kh*4 + kw)*CIN + ci0;

        if (cc) __syncthreads();
        {
            const uint4* src = (const uint4*)(wbase + woff);
            #pragma unroll
            for (int j = 0; j < NU4; ++j) {
                Q16 v; v.q = src[j];
                const int u0 = wco*17 + wpart*(NU4*2) + j*2;
                Wls[u0]   = v.u[0];
                Wls[u0+1] = v.u[1];
            }
        }
        {
            const bool ok = (unsigned)ih < (unsigned)IH && (unsigned)iw < (unsigned)IW;
            const int u0 = t*17;
            if (ok) {
                const uint4* src = (const uint4*)
                    (xin + ((size_t)(img_s*IH + ih)*IW + iw)*CIN + ci0);
                #pragma unroll
                for (int j = 0; j < 8; ++j) {
                    Q16 v; v.q = src[j];
                    Xs[u0 + j*2]   = v.u[0];
                    Xs[u0 + j*2+1] = v.u[1];
                }
            } else {
                #pragma unroll
                for (int j = 0; j < 16; ++j) Xs[u0 + j] = 0ull;
            }
        }
        __syncthreads();

        #pragma unroll
        for (int kk = 0; kk < 4; ++kk) {
            const int uo = kk*4 + 2*half;
            f16x8 wf[CO_FR], xf[4];
            #pragma unroll
            for (int i = 0; i < CO_FR; ++i) {
                U64x2 u; const int rw = (co_w + i*32 + l31)*17 + uo;
                u.u[0] = Wls[rw]; u.u[1] = Wls[rw+1]; wf[i] = u.v;
            }
            #pragma unroll
            for (int b = 0; b < 4; ++b) {
                U64x2 u; const int rx = (sp_w + b*32 + l31)*17 + uo;
                u.u[0] = Xs[rx]; u.u[1] = Xs[rx+1]; xf[b] = u.v;
            }
            #pragma unroll
            for (int i = 0; i < CO_FR; ++i)
                #pragma unroll
                for (int b = 0; b < 4; ++b)
                    acc[i][b] = __builtin_amdgcn_mfma_f32_32x32x16_f16(
                        xf[b], wf[i], acc[i][b], 0, 0, 0);
        }
    }

    #pragma unroll
    for (int b = 0; b < 4; ++b) {
        #pragma unroll
        for (int q = 0; q < 4; ++q) {
            #pragma unroll
            for (int r2 = 0; r2 < 4; ++r2) {
                const int sp_loc = sp_w + b*32 + q*8 + 4*half + r2;
                const int gsp    = bx*SPT + sp_loc;
                size_t base;
                if (DEC) {
                    const int img = gsp >> LSPB;
                    const int r   = gsp & (SPB-1);
                    const int oh  = 2*(r >> LOWo) + poh;
                    const int ow  = 2*(r & (OWo-1)) + pw;
                    base = ((size_t)(img*OH + oh)*OW + ow)*COUT + cob*COB;
                } else {
                    base = (size_t)gsp*COUT + cob*COB;
                }
                #pragma unroll
                for (int i = 0; i < CO_FR; ++i) {
                    const int co_l = co_w + i*32 + l31;
                    const float v  = acc[i][b][q*4 + r2];
                    if (KS == 1) out16[base + co_l] = (_Float16)v;
                    else         out32[(size_t)ks*ps + base + co_l] = v;
                }
            }
        }
    }
}

// ---------------------------------------------------------------------------
// conv1 via MFMA: x prepacked f16 (n,64,64,4) ci-padded; K = tap*4+ci = 64
// (one LDS chunk). Same frag/epilogue mapping as mfma_conv (COB=64, CO_FR=1).
// ---------------------------------------------------------------------------
__global__ __launch_bounds__(256,2) void conv1_mfma(
    const f16* __restrict__ xp, const f16* __restrict__ wp,
    f16* __restrict__ out)
{
    __shared__ unsigned long long Xs[256*17];
    __shared__ unsigned long long Wls[64*17];
    const int t = threadIdx.x, bx = blockIdx.x;

    // stage W: 64 co rows x 16 u64; thread -> (row = t>>2, 4 u64)
    {
        const int r = t >> 2, part = t & 3;
        const uint4* src = (const uint4*)(wp + r*64 + part*16);
        Q16 v0; v0.q = src[0];
        Q16 v1; v1.q = src[1];
        const int u0 = r*17 + part*4;
        Wls[u0]   = v0.u[0]; Wls[u0+1] = v0.u[1];
        Wls[u0+2] = v1.u[0]; Wls[u0+3] = v1.u[1];
    }
    // stage X: thread t owns sp row t; 16 taps x b64
    {
        const int gsp = bx*256 + t;
        const int n = gsp >> 10, r = gsp & 1023;
        const int oy = r >> 5, ox = r & 31;
        const int ih0 = 2*oy - 1, iw0 = 2*ox - 1;
        const int u0 = t*17;
        #pragma unroll
        for (int tap = 0; tap < 16; ++tap) {
            const int ih = ih0 + (tap >> 2), iw = iw0 + (tap & 3);
            unsigned long long v = 0ull;
            if ((unsigned)ih < 64u && (unsigned)iw < 64u)
                v = *(const unsigned long long*)(xp + (((size_t)n*64 + ih)*64 + iw)*4);
            Xs[u0 + tap] = v;
        }
    }
    __syncthreads();

    const int wave = t >> 6, lane = t & 63, half = lane >> 5, l31 = lane & 31;
    const int co_w = (wave >> 1) * 32;
    const int sp_w = (wave & 1) * 128;

    f32x16 acc[4];
    #pragma unroll
    for (int b = 0; b < 4; ++b)
        #pragma unroll
        for (int r = 0; r < 16; ++r) acc[b][r] = 0.f;

    #pragma unroll
    for (int kk = 0; kk < 4; ++kk) {
        const int uo = kk*4 + 2*half;
        U64x2 uw; const int rw = (co_w + l31)*17 + uo;
        uw.u[0] = Wls[rw]; uw.u[1] = Wls[rw+1];
        #pragma unroll
        for (int b = 0; b < 4; ++b) {
            U64x2 ux; const int rx = (sp_w + b*32 + l31)*17 + uo;
            ux.u[0] = Xs[rx]; ux.u[1] = Xs[rx+1];
            acc[b] = __builtin_amdgcn_mfma_f32_32x32x16_f16(
                ux.v, uw.v, acc[b], 0, 0, 0);
        }
    }
    #pragma unroll
    for (int b = 0; b < 4; ++b)
        #pragma unroll
        for (int q = 0; q < 4; ++q)
            #pragma unroll
            for (int r2 = 0; r2 < 4; ++r2) {
                const int sp_loc = sp_w + b*32 + q*8 + 4*half + r2;
                out[(size_t)(bx*256 + sp_loc)*64 + co_w + l31] =
                    (_Float16)acc[b][q*4 + r2];
            }
}

// pack x f32 NCHW (256,3,64,64) -> f16 (n,64,64,4), ci padded with 0
__global__ __launch_bounds__(256) void prep_x(
    const float* __restrict__ x, f16* __restrict__ xp)
{
    const int i = blockIdx.x*256 + threadIdx.x;     // 1,048,576 pixels
    const int n = i >> 12, p = i & 4095;
    const float* b = x + (size_t)n*12288 + p;
    union { _Float16 h[4]; unsigned long long u; } o;
    o.h[0] = (_Float16)b[0];
    o.h[1] = (_Float16)b[4096];
    o.h[2] = (_Float16)b[8192];
    o.h[3] = (_Float16)0.f;
    *(unsigned long long*)(xp + (size_t)i*4) = o.u;
}

// w1 f32 (64,3,4,4) -> f16 [co][tap*4+ci] padded
__global__ __launch_bounds__(256) void prep_w1(
    const float* __restrict__ w1, f16* __restrict__ wp)
{
    const int e = blockIdx.x*256 + threadIdx.x;     // 4096
    const int co = e >> 6, k = e & 63, tap = k >> 2, ci = k & 3;
    const float v = (ci < 3) ? w1[(co*3 + ci)*16 + tap] : 0.f;
    wp[e] = (_Float16)v;
}

// ---------------------------------------------------------------------------
// Weight prep for layers 2-4, d1-d3 (unchanged, verified)
// ---------------------------------------------------------------------------
__global__ __launch_bounds__(256) void prep_w(
    const float* __restrict__ w2, const float* __restrict__ w3,
    const float* __restrict__ w4, const float* __restrict__ dw1,
    const float* __restrict__ dw2, const float* __restrict__ dw3,
    f16* __restrict__ dst)
{
    const int e = blockIdx.x*256 + threadIdx.x;
    float v;
    if (e < 131072) {
        int co = e >> 10, r = e & 1023, khw = r >> 6, ci = r & 63;
        v = w2[(co*64 + ci)*16 + khw];
    } else if (e < 655360) {
        int l = e - 131072;
        int co = l >> 11, r = l & 2047, khw = r >> 7, ci = r & 127;
        v = w3[(co*128 + ci)*16 + khw];
    } else if (e < 2752512) {
        int l = e - 655360;
        int co = l >> 12, r = l & 4095, khw = r >> 8, ci = r & 255;
        v = w4[(co*256 + ci)*16 + khw];
    } else if (e < 4849664) {
        int l = e - 2752512;
        int co = l >> 13, r = l & 8191, khw = r >> 9, ci = r & 511;
        v = dw1[(ci*256 + co)*16 + khw];
    } else if (e < 5373952) {
        int l = e - 4849664;
        int co = l >> 12, r = l & 4095, khw = r >> 8, ci = r & 255;
        v = dw2[(ci*128 + co)*16 + khw];
    } else {
        int l = e - 5373952;
        int co = l >> 11, r = l & 2047, khw = r >> 7, ci = r & 127;
        v = dw3[(ci*64 + co)*16 + khw];
    }
    dst[e] = (_Float16)v;
}

// ---------------------------------------------------------------------------
// deconv4 (64->3): ci-split 2-way. Each half computes 32 ci over the 2x2
// parity quad x 3 channels; f32 partials [half][T][12]; combine adds + tanh.
// ---------------------------------------------------------------------------
__global__ __launch_bounds__(256) void deconv4_part(
    const f16* __restrict__ xin, const float* __restrict__ w,
    float* __restrict__ pout)
{
    const int T   = blockIdx.x * 256 + threadIdx.x;   // 262144
    const int h   = blockIdx.y;                       // ci half
    const int n   = T >> 10;
    const int p   = T & 1023;
    const int ohh = p >> 5, oww = p & 31;

    float acc[12];
    #pragma unroll
    for (int i = 0; i < 12; ++i) acc[i] = 0.f;

    const f16* inb = xin + (size_t)n * (32*32*64);

    for (int c8 = h*4; c8 < h*4 + 4; ++c8) {
        union { uint4 q; _Float16 hh[8]; } xp[9];
        #pragma unroll
        for (int dy = -1; dy <= 1; ++dy)
            #pragma unroll
            for (int dx = -1; dx <= 1; ++dx) {
                const int ih = ohh + dy, iw = oww + dx;
                const int j  = (dy+1)*3 + (dx+1);
                if ((unsigned)ih < 32u && (unsigned)iw < 32u)
                    xp[j].q = *(const uint4*)(inb + ((ih*32 + iw)*64) + c8*8);
                else
                    xp[j].q = make_uint4(0u,0u,0u,0u);
            }
        #pragma unroll
        for (int cl = 0; cl < 8; ++cl) {
            const int ci = c8*8 + cl;
            float xv[9];
            #pragma unroll
            for (int j = 0; j < 9; ++j) xv[j] = (float)xp[j].hh[cl];
            #pragma unroll
            for (int co = 0; co < 3; ++co) {
                const float* wr = w + (ci*3 + co)*16;
                #pragma unroll
                for (int par = 0; par < 4; ++par) {
                    const int poh = par >> 1, pw = par & 1;
                    #pragma unroll
                    for (int tap = 0; tap < 4; ++tap) {
                        const int t2h = tap >> 1, t2w = tap & 1;
                        const int kh = (1-poh) + 2*t2h, kw = (1-pw) + 2*t2w;
                        const int jx = (poh - t2h + 1)*3 + (pw - t2w + 1);
                        acc[par*3+co] = fmaf(xv[jx], wr[kh*4+kw], acc[par*3+co]);
                    }
                }
            }
        }
    }
    float* o = pout + ((size_t)h*262144 + T)*12;
    #pragma unroll
    for (int i = 0; i < 12; ++i) o[i] = acc[i];
}

__global__ __launch_bounds__(256) void deconv4_combine(
    const float* __restrict__ pin, float* __restrict__ out)
{
    const int T   = blockIdx.x * 256 + threadIdx.x;
    const int n   = T >> 10;
    const int p   = T & 1023;
    const int ohh = p >> 5, oww = p & 31;

    const float* a = pin + (size_t)T*12;
    const float* b = pin + (size_t)262144*12 + (size_t)T*12;
    float acc[12];
    #pragma unroll
    for (int i = 0; i < 12; i += 4) {
        float4 va = *(const float4*)(a + i);
        float4 vb = *(const float4*)(b + i);
        acc[i]   = va.x + vb.x; acc[i+1] = va.y + vb.y;
        acc[i+2] = va.z + vb.z; acc[i+3] = va.w + vb.w;
    }
    #pragma unroll
    for (int par = 0; par < 4; ++par) {
        const int poh = par >> 1, pw = par & 1;
        const int oh = 2*ohh + poh, ow = 2*oww + pw;
        #pragma unroll
        for (int co = 0; co < 3; ++co)
            out[(((size_t)n*3 + co)*64 + oh)*64 + ow] = fast_tanh(acc[par*3+co]);
    }
}

// ---------------------------------------------------------------------------
// BN stack (unchanged, verified)
// ---------------------------------------------------------------------------
template<typename T, int P>
__global__ __launch_bounds__(256) void bn_partial(
    const T* __restrict__ x, size_t ps, float* __restrict__ psum,
    float* __restrict__ psq, int C, int rowsPerS, int S)
{
    const int s = blockIdx.x;
    const int c = (blockIdx.y << 6) + (threadIdx.x & 63);
    float a = 0.f, q = 0.f;
    const int rEnd = (s + 1) * rowsPerS;
    for (int r = s*rowsPerS + (threadIdx.x >> 6); r < rEnd; r += 4) {
        float v = 0.f;
        #pragma unroll
        for (int p = 0; p < P; ++p)
            v += (float)x[p*ps + (size_t)r * C + c];
        a += v; q += v * v;
    }
    __shared__ float ls[256], lq[256];
    ls[threadIdx.x] = a; lq[threadIdx.x] = q;
    __syncthreads();
    if (threadIdx.x < 64) {
        a = ls[threadIdx.x] + ls[threadIdx.x+64] + ls[threadIdx.x+128] + ls[threadIdx.x+192];
        q = lq[threadIdx.x] + lq[threadIdx.x+64] + lq[threadIdx.x+128] + lq[threadIdx.x+192];
        psum[c * S + s] = a; psq[c * S + s] = q;
    }
}

__global__ __launch_bounds__(256) void bn_finalize(
    const float* __restrict__ psum, const float* __restrict__ psq,
    const float* __restrict__ gamma, const float* __restrict__ beta,
    float* __restrict__ scale, float* __restrict__ shift,
    int C, int S, float inv_count)
{
    int c = blockIdx.x * 256 + threadIdx.x;
    if (c >= C) return;
    float s = 0.f, q = 0.f;
    for (int i = 0; i < S; ++i) { s += psum[c*S + i]; q += psq[c*S + i]; }
    float m   = s * inv_count;
    float var = q * inv_count - m * m;
    var = var < 0.f ? 0.f : var;
    float sc = gamma[c] * rsqrtf(var + 1e-5f);
    scale[c] = sc;
    shift[c] = beta[c] - m * sc;
}

__global__ __launch_bounds__(256) void bn_act16(
    f16* __restrict__ x, const float* __restrict__ sc, const float* __restrict__ sh,
    int Cmask, float slope)
{
    const size_t i8 = ((size_t)blockIdx.x*256 + threadIdx.x) * 8;
    union { uint4 u; _Float16 h[8]; } a;
    a.u = *(const uint4*)(x + i8);
    const int c0 = (int)(i8 & (size_t)Cmask);
    #pragma unroll
    for (int j = 0; j < 8; ++j) {
        float v = (float)a.h[j] * sc[c0+j] + sh[c0+j];
        a.h[j] = (_Float16)(v >= 0.f ? v : slope * v);
    }
    *(uint4*)(x + i8) = a.u;
}

template<int P>
__global__ __launch_bounds__(256) void bn_act32(
    const float* __restrict__ x, size_t ps, f16* __restrict__ y,
    const float* __restrict__ sc, const float* __restrict__ sh,
    int Cmask, float slope)
{
    const size_t i8 = ((size_t)blockIdx.x*256 + threadIdx.x) * 8;
    float xv[8] = {0,0,0,0,0,0,0,0};
    #pragma unroll
    for (int p = 0; p < P; ++p) {
        float4 v0 = *(const float4*)(x + p*ps + i8);
        float4 v1 = *(const float4*)(x + p*ps + i8 + 4);
        xv[0]+=v0.x; xv[1]+=v0.y; xv[2]+=v0.z; xv[3]+=v0.w;
        xv[4]+=v1.x; xv[5]+=v1.y; xv[6]+=v1.z; xv[7]+=v1.w;
    }
    union { uint4 u; _Float16 h[8]; } a;
    const int c0 = (int)(i8 & (size_t)Cmask);
    #pragma unroll
    for (int j = 0; j < 8; ++j) {
        float v = xv[j] * sc[c0+j] + sh[c0+j];
        a.h[j] = (_Float16)(v >= 0.f ? v : slope * v);
    }
    *(uint4*)(y + i8) = a.u;
}

__global__ __launch_bounds__(256) void chanlin16(
    const f16* __restrict__ in, const float* __restrict__ w,
    const float* __restrict__ bias, f16* __restrict__ out)
{
    const int i = blockIdx.x*256 + threadIdx.x;
    const int c  = i & 511;
    const int bt = i >> 9;
    const int b  = bt >> 4, tt = bt & 15;
    const f16* src = in + ((size_t)b*16)*512 + c;
    const float* wr = w + ((size_t)c*16 + tt)*16;
    float acc = bias[c*16 + tt];
    #pragma unroll
    for (int s = 0; s < 16; ++s)
        acc = fmaf((float)src[s*512], wr[s], acc);
    out[i] = (_Float16)acc;
}

extern "C" void kernel_launch(void* const* d_in, const int* in_sizes, int n_in,
                              void* d_out, int out_size, void* d_ws, size_t ws_size,
                              hipStream_t stream)
{
    const float* x   = (const float*)d_in[0];
    const float* w1  = (const float*)d_in[1];
    const float* w2  = (const float*)d_in[2];
    const float* w3  = (const float*)d_in[3];
    const float* w4  = (const float*)d_in[4];
    const float* g1  = (const float*)d_in[5];
    const float* b1  = (const float*)d_in[6];
    const float* g2  = (const float*)d_in[7];
    const float* b2  = (const float*)d_in[8];
    const float* g3  = (const float*)d_in[9];
    const float* b3  = (const float*)d_in[10];
    const float* g4  = (const float*)d_in[11];
    const float* b4  = (const float*)d_in[12];
    const float* cww = (const float*)d_in[13];
    const float* cwb = (const float*)d_in[14];
    const float* dw1 = (const float*)d_in[15];
    const float* dw2 = (const float*)d_in[16];
    const float* dw3 = (const float*)d_in[17];
    const float* dw4 = (const float*)d_in[18];
    const float* dg1 = (const float*)d_in[19];
    const float* db1 = (const float*)d_in[20];
    const float* dg2 = (const float*)d_in[21];
    const float* db2 = (const float*)d_in[22];
    const float* dg3 = (const float*)d_in[23];
    const float* db3 = (const float*)d_in[24];

    // ws: stats 256K | slotA 33.55M | slotB 33.55M | gap | wprep 11M+8K
    char* WS = (char*)d_ws;
    float* psum  = (float*)WS;
    float* psq   = (float*)(WS + 65536);
    float* scale = (float*)(WS + 131072);
    float* shift = (float*)(WS + 133120);
    f16* slotA   = (f16*)(WS + 262144);
    f16* slotB   = (f16*)(WS + 262144 + 33554432);
    f16* wprep   = (f16*)(WS + 84148224);
    f16* wprep1  = wprep + 5505024;               // 4096 f16 for conv1

    f16*   A_hi  = slotA + 8388608;
    f16*   B_hi  = slotB + 8388608;
    float* pA    = (float*)slotA;
    float* pB    = (float*)slotB;
    f16*   xpack = slotA;                          // conv1 input pack (8 MB)

    prep_w<<<21504, 256, 0, stream>>>(w2, w3, w4, dw1, dw2, dw3, wprep);
    prep_w1<<<16, 256, 0, stream>>>(w1, wprep1);
    prep_x<<<4096, 256, 0, stream>>>(x, xpack);

    // ---- conv1 (MFMA): xpack(slotA) -> slotB f16 NHWC ----
    conv1_mfma<<<1024, 256, 0, stream>>>(xpack, wprep1, slotB);
    bn_partial<f16,1><<<dim3(256,1), 256, 0, stream>>>(slotB, 0, psum, psq, 64, 1024, 256);
    bn_finalize<<<1, 256, 0, stream>>>(psum, psq, g1, b1, scale, shift, 64, 256, 1.f/262144.f);
    bn_act16<<<8192, 256, 0, stream>>>(slotB, scale, shift, 63, 0.2f);

    // ---- conv2: slotB -> slotA f16 ----
    mfma_conv<64,32,32,16,16,128, 128,256,1,2,false><<<dim3(256,1,1), 256, 0, stream>>>(
        slotB, wprep, slotA, nullptr, 0);
    bn_partial<f16,1><<<dim3(128,2), 256, 0, stream>>>(slotA, 0, psum, psq, 128, 512, 128);
    bn_finalize<<<1, 256, 0, stream>>>(psum, psq, g2, b2, scale, shift, 128, 128, 1.f/65536.f);
    bn_act16<<<4096, 256, 0, stream>>>(slotA, scale, shift, 127, 0.2f);

    // ---- conv3 (KS=2): slotA -> partials in slotB ----
    mfma_conv<128,16,16,8,8,256, 128,256,2,2,false><<<dim3(64,2,2), 256, 0, stream>>>(
        slotA, wprep + 131072, nullptr, pB, (size_t)4194304);
    bn_partial<float,2><<<dim3(64,4), 256, 0, stream>>>(pB, (size_t)4194304, psum, psq, 256, 256, 64);
    bn_finalize<<<1, 256, 0, stream>>>(psum, psq, g3, b3, scale, shift, 256, 64, 1.f/16384.f);
    bn_act32<2><<<2048, 256, 0, stream>>>(pB, (size_t)4194304, A_hi, scale, shift, 255, 0.2f);

    // ---- conv4 (KS=4): A_hi -> partials in slotB ----
    mfma_conv<256,8,8,4,4,512, 128,256,4,2,false><<<dim3(16,4,4), 256, 0, stream>>>(
        A_hi, wprep + 655360, nullptr, pB, (size_t)2097152);
    bn_partial<float,4><<<dim3(32,8), 256, 0, stream>>>(pB, (size_t)2097152, psum, psq, 512, 128, 32);
    bn_finalize<<<2, 256, 0, stream>>>(psum, psq, g4, b4, scale, shift, 512, 32, 1.f/4096.f);
    bn_act32<4><<<1024, 256, 0, stream>>>(pB, (size_t)2097152, slotA, scale, shift, 511, 0.2f);

    // ---- channel-wise linear: slotA(lo) -> slotB(lo) ----
    chanlin16<<<8192, 256, 0, stream>>>(slotA, cww, cwb, slotB);

    // ---- deconv1 (KS=2): slotB(lo) -> partials in slotA ----
    mfma_conv<512,4,4,8,8,256, 128,256,2,2,true><<<dim3(16,2,8), 256, 0, stream>>>(
        slotB, wprep + 2752512, nullptr, pA, (size_t)4194304);
    bn_partial<float,2><<<dim3(64,4), 256, 0, stream>>>(pA, (size_t)4194304, psum, psq, 256, 256, 64);
    bn_finalize<<<1, 256, 0, stream>>>(psum, psq, dg1, db1, scale, shift, 256, 64, 1.f/16384.f);
    bn_act32<2><<<2048, 256, 0, stream>>>(pA, (size_t)4194304, B_hi, scale, shift, 255, 0.f);

    // ---- deconv2: B_hi -> slotA(lo) f16 ----
    mfma_conv<256,8,8,16,16,128, 128,256,1,2,true><<<dim3(64,1,4), 256, 0, stream>>>(
        B_hi, wprep + 4849664, slotA, nullptr, 0);
    bn_partial<f16,1><<<dim3(128,2), 256, 0, stream>>>(slotA, 0, psum, psq, 128, 512, 128);
    bn_finalize<<<1, 256, 0, stream>>>(psum, psq, dg2, db2, scale, shift, 128, 128, 1.f/65536.f);
    bn_act16<<<4096, 256, 0, stream>>>(slotA, scale, shift, 127, 0.f);

    // ---- deconv3 (COB=64, CO_FR=1): slotA(lo) -> slotB full ----
    mfma_conv<128,16,16,32,32,64, 64,256,1,1,true><<<dim3(256,1,4), 256, 0, stream>>>(
        slotA, wprep + 5373952, slotB, nullptr, 0);
    bn_partial<f16,1><<<dim3(256,1), 256, 0, stream>>>(slotB, 0, psum, psq, 64, 1024, 256);
    bn_finalize<<<1, 256, 0, stream>>>(psum, psq, dg3, db3, scale, shift, 64, 256, 1.f/262144.f);
    bn_act16<<<8192, 256, 0, stream>>>(slotB, scale, shift, 63, 0.f);

    // ---- deconv4: ci-split partials (slotA f32 arena) + combine/tanh ----
    deconv4_part<<<dim3(1024,2), 256, 0, stream>>>(slotB, dw4, pA);
    deconv4_combine<<<1024, 256, 0, stream>>>(pA, (float*)d_out);
}

// Round 9
// 943.403 us; speedup vs baseline: 28.9548x; 1.0497x over previous
//
#include <hip/hip_runtime.h>
#include <math.h>

typedef _Float16 f16;
typedef __attribute__((ext_vector_type(8))) _Float16 f16x8;
typedef __attribute__((ext_vector_type(16))) float f32x16;

union U64x2 { unsigned long long u[2]; f16x8 v; };
union Q16   { uint4 q; unsigned long long u[2]; };

constexpr int ilog2c(int x) { return x <= 1 ? 0 : 1 + ilog2c(x >> 1); }

__device__ __forceinline__ float fast_tanh(float x) {
    float e = __expf(2.f * x);
    return (e - 1.f) / (e + 1.f);
}

// ===========================================================================
// fp16 MFMA implicit-GEMM conv/deconv (k4 s2 p1), NHWC activations.
// A-operand = X (sp rows), B-operand = W (co cols) => D: row=sp, col=co.
// K-split (KS>1) blocks write disjoint f32 partial buffers; BN pass sums.
// (verified rounds 7-8)
// ===========================================================================
template<int CIN,int IH,int IW,int OH,int OW,int COUT,int COB,int SPT,int KS,
         int CO_FR,bool DEC>
__global__ __launch_bounds__(256,2) void mfma_conv(
    const f16* __restrict__ xin, const f16* __restrict__ wp,
    f16* __restrict__ out16, float* __restrict__ out32, size_t ps)
{
    constexpr int OHo  = DEC ? OH/2 : OH;
    constexpr int OWo  = DEC ? OW/2 : OW;
    constexpr int KTOT = CIN * (DEC ? 4 : 16);
    constexpr int CH   = (KTOT/64) / KS;
    constexpr int RPT  = CIN / 64;
    constexpr int RSH  = (RPT==1?0:RPT==2?1:RPT==4?2:3);
    constexpr int WSTR = CIN * 16;
    constexpr int TPR  = 256 / COB;
    constexpr int NU4  = 8 / TPR;
    constexpr int SPB  = OHo * OWo;
    constexpr int LSPB = ilog2c(SPB);
    constexpr int LOWo = ilog2c(OWo);

    __shared__ unsigned long long Xs[SPT*17];
    __shared__ unsigned long long Wls[COB*17];

    const int t   = threadIdx.x;
    const int bx  = blockIdx.x;
    const int cob = blockIdx.y;
    const int bz  = blockIdx.z;
    const int par = DEC ? (bz & 3) : 0;
    const int ks  = DEC ? (bz >> 2) : bz;
    const int poh = par >> 1, pw = par & 1;

    const int gsp_s = bx*SPT + t;
    const int img_s = gsp_s >> LSPB;
    const int r_s   = gsp_s & (SPB-1);
    const int oy_s  = r_s >> LOWo;
    const int ox_s  = r_s & (OWo-1);

    const int wco   = t / TPR;
    const int wpart = t % TPR;
    const f16* wbase = wp + (size_t)(cob*COB + wco)*WSTR + wpart*(64/TPR);

    const int wave = t >> 6, lane = t & 63, half = lane >> 5, l31 = lane & 31;
    const int co_w = (wave >> 1) * (CO_FR*32);
    const int sp_w = (wave & 1) * 128;

    f32x16 acc[CO_FR][4];
    #pragma unroll
    for (int i = 0; i < CO_FR; ++i)
        #pragma unroll
        for (int b = 0; b < 4; ++b)
            #pragma unroll
            for (int r = 0; r < 16; ++r) acc[i][b][r] = 0.f;

    for (int cc = 0; cc < CH; ++cc) {
        const int gc  = ks*CH + cc;
        const int tap = gc >> RSH;
        const int ci0 = (gc & (RPT-1)) << 6;
        int kh, kw, ih, iw;
        if (DEC) {
            const int t2h = tap >> 1, t2w = tap & 1;
            kh = (1-poh) + 2*t2h; kw = (1-pw) + 2*t2w;
            ih = oy_s + poh - t2h; iw = ox_s + pw - t2w;
        } else {
            kh = tap >> 2; kw = tap & 3;
            ih = 2*oy_s - 1 + kh; iw = 2*ox_s - 1 + kw;
        }
        const int woff = (kh*4 + kw)*CIN + ci0;

        if (cc) __syncthreads();
        {
            const uint4* src = (const uint4*)(wbase + woff);
            #pragma unroll
            for (int j = 0; j < NU4; ++j) {
                Q16 v; v.q = src[j];
                const int u0 = wco*17 + wpart*(NU4*2) + j*2;
                Wls[u0]   = v.u[0];
                Wls[u0+1] = v.u[1];
            }
        }
        {
            const bool ok = (unsigned)ih < (unsigned)IH && (unsigned)iw < (unsigned)IW;
            const int u0 = t*17;
            if (ok) {
                const uint4* src = (const uint4*)
                    (xin + ((size_t)(img_s*IH + ih)*IW + iw)*CIN + ci0);
                #pragma unroll
                for (int j = 0; j < 8; ++j) {
                    Q16 v; v.q = src[j];
                    Xs[u0 + j*2]   = v.u[0];
                    Xs[u0 + j*2+1] = v.u[1];
                }
            } else {
                #pragma unroll
                for (int j = 0; j < 16; ++j) Xs[u0 + j] = 0ull;
            }
        }
        __syncthreads();

        #pragma unroll
        for (int kk = 0; kk < 4; ++kk) {
            const int uo = kk*4 + 2*half;
            f16x8 wf[CO_FR], xf[4];
            #pragma unroll
            for (int i = 0; i < CO_FR; ++i) {
                U64x2 u; const int rw = (co_w + i*32 + l31)*17 + uo;
                u.u[0] = Wls[rw]; u.u[1] = Wls[rw+1]; wf[i] = u.v;
            }
            #pragma unroll
            for (int b = 0; b < 4; ++b) {
                U64x2 u; const int rx = (sp_w + b*32 + l31)*17 + uo;
                u.u[0] = Xs[rx]; u.u[1] = Xs[rx+1]; xf[b] = u.v;
            }
            #pragma unroll
            for (int i = 0; i < CO_FR; ++i)
                #pragma unroll
                for (int b = 0; b < 4; ++b)
                    acc[i][b] = __builtin_amdgcn_mfma_f32_32x32x16_f16(
                        xf[b], wf[i], acc[i][b], 0, 0, 0);
        }
    }

    #pragma unroll
    for (int b = 0; b < 4; ++b) {
        #pragma unroll
        for (int q = 0; q < 4; ++q) {
            #pragma unroll
            for (int r2 = 0; r2 < 4; ++r2) {
                const int sp_loc = sp_w + b*32 + q*8 + 4*half + r2;
                const int gsp    = bx*SPT + sp_loc;
                size_t base;
                if (DEC) {
                    const int img = gsp >> LSPB;
                    const int r   = gsp & (SPB-1);
                    const int oh  = 2*(r >> LOWo) + poh;
                    const int ow  = 2*(r & (OWo-1)) + pw;
                    base = ((size_t)(img*OH + oh)*OW + ow)*COUT + cob*COB;
                } else {
                    base = (size_t)gsp*COUT + cob*COB;
                }
                #pragma unroll
                for (int i = 0; i < CO_FR; ++i) {
                    const int co_l = co_w + i*32 + l31;
                    const float v  = acc[i][b][q*4 + r2];
                    if (KS == 1) out16[base + co_l] = (_Float16)v;
                    else         out32[(size_t)ks*ps + base + co_l] = v;
                }
            }
        }
    }
}

// ---------------------------------------------------------------------------
// conv1 via MFMA (verified round 8)
// ---------------------------------------------------------------------------
__global__ __launch_bounds__(256,2) void conv1_mfma(
    const f16* __restrict__ xp, const f16* __restrict__ wp,
    f16* __restrict__ out)
{
    __shared__ unsigned long long Xs[256*17];
    __shared__ unsigned long long Wls[64*17];
    const int t = threadIdx.x, bx = blockIdx.x;

    {
        const int r = t >> 2, part = t & 3;
        const uint4* src = (const uint4*)(wp + r*64 + part*16);
        Q16 v0; v0.q = src[0];
        Q16 v1; v1.q = src[1];
        const int u0 = r*17 + part*4;
        Wls[u0]   = v0.u[0]; Wls[u0+1] = v0.u[1];
        Wls[u0+2] = v1.u[0]; Wls[u0+3] = v1.u[1];
    }
    {
        const int gsp = bx*256 + t;
        const int n = gsp >> 10, r = gsp & 1023;
        const int oy = r >> 5, ox = r & 31;
        const int ih0 = 2*oy - 1, iw0 = 2*ox - 1;
        const int u0 = t*17;
        #pragma unroll
        for (int tap = 0; tap < 16; ++tap) {
            const int ih = ih0 + (tap >> 2), iw = iw0 + (tap & 3);
            unsigned long long v = 0ull;
            if ((unsigned)ih < 64u && (unsigned)iw < 64u)
                v = *(const unsigned long long*)(xp + (((size_t)n*64 + ih)*64 + iw)*4);
            Xs[u0 + tap] = v;
        }
    }
    __syncthreads();

    const int wave = t >> 6, lane = t & 63, half = lane >> 5, l31 = lane & 31;
    const int co_w = (wave >> 1) * 32;
    const int sp_w = (wave & 1) * 128;

    f32x16 acc[4];
    #pragma unroll
    for (int b = 0; b < 4; ++b)
        #pragma unroll
        for (int r = 0; r < 16; ++r) acc[b][r] = 0.f;

    #pragma unroll
    for (int kk = 0; kk < 4; ++kk) {
        const int uo = kk*4 + 2*half;
        U64x2 uw; const int rw = (co_w + l31)*17 + uo;
        uw.u[0] = Wls[rw]; uw.u[1] = Wls[rw+1];
        #pragma unroll
        for (int b = 0; b < 4; ++b) {
            U64x2 ux; const int rx = (sp_w + b*32 + l31)*17 + uo;
            ux.u[0] = Xs[rx]; ux.u[1] = Xs[rx+1];
            acc[b] = __builtin_amdgcn_mfma_f32_32x32x16_f16(
                ux.v, uw.v, acc[b], 0, 0, 0);
        }
    }
    #pragma unroll
    for (int b = 0; b < 4; ++b)
        #pragma unroll
        for (int q = 0; q < 4; ++q)
            #pragma unroll
            for (int r2 = 0; r2 < 4; ++r2) {
                const int sp_loc = sp_w + b*32 + q*8 + 4*half + r2;
                out[(size_t)(bx*256 + sp_loc)*64 + co_w + l31] =
                    (_Float16)acc[b][q*4 + r2];
            }
}

// ---------------------------------------------------------------------------
// deconv4 (64->3) via MFMA, COUT padded to 32. Orientation A=W, B=X
// (round-5-verified): D row=co (reg), col=sp (lane). Only rows co<3 stored
// (q=0, half=0, r2<3) -> 32-lane stride-2-float stores into f32 NCHW + tanh.
// Grid (1024, parity=4). wp: [co(32)][khw*64+ci] f16, rows 3..31 zero.
// ---------------------------------------------------------------------------
__global__ __launch_bounds__(256,2) void deconv4_mfma(
    const f16* __restrict__ xin, const f16* __restrict__ wp,
    float* __restrict__ out)
{
    __shared__ unsigned long long Xs[256*17];
    __shared__ unsigned long long Wls[32*17];

    const int t   = threadIdx.x;
    const int bx  = blockIdx.x;
    const int par = blockIdx.y;
    const int poh = par >> 1, pw = par & 1;

    const int gsp_s = bx*256 + t;
    const int img_s = gsp_s >> 10;
    const int r_s   = gsp_s & 1023;
    const int oy_s  = r_s >> 5;
    const int ox_s  = r_s & 31;

    const int wco   = t >> 3;          // 0..31
    const int wpart = t & 7;           // 0..7, 8 f16 each

    const int wave = t >> 6, lane = t & 63, half = lane >> 5, l31 = lane & 31;
    const int sp_w = wave * 64;

    f32x16 acc[2];
    #pragma unroll
    for (int b = 0; b < 2; ++b)
        #pragma unroll
        for (int r = 0; r < 16; ++r) acc[b][r] = 0.f;

    for (int cc = 0; cc < 4; ++cc) {           // tap = cc
        const int t2h = cc >> 1, t2w = cc & 1;
        const int kh = (1-poh) + 2*t2h, kw = (1-pw) + 2*t2w;
        const int ih = oy_s + poh - t2h, iw = ox_s + pw - t2w;

        if (cc) __syncthreads();
        {   // W-stage: 32 rows x 64 f16
            Q16 v; v.q = *(const uint4*)(wp + wco*1024 + (kh*4 + kw)*64 + wpart*8);
            const int u0 = wco*17 + wpart*2;
            Wls[u0] = v.u[0]; Wls[u0+1] = v.u[1];
        }
        {   // X-stage: thread t owns sp row t, 64 ci contiguous
            const bool ok = (unsigned)ih < 32u && (unsigned)iw < 32u;
            const int u0 = t*17;
            if (ok) {
                const uint4* src = (const uint4*)
                    (xin + ((size_t)(img_s*32 + ih)*32 + iw)*64);
                #pragma unroll
                for (int j = 0; j < 8; ++j) {
                    Q16 v; v.q = src[j];
                    Xs[u0 + j*2]   = v.u[0];
                    Xs[u0 + j*2+1] = v.u[1];
                }
            } else {
                #pragma unroll
                for (int j = 0; j < 16; ++j) Xs[u0 + j] = 0ull;
            }
        }
        __syncthreads();

        #pragma unroll
        for (int kk = 0; kk < 4; ++kk) {
            const int uo = kk*4 + 2*half;
            U64x2 uw; const int rw = l31*17 + uo;
            uw.u[0] = Wls[rw]; uw.u[1] = Wls[rw+1];
            #pragma unroll
            for (int b = 0; b < 2; ++b) {
                U64x2 ux; const int rx = (sp_w + b*32 + l31)*17 + uo;
                ux.u[0] = Xs[rx]; ux.u[1] = Xs[rx+1];
                acc[b] = __builtin_amdgcn_mfma_f32_32x32x16_f16(
                    uw.v, ux.v, acc[b], 0, 0, 0);   // A=W, B=X
            }
        }
    }

    // epilogue: co = q*8 + 4*half + r2; live rows have half==0,q==0,r2<3
    if (half == 0) {
        #pragma unroll
        for (int b = 0; b < 2; ++b) {
            const int gsp = bx*256 + sp_w + b*32 + l31;
            const int img = gsp >> 10;
            const int r   = gsp & 1023;
            const int oh  = 2*(r >> 5) + poh;
            const int ow  = 2*(r & 31) + pw;
            #pragma unroll
            for (int co = 0; co < 3; ++co)
                out[(((size_t)img*3 + co)*64 + oh)*64 + ow] =
                    fast_tanh(acc[b][co]);
        }
    }
}

// pack x f32 NCHW (256,3,64,64) -> f16 (n,64,64,4), ci padded with 0
__global__ __launch_bounds__(256) void prep_x(
    const float* __restrict__ x, f16* __restrict__ xp)
{
    const int i = blockIdx.x*256 + threadIdx.x;
    const int n = i >> 12, p = i & 4095;
    const float* b = x + (size_t)n*12288 + p;
    union { _Float16 h[4]; unsigned long long u; } o;
    o.h[0] = (_Float16)b[0];
    o.h[1] = (_Float16)b[4096];
    o.h[2] = (_Float16)b[8192];
    o.h[3] = (_Float16)0.f;
    *(unsigned long long*)(xp + (size_t)i*4) = o.u;
}

// w1 f32 (64,3,4,4) -> f16 [co][tap*4+ci] padded
__global__ __launch_bounds__(256) void prep_w1(
    const float* __restrict__ w1, f16* __restrict__ wp)
{
    const int e = blockIdx.x*256 + threadIdx.x;
    const int co = e >> 6, k = e & 63, tap = k >> 2, ci = k & 3;
    const float v = (ci < 3) ? w1[(co*3 + ci)*16 + tap] : 0.f;
    wp[e] = (_Float16)v;
}

// dw4 f32 (64,3,4,4) -> f16 [co(32)][khw*64 + ci], co>=3 zero
__global__ __launch_bounds__(256) void prep_w4(
    const float* __restrict__ dw4, f16* __restrict__ wp)
{
    const int e = blockIdx.x*256 + threadIdx.x;    // 32768
    const int co = e >> 10, r = e & 1023, khw = r >> 6, ci = r & 63;
    const float v = (co < 3) ? dw4[(ci*3 + co)*16 + khw] : 0.f;
    wp[e] = (_Float16)v;
}

// ---------------------------------------------------------------------------
// Weight prep for layers 2-4, d1-d3 (verified)
// ---------------------------------------------------------------------------
__global__ __launch_bounds__(256) void prep_w(
    const float* __restrict__ w2, const float* __restrict__ w3,
    const float* __restrict__ w4, const float* __restrict__ dw1,
    const float* __restrict__ dw2, const float* __restrict__ dw3,
    f16* __restrict__ dst)
{
    const int e = blockIdx.x*256 + threadIdx.x;
    float v;
    if (e < 131072) {
        int co = e >> 10, r = e & 1023, khw = r >> 6, ci = r & 63;
        v = w2[(co*64 + ci)*16 + khw];
    } else if (e < 655360) {
        int l = e - 131072;
        int co = l >> 11, r = l & 2047, khw = r >> 7, ci = r & 127;
        v = w3[(co*128 + ci)*16 + khw];
    } else if (e < 2752512) {
        int l = e - 655360;
        int co = l >> 12, r = l & 4095, khw = r >> 8, ci = r & 255;
        v = w4[(co*256 + ci)*16 + khw];
    } else if (e < 4849664) {
        int l = e - 2752512;
        int co = l >> 13, r = l & 8191, khw = r >> 9, ci = r & 511;
        v = dw1[(ci*256 + co)*16 + khw];
    } else if (e < 5373952) {
        int l = e - 4849664;
        int co = l >> 12, r = l & 4095, khw = r >> 8, ci = r & 255;
        v = dw2[(ci*128 + co)*16 + khw];
    } else {
        int l = e - 5373952;
        int co = l >> 11, r = l & 2047, khw = r >> 7, ci = r & 127;
        v = dw3[(ci*64 + co)*16 + khw];
    }
    dst[e] = (_Float16)v;
}

// ---------------------------------------------------------------------------
// BN stack (verified)
// ---------------------------------------------------------------------------
template<typename T, int P>
__global__ __launch_bounds__(256) void bn_partial(
    const T* __restrict__ x, size_t ps, float* __restrict__ psum,
    float* __restrict__ psq, int C, int rowsPerS, int S)
{
    const int s = blockIdx.x;
    const int c = (blockIdx.y << 6) + (threadIdx.x & 63);
    float a = 0.f, q = 0.f;
    const int rEnd = (s + 1) * rowsPerS;
    for (int r = s*rowsPerS + (threadIdx.x >> 6); r < rEnd; r += 4) {
        float v = 0.f;
        #pragma unroll
        for (int p = 0; p < P; ++p)
            v += (float)x[p*ps + (size_t)r * C + c];
        a += v; q += v * v;
    }
    __shared__ float ls[256], lq[256];
    ls[threadIdx.x] = a; lq[threadIdx.x] = q;
    __syncthreads();
    if (threadIdx.x < 64) {
        a = ls[threadIdx.x] + ls[threadIdx.x+64] + ls[threadIdx.x+128] + ls[threadIdx.x+192];
        q = lq[threadIdx.x] + lq[threadIdx.x+64] + lq[threadIdx.x+128] + lq[threadIdx.x+192];
        psum[c * S + s] = a; psq[c * S + s] = q;
    }
}

__global__ __launch_bounds__(256) void bn_finalize(
    const float* __restrict__ psum, const float* __restrict__ psq,
    const float* __restrict__ gamma, const float* __restrict__ beta,
    float* __restrict__ scale, float* __restrict__ shift,
    int C, int S, float inv_count)
{
    int c = blockIdx.x * 256 + threadIdx.x;
    if (c >= C) return;
    float s = 0.f, q = 0.f;
    for (int i = 0; i < S; ++i) { s += psum[c*S + i]; q += psq[c*S + i]; }
    float m   = s * inv_count;
    float var = q * inv_count - m * m;
    var = var < 0.f ? 0.f : var;
    float sc = gamma[c] * rsqrtf(var + 1e-5f);
    scale[c] = sc;
    shift[c] = beta[c] - m * sc;
}

__global__ __launch_bounds__(256) void bn_act16(
    f16* __restrict__ x, const float* __restrict__ sc, const float* __restrict__ sh,
    int Cmask, float slope)
{
    const size_t i8 = ((size_t)blockIdx.x*256 + threadIdx.x) * 8;
    union { uint4 u; _Float16 h[8]; } a;
    a.u = *(const uint4*)(x + i8);
    const int c0 = (int)(i8 & (size_t)Cmask);
    #pragma unroll
    for (int j = 0; j < 8; ++j) {
        float v = (float)a.h[j] * sc[c0+j] + sh[c0+j];
        a.h[j] = (_Float16)(v >= 0.f ? v : slope * v);
    }
    *(uint4*)(x + i8) = a.u;
}

template<int P>
__global__ __launch_bounds__(256) void bn_act32(
    const float* __restrict__ x, size_t ps, f16* __restrict__ y,
    const float* __restrict__ sc, const float* __restrict__ sh,
    int Cmask, float slope)
{
    const size_t i8 = ((size_t)blockIdx.x*256 + threadIdx.x) * 8;
    float xv[8] = {0,0,0,0,0,0,0,0};
    #pragma unroll
    for (int p = 0; p < P; ++p) {
        float4 v0 = *(const float4*)(x + p*ps + i8);
        float4 v1 = *(const float4*)(x + p*ps + i8 + 4);
        xv[0]+=v0.x; xv[1]+=v0.y; xv[2]+=v0.z; xv[3]+=v0.w;
        xv[4]+=v1.x; xv[5]+=v1.y; xv[6]+=v1.z; xv[7]+=v1.w;
    }
    union { uint4 u; _Float16 h[8]; } a;
    const int c0 = (int)(i8 & (size_t)Cmask);
    #pragma unroll
    for (int j = 0; j < 8; ++j) {
        float v = xv[j] * sc[c0+j] + sh[c0+j];
        a.h[j] = (_Float16)(v >= 0.f ? v : slope * v);
    }
    *(uint4*)(y + i8) = a.u;
}

__global__ __launch_bounds__(256) void chanlin16(
    const f16* __restrict__ in, const float* __restrict__ w,
    const float* __restrict__ bias, f16* __restrict__ out)
{
    const int i = blockIdx.x*256 + threadIdx.x;
    const int c  = i & 511;
    const int bt = i >> 9;
    const int b  = bt >> 4, tt = bt & 15;
    const f16* src = in + ((size_t)b*16)*512 + c;
    const float* wr = w + ((size_t)c*16 + tt)*16;
    float acc = bias[c*16 + tt];
    #pragma unroll
    for (int s = 0; s < 16; ++s)
        acc = fmaf((float)src[s*512], wr[s], acc);
    out[i] = (_Float16)acc;
}

extern "C" void kernel_launch(void* const* d_in, const int* in_sizes, int n_in,
                              void* d_out, int out_size, void* d_ws, size_t ws_size,
                              hipStream_t stream)
{
    const float* x   = (const float*)d_in[0];
    const float* w1  = (const float*)d_in[1];
    const float* w2  = (const float*)d_in[2];
    const float* w3  = (const float*)d_in[3];
    const float* w4  = (const float*)d_in[4];
    const float* g1  = (const float*)d_in[5];
    const float* b1  = (const float*)d_in[6];
    const float* g2  = (const float*)d_in[7];
    const float* b2  = (const float*)d_in[8];
    const float* g3  = (const float*)d_in[9];
    const float* b3  = (const float*)d_in[10];
    const float* g4  = (const float*)d_in[11];
    const float* b4  = (const float*)d_in[12];
    const float* cww = (const float*)d_in[13];
    const float* cwb = (const float*)d_in[14];
    const float* dw1 = (const float*)d_in[15];
    const float* dw2 = (const float*)d_in[16];
    const float* dw3 = (const float*)d_in[17];
    const float* dw4 = (const float*)d_in[18];
    const float* dg1 = (const float*)d_in[19];
    const float* db1 = (const float*)d_in[20];
    const float* dg2 = (const float*)d_in[21];
    const float* db2 = (const float*)d_in[22];
    const float* dg3 = (const float*)d_in[23];
    const float* db3 = (const float*)d_in[24];

    // ws: stats 256K | slotA 33.55M | slotB 33.55M | gap | wprep 11M+8K+64K
    char* WS = (char*)d_ws;
    float* psum  = (float*)WS;
    float* psq   = (float*)(WS + 65536);
    float* scale = (float*)(WS + 131072);
    float* shift = (float*)(WS + 133120);
    f16* slotA   = (f16*)(WS + 262144);
    f16* slotB   = (f16*)(WS + 262144 + 33554432);
    f16* wprep   = (f16*)(WS + 84148224);
    f16* wprep1  = wprep + 5505024;               // 4096 f16 (conv1)
    f16* wprep4  = wprep1 + 4096;                 // 32768 f16 (deconv4)

    f16*   A_hi  = slotA + 8388608;
    f16*   B_hi  = slotB + 8388608;
    float* pA    = (float*)slotA;
    float* pB    = (float*)slotB;
    f16*   xpack = slotA;

    prep_w<<<21504, 256, 0, stream>>>(w2, w3, w4, dw1, dw2, dw3, wprep);
    prep_w1<<<16, 256, 0, stream>>>(w1, wprep1);
    prep_w4<<<128, 256, 0, stream>>>(dw4, wprep4);
    prep_x<<<4096, 256, 0, stream>>>(x, xpack);

    // ---- conv1 (MFMA): xpack(slotA) -> slotB f16 NHWC ----
    conv1_mfma<<<1024, 256, 0, stream>>>(xpack, wprep1, slotB);
    bn_partial<f16,1><<<dim3(256,1), 256, 0, stream>>>(slotB, 0, psum, psq, 64, 1024, 256);
    bn_finalize<<<1, 256, 0, stream>>>(psum, psq, g1, b1, scale, shift, 64, 256, 1.f/262144.f);
    bn_act16<<<8192, 256, 0, stream>>>(slotB, scale, shift, 63, 0.2f);

    // ---- conv2: slotB -> slotA f16 ----
    mfma_conv<64,32,32,16,16,128, 128,256,1,2,false><<<dim3(256,1,1), 256, 0, stream>>>(
        slotB, wprep, slotA, nullptr, 0);
    bn_partial<f16,1><<<dim3(128,2), 256, 0, stream>>>(slotA, 0, psum, psq, 128, 512, 128);
    bn_finalize<<<1, 256, 0, stream>>>(psum, psq, g2, b2, scale, shift, 128, 128, 1.f/65536.f);
    bn_act16<<<4096, 256, 0, stream>>>(slotA, scale, shift, 127, 0.2f);

    // ---- conv3 (KS=2): slotA -> partials in slotB ----
    mfma_conv<128,16,16,8,8,256, 128,256,2,2,false><<<dim3(64,2,2), 256, 0, stream>>>(
        slotA, wprep + 131072, nullptr, pB, (size_t)4194304);
    bn_partial<float,2><<<dim3(64,4), 256, 0, stream>>>(pB, (size_t)4194304, psum, psq, 256, 256, 64);
    bn_finalize<<<1, 256, 0, stream>>>(psum, psq, g3, b3, scale, shift, 256, 64, 1.f/16384.f);
    bn_act32<2><<<2048, 256, 0, stream>>>(pB, (size_t)4194304, A_hi, scale, shift, 255, 0.2f);

    // ---- conv4 (KS=4): A_hi -> partials in slotB ----
    mfma_conv<256,8,8,4,4,512, 128,256,4,2,false><<<dim3(16,4,4), 256, 0, stream>>>(
        A_hi, wprep + 655360, nullptr, pB, (size_t)2097152);
    bn_partial<float,4><<<dim3(32,8), 256, 0, stream>>>(pB, (size_t)2097152, psum, psq, 512, 128, 32);
    bn_finalize<<<2, 256, 0, stream>>>(psum, psq, g4, b4, scale, shift, 512, 32, 1.f/4096.f);
    bn_act32<4><<<1024, 256, 0, stream>>>(pB, (size_t)2097152, slotA, scale, shift, 511, 0.2f);

    // ---- channel-wise linear: slotA(lo) -> slotB(lo) ----
    chanlin16<<<8192, 256, 0, stream>>>(slotA, cww, cwb, slotB);

    // ---- deconv1 (KS=2): slotB(lo) -> partials in slotA ----
    mfma_conv<512,4,4,8,8,256, 128,256,2,2,true><<<dim3(16,2,8), 256, 0, stream>>>(
        slotB, wprep + 2752512, nullptr, pA, (size_t)4194304);
    bn_partial<float,2><<<dim3(64,4), 256, 0, stream>>>(pA, (size_t)4194304, psum, psq, 256, 256, 64);
    bn_finalize<<<1, 256, 0, stream>>>(psum, psq, dg1, db1, scale, shift, 256, 64, 1.f/16384.f);
    bn_act32<2><<<2048, 256, 0, stream>>>(pA, (size_t)4194304, B_hi, scale, shift, 255, 0.f);

    // ---- deconv2: B_hi -> slotA(lo) f16 ----
    mfma_conv<256,8,8,16,16,128, 128,256,1,2,true><<<dim3(64,1,4), 256, 0, stream>>>(
        B_hi, wprep + 4849664, slotA, nullptr, 0);
    bn_partial<f16,1><<<dim3(128,2), 256, 0, stream>>>(slotA, 0, psum, psq, 128, 512, 128);
    bn_finalize<<<1, 256, 0, stream>>>(psum, psq, dg2, db2, scale, shift, 128, 128, 1.f/65536.f);
    bn_act16<<<4096, 256, 0, stream>>>(slotA, scale, shift, 127, 0.f);

    // ---- deconv3 (COB=64, CO_FR=1): slotA(lo) -> slotB full ----
    mfma_conv<128,16,16,32,32,64, 64,256,1,1,true><<<dim3(256,1,4), 256, 0, stream>>>(
        slotA, wprep + 5373952, slotB, nullptr, 0);
    bn_partial<f16,1><<<dim3(256,1), 256, 0, stream>>>(slotB, 0, psum, psq, 64, 1024, 256);
    bn_finalize<<<1, 256, 0, stream>>>(psum, psq, dg3, db3, scale, shift, 64, 256, 1.f/262144.f);
    bn_act16<<<8192, 256, 0, stream>>>(slotB, scale, shift, 63, 0.f);

    // ---- deconv4 (MFMA, COUT padded to 32) + tanh: slotB -> d_out ----
    deconv4_mfma<<<dim3(1024,4), 256, 0, stream>>>(slotB, wprep4, (float*)d_out);
}

// Round 10
// 721.821 us; speedup vs baseline: 37.8432x; 1.3070x over previous
//
#include <hip/hip_runtime.h>
#include <math.h>

typedef _Float16 f16;
typedef __attribute__((ext_vector_type(8))) _Float16 f16x8;
typedef __attribute__((ext_vector_type(16))) float f32x16;

union U64x2 { unsigned long long u[2]; f16x8 v; };
union Q16   { uint4 q; unsigned long long u[2]; };

constexpr int ilog2c(int x) { return x <= 1 ? 0 : 1 + ilog2c(x >> 1); }

__device__ __forceinline__ float fast_tanh(float x) {
    float e = __expf(2.f * x);
    return (e - 1.f) / (e + 1.f);
}

// ===========================================================================
// fp16 MFMA implicit-GEMM conv/deconv (k4 s2 p1), NHWC activations.
// A-operand = X (sp rows), B-operand = W (co cols) => D: row=sp, col=co.
// KS>1: disjoint f32 partial buffers. KS==1 + stats: fused BN sum/sumsq
// (lane pair l/l+32 share co -> shfl reduce -> f32 atomicAdd per co).
// (verified rounds 7-9; stats fusion new)
// ===========================================================================
template<int CIN,int IH,int IW,int OH,int OW,int COUT,int COB,int SPT,int KS,
         int CO_FR,bool DEC>
__global__ __launch_bounds__(256,2) void mfma_conv(
    const f16* __restrict__ xin, const f16* __restrict__ wp,
    f16* __restrict__ out16, float* __restrict__ out32, size_t ps,
    float* __restrict__ psumF, float* __restrict__ psqF)
{
    constexpr int OHo  = DEC ? OH/2 : OH;
    constexpr int OWo  = DEC ? OW/2 : OW;
    constexpr int KTOT = CIN * (DEC ? 4 : 16);
    constexpr int CH   = (KTOT/64) / KS;
    constexpr int RPT  = CIN / 64;
    constexpr int RSH  = (RPT==1?0:RPT==2?1:RPT==4?2:3);
    constexpr int WSTR = CIN * 16;
    constexpr int TPR  = 256 / COB;
    constexpr int NU4  = 8 / TPR;
    constexpr int SPB  = OHo * OWo;
    constexpr int LSPB = ilog2c(SPB);
    constexpr int LOWo = ilog2c(OWo);

    __shared__ unsigned long long Xs[SPT*17];
    __shared__ unsigned long long Wls[COB*17];

    const int t   = threadIdx.x;
    const int bx  = blockIdx.x;
    const int cob = blockIdx.y;
    const int bz  = blockIdx.z;
    const int par = DEC ? (bz & 3) : 0;
    const int ks  = DEC ? (bz >> 2) : bz;
    const int poh = par >> 1, pw = par & 1;

    const int gsp_s = bx*SPT + t;
    const int img_s = gsp_s >> LSPB;
    const int r_s   = gsp_s & (SPB-1);
    const int oy_s  = r_s >> LOWo;
    const int ox_s  = r_s & (OWo-1);

    const int wco   = t / TPR;
    const int wpart = t % TPR;
    const f16* wbase = wp + (size_t)(cob*COB + wco)*WSTR + wpart*(64/TPR);

    const int wave = t >> 6, lane = t & 63, half = lane >> 5, l31 = lane & 31;
    const int co_w = (wave >> 1) * (CO_FR*32);
    const int sp_w = (wave & 1) * 128;

    f32x16 acc[CO_FR][4];
    #pragma unroll
    for (int i = 0; i < CO_FR; ++i)
        #pragma unroll
        for (int b = 0; b < 4; ++b)
            #pragma unroll
            for (int r = 0; r < 16; ++r) acc[i][b][r] = 0.f;

    for (int cc = 0; cc < CH; ++cc) {
        const int gc  = ks*CH + cc;
        const int tap = gc >> RSH;
        const int ci0 = (gc & (RPT-1)) << 6;
        int kh, kw, ih, iw;
        if (DEC) {
            const int t2h = tap >> 1, t2w = tap & 1;
            kh = (1-poh) + 2*t2h; kw = (1-pw) + 2*t2w;
            ih = oy_s + poh - t2h; iw = ox_s + pw - t2w;
        } else {
            kh = tap >> 2; kw = tap & 3;
            ih = 2*oy_s - 1 + kh; iw = 2*ox_s - 1 + kw;
        }
        const int woff = (kh*4 + kw)*CIN + ci0;

        if (cc) __syncthreads();
        {
            const uint4* src = (const uint4*)(wbase + woff);
            #pragma unroll
            for (int j = 0; j < NU4; ++j) {
                Q16 v; v.q = src[j];
                const int u0 = wco*17 + wpart*(NU4*2) + j*2;
                Wls[u0]   = v.u[0];
                Wls[u0+1] = v.u[1];
            }
        }
        {
            const bool ok = (unsigned)ih < (unsigned)IH && (unsigned)iw < (unsigned)IW;
            const int u0 = t*17;
            if (ok) {
                const uint4* src = (const uint4*)
                    (xin + ((size_t)(img_s*IH + ih)*IW + iw)*CIN + ci0);
                #pragma unroll
                for (int j = 0; j < 8; ++j) {
                    Q16 v; v.q = src[j];
                    Xs[u0 + j*2]   = v.u[0];
                    Xs[u0 + j*2+1] = v.u[1];
                }
            } else {
                #pragma unroll
                for (int j = 0; j < 16; ++j) Xs[u0 + j] = 0ull;
            }
        }
        __syncthreads();

        #pragma unroll
        for (int kk = 0; kk < 4; ++kk) {
            const int uo = kk*4 + 2*half;
            f16x8 wf[CO_FR], xf[4];
            #pragma unroll
            for (int i = 0; i < CO_FR; ++i) {
                U64x2 u; const int rw = (co_w + i*32 + l31)*17 + uo;
                u.u[0] = Wls[rw]; u.u[1] = Wls[rw+1]; wf[i] = u.v;
            }
            #pragma unroll
            for (int b = 0; b < 4; ++b) {
                U64x2 u; const int rx = (sp_w + b*32 + l31)*17 + uo;
                u.u[0] = Xs[rx]; u.u[1] = Xs[rx+1]; xf[b] = u.v;
            }
            #pragma unroll
            for (int i = 0; i < CO_FR; ++i)
                #pragma unroll
                for (int b = 0; b < 4; ++b)
                    acc[i][b] = __builtin_amdgcn_mfma_f32_32x32x16_f16(
                        xf[b], wf[i], acc[i][b], 0, 0, 0);
        }
    }

    #pragma unroll
    for (int b = 0; b < 4; ++b) {
        #pragma unroll
        for (int q = 0; q < 4; ++q) {
            #pragma unroll
            for (int r2 = 0; r2 < 4; ++r2) {
                const int sp_loc = sp_w + b*32 + q*8 + 4*half + r2;
                const int gsp    = bx*SPT + sp_loc;
                size_t base;
                if (DEC) {
                    const int img = gsp >> LSPB;
                    const int r   = gsp & (SPB-1);
                    const int oh  = 2*(r >> LOWo) + poh;
                    const int ow  = 2*(r & (OWo-1)) + pw;
                    base = ((size_t)(img*OH + oh)*OW + ow)*COUT + cob*COB;
                } else {
                    base = (size_t)gsp*COUT + cob*COB;
                }
                #pragma unroll
                for (int i = 0; i < CO_FR; ++i) {
                    const int co_l = co_w + i*32 + l31;
                    const float v  = acc[i][b][q*4 + r2];
                    if (KS == 1) out16[base + co_l] = (_Float16)v;
                    else         out32[(size_t)ks*ps + base + co_l] = v;
                }
            }
        }
    }

    // fused BN stats (KS==1): per-lane sums over the 64 sp values per co,
    // pair-reduce lanes l/l+32 (same co), then one f32 atomicAdd per co.
    if (KS == 1 && psumF != nullptr) {
        #pragma unroll
        for (int i = 0; i < CO_FR; ++i) {
            float s = 0.f, q = 0.f;
            #pragma unroll
            for (int b = 0; b < 4; ++b)
                #pragma unroll
                for (int r = 0; r < 16; ++r) {
                    const float v = acc[i][b][r];
                    s += v; q += v * v;
                }
            s += __shfl_down(s, 32);
            q += __shfl_down(q, 32);
            if (half == 0) {
                const int co = cob*COB + co_w + i*32 + l31;
                atomicAdd(psumF + co, s);
                atomicAdd(psqF + co, q);
            }
        }
    }
}

// ---------------------------------------------------------------------------
// conv1 via MFMA (verified round 8) + fused BN stats
// ---------------------------------------------------------------------------
__global__ __launch_bounds__(256,2) void conv1_mfma(
    const f16* __restrict__ xp, const f16* __restrict__ wp,
    f16* __restrict__ out, float* __restrict__ psumF, float* __restrict__ psqF)
{
    __shared__ unsigned long long Xs[256*17];
    __shared__ unsigned long long Wls[64*17];
    const int t = threadIdx.x, bx = blockIdx.x;

    {
        const int r = t >> 2, part = t & 3;
        const uint4* src = (const uint4*)(wp + r*64 + part*16);
        Q16 v0; v0.q = src[0];
        Q16 v1; v1.q = src[1];
        const int u0 = r*17 + part*4;
        Wls[u0]   = v0.u[0]; Wls[u0+1] = v0.u[1];
        Wls[u0+2] = v1.u[0]; Wls[u0+3] = v1.u[1];
    }
    {
        const int gsp = bx*256 + t;
        const int n = gsp >> 10, r = gsp & 1023;
        const int oy = r >> 5, ox = r & 31;
        const int ih0 = 2*oy - 1, iw0 = 2*ox - 1;
        const int u0 = t*17;
        #pragma unroll
        for (int tap = 0; tap < 16; ++tap) {
            const int ih = ih0 + (tap >> 2), iw = iw0 + (tap & 3);
            unsigned long long v = 0ull;
            if ((unsigned)ih < 64u && (unsigned)iw < 64u)
                v = *(const unsigned long long*)(xp + (((size_t)n*64 + ih)*64 + iw)*4);
            Xs[u0 + tap] = v;
        }
    }
    __syncthreads();

    const int wave = t >> 6, lane = t & 63, half = lane >> 5, l31 = lane & 31;
    const int co_w = (wave >> 1) * 32;
    const int sp_w = (wave & 1) * 128;

    f32x16 acc[4];
    #pragma unroll
    for (int b = 0; b < 4; ++b)
        #pragma unroll
        for (int r = 0; r < 16; ++r) acc[b][r] = 0.f;

    #pragma unroll
    for (int kk = 0; kk < 4; ++kk) {
        const int uo = kk*4 + 2*half;
        U64x2 uw; const int rw = (co_w + l31)*17 + uo;
        uw.u[0] = Wls[rw]; uw.u[1] = Wls[rw+1];
        #pragma unroll
        for (int b = 0; b < 4; ++b) {
            U64x2 ux; const int rx = (sp_w + b*32 + l31)*17 + uo;
            ux.u[0] = Xs[rx]; ux.u[1] = Xs[rx+1];
            acc[b] = __builtin_amdgcn_mfma_f32_32x32x16_f16(
                ux.v, uw.v, acc[b], 0, 0, 0);
        }
    }
    #pragma unroll
    for (int b = 0; b < 4; ++b)
        #pragma unroll
        for (int q = 0; q < 4; ++q)
            #pragma unroll
            for (int r2 = 0; r2 < 4; ++r2) {
                const int sp_loc = sp_w + b*32 + q*8 + 4*half + r2;
                out[(size_t)(bx*256 + sp_loc)*64 + co_w + l31] =
                    (_Float16)acc[b][q*4 + r2];
            }

    float s = 0.f, q = 0.f;
    #pragma unroll
    for (int b = 0; b < 4; ++b)
        #pragma unroll
        for (int r = 0; r < 16; ++r) {
            const float v = acc[b][r];
            s += v; q += v * v;
        }
    s += __shfl_down(s, 32);
    q += __shfl_down(q, 32);
    if (half == 0) {
        const int co = co_w + l31;
        atomicAdd(psumF + co, s);
        atomicAdd(psqF + co, q);
    }
}

// ---------------------------------------------------------------------------
// deconv4 (64->3) via MFMA, COUT padded to 32 (verified round 9)
// ---------------------------------------------------------------------------
__global__ __launch_bounds__(256,2) void deconv4_mfma(
    const f16* __restrict__ xin, const f16* __restrict__ wp,
    float* __restrict__ out)
{
    __shared__ unsigned long long Xs[256*17];
    __shared__ unsigned long long Wls[32*17];

    const int t   = threadIdx.x;
    const int bx  = blockIdx.x;
    const int par = blockIdx.y;
    const int poh = par >> 1, pw = par & 1;

    const int gsp_s = bx*256 + t;
    const int img_s = gsp_s >> 10;
    const int r_s   = gsp_s & 1023;
    const int oy_s  = r_s >> 5;
    const int ox_s  = r_s & 31;

    const int wco   = t >> 3;
    const int wpart = t & 7;

    const int wave = t >> 6, lane = t & 63, half = lane >> 5, l31 = lane & 31;
    const int sp_w = wave * 64;

    f32x16 acc[2];
    #pragma unroll
    for (int b = 0; b < 2; ++b)
        #pragma unroll
        for (int r = 0; r < 16; ++r) acc[b][r] = 0.f;

    for (int cc = 0; cc < 4; ++cc) {
        const int t2h = cc >> 1, t2w = cc & 1;
        const int kh = (1-poh) + 2*t2h, kw = (1-pw) + 2*t2w;
        const int ih = oy_s + poh - t2h, iw = ox_s + pw - t2w;

        if (cc) __syncthreads();
        {
            Q16 v; v.q = *(const uint4*)(wp + wco*1024 + (kh*4 + kw)*64 + wpart*8);
            const int u0 = wco*17 + wpart*2;
            Wls[u0] = v.u[0]; Wls[u0+1] = v.u[1];
        }
        {
            const bool ok = (unsigned)ih < 32u && (unsigned)iw < 32u;
            const int u0 = t*17;
            if (ok) {
                const uint4* src = (const uint4*)
                    (xin + ((size_t)(img_s*32 + ih)*32 + iw)*64);
                #pragma unroll
                for (int j = 0; j < 8; ++j) {
                    Q16 v; v.q = src[j];
                    Xs[u0 + j*2]   = v.u[0];
                    Xs[u0 + j*2+1] = v.u[1];
                }
            } else {
                #pragma unroll
                for (int j = 0; j < 16; ++j) Xs[u0 + j] = 0ull;
            }
        }
        __syncthreads();

        #pragma unroll
        for (int kk = 0; kk < 4; ++kk) {
            const int uo = kk*4 + 2*half;
            U64x2 uw; const int rw = l31*17 + uo;
            uw.u[0] = Wls[rw]; uw.u[1] = Wls[rw+1];
            #pragma unroll
            for (int b = 0; b < 2; ++b) {
                U64x2 ux; const int rx = (sp_w + b*32 + l31)*17 + uo;
                ux.u[0] = Xs[rx]; ux.u[1] = Xs[rx+1];
                acc[b] = __builtin_amdgcn_mfma_f32_32x32x16_f16(
                    uw.v, ux.v, acc[b], 0, 0, 0);
            }
        }
    }

    if (half == 0) {
        #pragma unroll
        for (int b = 0; b < 2; ++b) {
            const int gsp = bx*256 + sp_w + b*32 + l31;
            const int img = gsp >> 10;
            const int r   = gsp & 1023;
            const int oh  = 2*(r >> 5) + poh;
            const int ow  = 2*(r & 31) + pw;
            #pragma unroll
            for (int co = 0; co < 3; ++co)
                out[(((size_t)img*3 + co)*64 + oh)*64 + ow] =
                    fast_tanh(acc[b][co]);
        }
    }
}

// ---------------------------------------------------------------------------
// prep kernels (verified)
// ---------------------------------------------------------------------------
__global__ __launch_bounds__(256) void prep_x(
    const float* __restrict__ x, f16* __restrict__ xp)
{
    const int i = blockIdx.x*256 + threadIdx.x;
    const int n = i >> 12, p = i & 4095;
    const float* b = x + (size_t)n*12288 + p;
    union { _Float16 h[4]; unsigned long long u; } o;
    o.h[0] = (_Float16)b[0];
    o.h[1] = (_Float16)b[4096];
    o.h[2] = (_Float16)b[8192];
    o.h[3] = (_Float16)0.f;
    *(unsigned long long*)(xp + (size_t)i*4) = o.u;
}

__global__ __launch_bounds__(256) void prep_w1(
    const float* __restrict__ w1, f16* __restrict__ wp)
{
    const int e = blockIdx.x*256 + threadIdx.x;
    const int co = e >> 6, k = e & 63, tap = k >> 2, ci = k & 3;
    const float v = (ci < 3) ? w1[(co*3 + ci)*16 + tap] : 0.f;
    wp[e] = (_Float16)v;
}

__global__ __launch_bounds__(256) void prep_w4(
    const float* __restrict__ dw4, f16* __restrict__ wp)
{
    const int e = blockIdx.x*256 + threadIdx.x;
    const int co = e >> 10, r = e & 1023, khw = r >> 6, ci = r & 63;
    const float v = (co < 3) ? dw4[(ci*3 + co)*16 + khw] : 0.f;
    wp[e] = (_Float16)v;
}

__global__ __launch_bounds__(256) void prep_w(
    const float* __restrict__ w2, const float* __restrict__ w3,
    const float* __restrict__ w4, const float* __restrict__ dw1,
    const float* __restrict__ dw2, const float* __restrict__ dw3,
    f16* __restrict__ dst)
{
    const int e = blockIdx.x*256 + threadIdx.x;
    float v;
    if (e < 131072) {
        int co = e >> 10, r = e & 1023, khw = r >> 6, ci = r & 63;
        v = w2[(co*64 + ci)*16 + khw];
    } else if (e < 655360) {
        int l = e - 131072;
        int co = l >> 11, r = l & 2047, khw = r >> 7, ci = r & 127;
        v = w3[(co*128 + ci)*16 + khw];
    } else if (e < 2752512) {
        int l = e - 655360;
        int co = l >> 12, r = l & 4095, khw = r >> 8, ci = r & 255;
        v = w4[(co*256 + ci)*16 + khw];
    } else if (e < 4849664) {
        int l = e - 2752512;
        int co = l >> 13, r = l & 8191, khw = r >> 9, ci = r & 511;
        v = dw1[(ci*256 + co)*16 + khw];
    } else if (e < 5373952) {
        int l = e - 4849664;
        int co = l >> 12, r = l & 4095, khw = r >> 8, ci = r & 255;
        v = dw2[(ci*128 + co)*16 + khw];
    } else {
        int l = e - 5373952;
        int co = l >> 11, r = l & 2047, khw = r >> 7, ci = r & 127;
        v = dw3[(ci*64 + co)*16 + khw];
    }
    dst[e] = (_Float16)v;
}

// ---------------------------------------------------------------------------
// BN stack: bn_partial only for conv4 (KS=4); finalize; fused affine+act
// ---------------------------------------------------------------------------
template<typename T, int P>
__global__ __launch_bounds__(256) void bn_partial(
    const T* __restrict__ x, size_t ps, float* __restrict__ psum,
    float* __restrict__ psq, int C, int rowsPerS, int S)
{
    const int s = blockIdx.x;
    const int c = (blockIdx.y << 6) + (threadIdx.x & 63);
    float a = 0.f, q = 0.f;
    const int rEnd = (s + 1) * rowsPerS;
    for (int r = s*rowsPerS + (threadIdx.x >> 6); r < rEnd; r += 4) {
        float v = 0.f;
        #pragma unroll
        for (int p = 0; p < P; ++p)
            v += (float)x[p*ps + (size_t)r * C + c];
        a += v; q += v * v;
    }
    __shared__ float ls[256], lq[256];
    ls[threadIdx.x] = a; lq[threadIdx.x] = q;
    __syncthreads();
    if (threadIdx.x < 64) {
        a = ls[threadIdx.x] + ls[threadIdx.x+64] + ls[threadIdx.x+128] + ls[threadIdx.x+192];
        q = lq[threadIdx.x] + lq[threadIdx.x+64] + lq[threadIdx.x+128] + lq[threadIdx.x+192];
        psum[c * S + s] = a; psq[c * S + s] = q;
    }
}

__global__ __launch_bounds__(256) void bn_finalize(
    const float* __restrict__ psum, const float* __restrict__ psq,
    const float* __restrict__ gamma, const float* __restrict__ beta,
    float* __restrict__ scale, float* __restrict__ shift,
    int C, int S, float inv_count)
{
    int c = blockIdx.x * 256 + threadIdx.x;
    if (c >= C) return;
    float s = 0.f, q = 0.f;
    for (int i = 0; i < S; ++i) { s += psum[c*S + i]; q += psq[c*S + i]; }
    float m   = s * inv_count;
    float var = q * inv_count - m * m;
    var = var < 0.f ? 0.f : var;
    float sc = gamma[c] * rsqrtf(var + 1e-5f);
    scale[c] = sc;
    shift[c] = beta[c] - m * sc;
}

__global__ __launch_bounds__(256) void bn_act16(
    f16* __restrict__ x, const float* __restrict__ sc, const float* __restrict__ sh,
    int Cmask, float slope)
{
    const size_t i8 = ((size_t)blockIdx.x*256 + threadIdx.x) * 8;
    union { uint4 u; _Float16 h[8]; } a;
    a.u = *(const uint4*)(x + i8);
    const int c0 = (int)(i8 & (size_t)Cmask);
    #pragma unroll
    for (int j = 0; j < 8; ++j) {
        float v = (float)a.h[j] * sc[c0+j] + sh[c0+j];
        a.h[j] = (_Float16)(v >= 0.f ? v : slope * v);
    }
    *(uint4*)(x + i8) = a.u;
}

template<int P>
__global__ __launch_bounds__(256) void bn_act32(
    const float* __restrict__ x, size_t ps, f16* __restrict__ y,
    const float* __restrict__ sc, const float* __restrict__ sh,
    int Cmask, float slope)
{
    const size_t i8 = ((size_t)blockIdx.x*256 + threadIdx.x) * 8;
    float xv[8] = {0,0,0,0,0,0,0,0};
    #pragma unroll
    for (int p = 0; p < P; ++p) {
        float4 v0 = *(const float4*)(x + p*ps + i8);
        float4 v1 = *(const float4*)(x + p*ps + i8 + 4);
        xv[0]+=v0.x; xv[1]+=v0.y; xv[2]+=v0.z; xv[3]+=v0.w;
        xv[4]+=v1.x; xv[5]+=v1.y; xv[6]+=v1.z; xv[7]+=v1.w;
    }
    union { uint4 u; _Float16 h[8]; } a;
    const int c0 = (int)(i8 & (size_t)Cmask);
    #pragma unroll
    for (int j = 0; j < 8; ++j) {
        float v = xv[j] * sc[c0+j] + sh[c0+j];
        a.h[j] = (_Float16)(v >= 0.f ? v : slope * v);
    }
    *(uint4*)(y + i8) = a.u;
}

__global__ __launch_bounds__(256) void chanlin16(
    const f16* __restrict__ in, const float* __restrict__ w,
    const float* __restrict__ bias, f16* __restrict__ out)
{
    const int i = blockIdx.x*256 + threadIdx.x;
    const int c  = i & 511;
    const int bt = i >> 9;
    const int b  = bt >> 4, tt = bt & 15;
    const f16* src = in + ((size_t)b*16)*512 + c;
    const float* wr = w + ((size_t)c*16 + tt)*16;
    float acc = bias[c*16 + tt];
    #pragma unroll
    for (int s = 0; s < 16; ++s)
        acc = fmaf((float)src[s*512], wr[s], acc);
    out[i] = (_Float16)acc;
}

extern "C" void kernel_launch(void* const* d_in, const int* in_sizes, int n_in,
                              void* d_out, int out_size, void* d_ws, size_t ws_size,
                              hipStream_t stream)
{
    const float* x   = (const float*)d_in[0];
    const float* w1  = (const float*)d_in[1];
    const float* w2  = (const float*)d_in[2];
    const float* w3  = (const float*)d_in[3];
    const float* w4  = (const float*)d_in[4];
    const float* g1  = (const float*)d_in[5];
    const float* b1  = (const float*)d_in[6];
    const float* g2  = (const float*)d_in[7];
    const float* b2  = (const float*)d_in[8];
    const float* g3  = (const float*)d_in[9];
    const float* b3  = (const float*)d_in[10];
    const float* g4  = (const float*)d_in[11];
    const float* b4  = (const float*)d_in[12];
    const float* cww = (const float*)d_in[13];
    const float* cwb = (const float*)d_in[14];
    const float* dw1 = (const float*)d_in[15];
    const float* dw2 = (const float*)d_in[16];
    const float* dw3 = (const float*)d_in[17];
    const float* dw4 = (const float*)d_in[18];
    const float* dg1 = (const float*)d_in[19];
    const float* db1 = (const float*)d_in[20];
    const float* dg2 = (const float*)d_in[21];
    const float* db2 = (const float*)d_in[22];
    const float* dg3 = (const float*)d_in[23];
    const float* db3 = (const float*)d_in[24];

    // ws header (256K): psum 64K | psq 64K | scale 2K | shift 2K | ... |
    //                   fused stats @192K: 7 layers x 1024 f32 (28K)
    char* WS = (char*)d_ws;
    float* psum  = (float*)WS;
    float* psq   = (float*)(WS + 65536);
    float* scale = (float*)(WS + 131072);
    float* shift = (float*)(WS + 133120);
    float* fst   = (float*)(WS + 196608);
    f16* slotA   = (f16*)(WS + 262144);
    f16* slotB   = (f16*)(WS + 262144 + 33554432);
    f16* wprep   = (f16*)(WS + 84148224);
    f16* wprep1  = wprep + 5505024;
    f16* wprep4  = wprep1 + 4096;

    f16*   A_hi  = slotA + 8388608;
    float* pB    = (float*)slotB;
    f16*   xpack = slotA;

    // per-layer fused stat slots: psum = fst + L*1024, psq = +512
    float* fs0 = fst;          float* fs1 = fst + 1024;
    float* fs2 = fst + 2048;   float* fs4 = fst + 4096;
    float* fs5 = fst + 5120;   float* fs6 = fst + 6144;

    hipMemsetAsync(fst, 0, 28672, stream);
    prep_w<<<21504, 256, 0, stream>>>(w2, w3, w4, dw1, dw2, dw3, wprep);
    prep_w1<<<16, 256, 0, stream>>>(w1, wprep1);
    prep_w4<<<128, 256, 0, stream>>>(dw4, wprep4);
    prep_x<<<4096, 256, 0, stream>>>(x, xpack);

    // ---- conv1 (MFMA + fused stats): xpack(slotA) -> slotB ----
    conv1_mfma<<<1024, 256, 0, stream>>>(xpack, wprep1, slotB, fs0, fs0 + 512);
    bn_finalize<<<1, 256, 0, stream>>>(fs0, fs0 + 512, g1, b1, scale, shift, 64, 1, 1.f/262144.f);
    bn_act16<<<8192, 256, 0, stream>>>(slotB, scale, shift, 63, 0.2f);

    // ---- conv2 (fused stats): slotB -> slotA ----
    mfma_conv<64,32,32,16,16,128, 128,256,1,2,false><<<dim3(256,1,1), 256, 0, stream>>>(
        slotB, wprep, slotA, nullptr, 0, fs1, fs1 + 512);
    bn_finalize<<<1, 256, 0, stream>>>(fs1, fs1 + 512, g2, b2, scale, shift, 128, 1, 1.f/65536.f);
    bn_act16<<<4096, 256, 0, stream>>>(slotA, scale, shift, 127, 0.2f);

    // ---- conv3 (KS=1, COB=64, fused stats): slotA -> A_hi f16 ----
    mfma_conv<128,16,16,8,8,256, 64,256,1,1,false><<<dim3(64,4,1), 256, 0, stream>>>(
        slotA, wprep + 131072, A_hi, nullptr, 0, fs2, fs2 + 512);
    bn_finalize<<<1, 256, 0, stream>>>(fs2, fs2 + 512, g3, b3, scale, shift, 256, 1, 1.f/16384.f);
    bn_act16<<<2048, 256, 0, stream>>>(A_hi, scale, shift, 255, 0.2f);

    // ---- conv4 (KS=4, partials in slotB): A_hi -> pB ----
    mfma_conv<256,8,8,4,4,512, 128,256,4,2,false><<<dim3(16,4,4), 256, 0, stream>>>(
        A_hi, wprep + 655360, nullptr, pB, (size_t)2097152, nullptr, nullptr);
    bn_partial<float,4><<<dim3(32,8), 256, 0, stream>>>(pB, (size_t)2097152, psum, psq, 512, 128, 32);
    bn_finalize<<<2, 256, 0, stream>>>(psum, psq, g4, b4, scale, shift, 512, 32, 1.f/4096.f);
    bn_act32<4><<<1024, 256, 0, stream>>>(pB, (size_t)2097152, slotA, scale, shift, 511, 0.2f);

    // ---- channel-wise linear: slotA(lo) -> slotB(lo) ----
    chanlin16<<<8192, 256, 0, stream>>>(slotA, cww, cwb, slotB);

    // ---- deconv1 (KS=1, COB=64, fused stats): slotB(lo) -> A_hi ----
    mfma_conv<512,4,4,8,8,256, 64,256,1,1,true><<<dim3(16,4,4), 256, 0, stream>>>(
        slotB, wprep + 2752512, A_hi, nullptr, 0, fs4, fs4 + 512);
    bn_finalize<<<1, 256, 0, stream>>>(fs4, fs4 + 512, dg1, db1, scale, shift, 256, 1, 1.f/16384.f);
    bn_act16<<<2048, 256, 0, stream>>>(A_hi, scale, shift, 255, 0.f);

    // ---- deconv2 (fused stats): A_hi -> slotB(lo) ----
    mfma_conv<256,8,8,16,16,128, 128,256,1,2,true><<<dim3(64,1,4), 256, 0, stream>>>(
        A_hi, wprep + 4849664, slotB, nullptr, 0, fs5, fs5 + 512);
    bn_finalize<<<1, 256, 0, stream>>>(fs5, fs5 + 512, dg2, db2, scale, shift, 128, 1, 1.f/65536.f);
    bn_act16<<<4096, 256, 0, stream>>>(slotB, scale, shift, 127, 0.f);

    // ---- deconv3 (COB=64, fused stats): slotB(lo) -> slotA full ----
    mfma_conv<128,16,16,32,32,64, 64,256,1,1,true><<<dim3(256,1,4), 256, 0, stream>>>(
        slotB, wprep + 5373952, slotA, nullptr, 0, fs6, fs6 + 512);
    bn_finalize<<<1, 256, 0, stream>>>(fs6, fs6 + 512, dg3, db3, scale, shift, 64, 1, 1.f/262144.f);
    bn_act16<<<8192, 256, 0, stream>>>(slotA, scale, shift, 63, 0.f);

    // ---- deconv4 (MFMA) + tanh: slotA -> d_out ----
    deconv4_mfma<<<dim3(1024,4), 256, 0, stream>>>(slotA, wprep4, (float*)d_out);
}